// Round 2
// baseline (934.821 us; speedup 1.0000x reference)
//
#include <hip/hip_runtime.h>
#include <hip/hip_bf16.h>

// ---------- helpers ----------
__device__ __forceinline__ float b2f(unsigned short u) {
    return __uint_as_float(((unsigned)u) << 16);
}
__device__ __forceinline__ unsigned short f2b(float f) {
    __hip_bfloat16 h = __float2bfloat16(f);
    return *reinterpret_cast<unsigned short*>(&h);
}
// cheap round-to-nearest-even bf16 (no NaN inputs in this pipeline)
__device__ __forceinline__ unsigned short f2b_rne(float f) {
    unsigned u = __float_as_uint(f);
    return (unsigned short)((u + 0x7fffu + ((u >> 16) & 1u)) >> 16);
}
// pack two f32 -> packed 2x bf16 (RNE), single VALU op
__device__ __forceinline__ unsigned pk_bf16(float lo, float hi) {
    unsigned r;
    asm("v_cvt_pk_bf16_f32 %0, %1, %2" : "=v"(r) : "v"(lo), "v"(hi));
    return r;
}
__device__ __forceinline__ float sigm(float v) {
    return 1.f / (1.f + __expf(-v));
}
// tanh-approx GELU (max abs dev from exact ~1e-3; post-W2 contribution <1e-3)
__device__ __forceinline__ float gelu_t(float x) {
    float y = 0.7978845608f * (x + 0.044715f * x * x * x);
    float e = __expf(2.f * y);
    float th = 1.f - 2.f / (e + 1.f);
    return 0.5f * x * (1.f + th);
}

typedef __attribute__((ext_vector_type(8))) short s8v;   // 8 bf16 (4 VGPRs)
typedef __attribute__((ext_vector_type(4))) float f4v;   // 4 fp32 acc

#define MFMA_BF16 __builtin_amdgcn_mfma_f32_16x16x32_bf16

// ---------- 15-feature map (full, for the boundary path) ----------
__device__ __forceinline__ void make_feats(const unsigned short* __restrict__ qpts,
                                           int r, float* __restrict__ f) {
    unsigned pq = *(const unsigned*)(qpts + (size_t)r * 2);
    float x0 = b2f((unsigned short)(pq & 0xffff));
    float x1 = b2f((unsigned short)(pq >> 16));
    const float PI = 3.14159265358979323846f;
    float a0 = x0 - 1.5f, a1 = x1 - 1.5f, c0 = x0 - 4.5f, c1 = x1 - 4.5f;
    f[0] = x0;        f[1] = x1;
    f[2] = x0 * x0;   f[3] = x1 * x1;
    f[4] = a0 * a0;   f[5] = a1 * a1;
    f[6] = c0 * c0;   f[7] = c1 * c1;
    f[8] = sigm(x0);  f[9] = sigm(x1);
    f[10] = sigm(a0); f[11] = sigm(a1);
    f[12] = sigm(c0); f[13] = sigm(c1);
    f[14] = a0;       f[15] = a1;
    f[16] = c0;       f[17] = c1;
    f[18] = __sinf(PI * x0);          f[19] = __sinf(PI * x1);
    f[20] = __cosf(PI * x0);          f[21] = __cosf(PI * x1);
    f[22] = __sinf(PI * 0.25f * x0);  f[23] = __sinf(PI * 0.25f * x1);
    f[24] = __cosf(PI * 0.25f * x0);  f[25] = __cosf(PI * 0.25f * x1);
    f[26] = __sinf(PI * 0.5f * x0);   f[27] = __sinf(PI * 0.5f * x1);
    f[28] = __cosf(PI * 0.5f * x0);   f[29] = __cosf(PI * 0.5f * x1);
}

// 8 features for k = qd*8 .. qd*8+7 (quad-split of the 30-vector, 30/31 -> 0)
__device__ __forceinline__ void feats8(unsigned pq, int qd, float* __restrict__ f8) {
    float x0 = b2f((unsigned short)(pq & 0xffff));
    float x1 = b2f((unsigned short)(pq >> 16));
    const float PI = 3.14159265358979323846f;
    float a0 = x0 - 1.5f, a1 = x1 - 1.5f, c0 = x0 - 4.5f, c1 = x1 - 4.5f;
    if (qd == 0) {
        f8[0] = x0;      f8[1] = x1;
        f8[2] = x0 * x0; f8[3] = x1 * x1;
        f8[4] = a0 * a0; f8[5] = a1 * a1;
        f8[6] = c0 * c0; f8[7] = c1 * c1;
    } else if (qd == 1) {
        f8[0] = sigm(x0); f8[1] = sigm(x1);
        f8[2] = sigm(a0); f8[3] = sigm(a1);
        f8[4] = sigm(c0); f8[5] = sigm(c1);
        f8[6] = a0;       f8[7] = a1;
    } else if (qd == 2) {
        f8[0] = c0; f8[1] = c1;
        f8[2] = __sinf(PI * x0);          f8[3] = __sinf(PI * x1);
        f8[4] = __cosf(PI * x0);          f8[5] = __cosf(PI * x1);
        f8[6] = __sinf(PI * 0.25f * x0);  f8[7] = __sinf(PI * 0.25f * x1);
    } else {
        f8[0] = __cosf(PI * 0.25f * x0);  f8[1] = __cosf(PI * 0.25f * x1);
        f8[2] = __sinf(PI * 0.5f * x0);   f8[3] = __sinf(PI * 0.5f * x1);
        f8[4] = __cosf(PI * 0.5f * x0);   f8[5] = __cosf(PI * 0.5f * x1);
        f8[6] = 0.f;                      f8[7] = 0.f;
    }
}

// ---------- canonicalize all inputs to bf16 (embedded dtype detection) ----------
struct ConvArgs {
    const void* p[22];
    int off[23];
};

__global__ __launch_bounds__(256) void convert_kernel(
    ConvArgs a, const unsigned short* __restrict__ pe_w_raw,
    int* __restrict__ flag, unsigned short* __restrict__ canon, int total)
{
    __shared__ int cnt;
    if (threadIdx.x == 0) cnt = 0;
    __syncthreads();
    float v = b2f(pe_w_raw[threadIdx.x * 2]);
    if (!(fabsf(v) < 1.0f)) atomicAdd(&cnt, 1);
    __syncthreads();
    int isf32 = (cnt >= 16) ? 1 : 0;
    if (blockIdx.x == 0 && threadIdx.x == 0) *flag = isf32;

    int g = blockIdx.x * 256 + threadIdx.x;
    if (g >= total) return;
    int s = 0;
    #pragma unroll
    for (int i = 1; i < 23; i++) s += (g >= a.off[i]) ? 1 : 0;
    int local = g - a.off[s];
    unsigned short r;
    if (isf32) r = f2b(((const float*)a.p[s])[local]);
    else       r = ((const unsigned short*)a.p[s])[local];
    canon[g] = r;
}

// ---------- boundary positional encoding (M rows, fp32 out) ----------
__global__ __launch_bounds__(256) void encode_kernel(
    const unsigned short* __restrict__ pts,
    const unsigned short* __restrict__ w,
    const unsigned short* __restrict__ b,
    float* __restrict__ out)
{
    __shared__ __align__(16) float wsm[30 * 128];
    __shared__ float bs[128];
    int t = threadIdx.x;
    for (int i = t; i < 30 * 128; i += 256) wsm[i] = b2f(w[i]);
    if (t < 128) bs[t] = b2f(b[t]);
    __syncthreads();

    int r = blockIdx.x * 8 + (t >> 5);
    int j = t & 31;
    float f[30];
    make_feats(pts, r, f);
    float s0 = bs[j * 4 + 0], s1 = bs[j * 4 + 1], s2 = bs[j * 4 + 2], s3 = bs[j * 4 + 3];
    #pragma unroll
    for (int ff = 0; ff < 30; ff++) {
        float4 wv = *(const float4*)&wsm[ff * 128 + j * 4];
        float fv = f[ff];
        s0 += fv * wv.x; s1 += fv * wv.y; s2 += fv * wv.z; s3 += fv * wv.w;
    }
    *(float4*)&out[(size_t)r * 128 + j * 4] =
        make_float4(__sinf(s0), __sinf(s1), __sinf(s2), __sinf(s3));
}

// ---------- boundary k/v heads (+ zeroing of kv/ks accumulators) ----------
__global__ __launch_bounds__(256) void khvh_kernel(
    const float* __restrict__ benc,
    const unsigned short* __restrict__ Wk, const unsigned short* __restrict__ bk,
    const unsigned short* __restrict__ Wv, const unsigned short* __restrict__ bv,
    float* __restrict__ kh, float* __restrict__ vh, float* __restrict__ kvz)
{
    int g = blockIdx.x * 256 + threadIdx.x;
    if (g < 12672) kvz[g] = 0.f;   // kvs(12288) + kss(384), contiguous
    int lh = g >> 17;
    int rem = g & 131071;
    int m = rem >> 5;
    int dd = rem & 31;
    const unsigned short* wk = Wk + lh * 4096 + dd;
    const unsigned short* wv = Wv + lh * 4096 + dd;
    const float* br = benc + (size_t)m * 128;
    float ka = 0.f, va = 0.f;
    #pragma unroll 8
    for (int c = 0; c < 128; c++) {
        float bb = br[c];
        ka += bb * b2f(wk[c * 32]);
        va += bb * b2f(wv[c * 32]);
    }
    ka += b2f(bk[lh * 32 + dd]); ka = ka * ka;
    va += b2f(bv[lh * 32 + dd]);
    kh[g] = ka; vh[g] = va;
}

// ---------- reduce over boundary points: kvsum[lh][d][e], ksum[lh][d] ----------
__global__ __launch_bounds__(1024) void kvred_kernel(
    const float* __restrict__ kh, const float* __restrict__ vh,
    float* __restrict__ kvsum, float* __restrict__ ksum)
{
    __shared__ float khs[1024];
    __shared__ float vhs[1024];
    int t = threadIdx.x;
    int lh = blockIdx.x >> 3;
    int part = blockIdx.x & 7;
    int dd = t >> 5, ee = t & 31;
    float kva = 0.f, ksa = 0.f;
    for (int ch = 0; ch < 16; ch++) {
        int base = lh * 131072 + (part * 16 + ch) * 1024;
        khs[t] = kh[base + t];
        vhs[t] = vh[base + t];
        __syncthreads();
        #pragma unroll
        for (int i = 0; i < 32; i++) {
            float kk = khs[i * 32 + dd];
            kva += kk * vhs[i * 32 + ee];
            ksa += kk;
        }
        __syncthreads();
    }
    atomicAdd(&kvsum[lh * 1024 + dd * 32 + ee], kva);
    if (ee == 0) atomicAdd(&ksum[lh * 32 + dd], ksa);
}

// ---------- prep: transposes + Wa fold + Ks + padded pe_wT, one kernel ----------
__global__ __launch_bounds__(256) void prep_kernel(
    const unsigned short* __restrict__ Wq, const unsigned short* __restrict__ W1,
    const unsigned short* __restrict__ W2, const unsigned short* __restrict__ pw1,
    const float* __restrict__ kvs, const float* __restrict__ kss,
    const unsigned short* __restrict__ Wo, const unsigned short* __restrict__ pe_w,
    unsigned short* __restrict__ wqT, unsigned short* __restrict__ w1T,
    unsigned short* __restrict__ w2T, unsigned short* __restrict__ pw1T,
    unsigned short* __restrict__ waT, unsigned short* __restrict__ ksT,
    unsigned short* __restrict__ pweT)
{
    int g = blockIdx.x * 256 + threadIdx.x;
    if (g < 49152) {
        int l = g >> 14, r = g & 16383, n = r >> 7, k = r & 127;
        wqT[g] = Wq[((l * 4 + (n >> 5)) * 128 + k) * 32 + (n & 31)];  // head-interleaved cols
    } else if (g < 98304) {
        int q = g - 49152; int l = q >> 14, r = q & 16383, n = r >> 7, k = r & 127;
        w1T[q] = W1[(l * 128 + k) * 128 + n];
    } else if (g < 147456) {
        int q = g - 98304; int l = q >> 14, r = q & 16383, n = r >> 7, k = r & 127;
        w2T[q] = W2[(l * 128 + k) * 128 + n];
    } else if (g < 155648) {
        int q = g - 147456; int n = q >> 7, k = q & 127;
        pw1T[q] = pw1[k * 64 + n];
    } else if (g < 204800) {
        int q = g - 155648; int l = q >> 14, r = q & 16383, n = r >> 7, k = r & 127;
        int hk = k >> 5, dk = k & 31;
        const float* kvp = kvs + (l * 4 + hk) * 1024 + dk * 32;
        const unsigned short* wop = Wo + (size_t)(l * 128 + hk * 32) * 128 + n;
        float s = 0.f;
        #pragma unroll 8
        for (int j = 0; j < 32; j++) s += kvp[j] * b2f(wop[j * 128]);
        waT[q] = f2b(s);
    } else if (g < 210944) {
        int q = g - 204800; int l = q >> 11, r = q & 2047, n = r >> 7, k = r & 127;
        unsigned short v = 0;
        if (n < 4 && (k >> 5) == n) v = f2b(kss[(l * 4 + n) * 32 + (k & 31)]);
        ksT[q] = v;
    } else if (g < 215040) {
        int q = g - 210944; int n = q >> 5, k = q & 31;   // pe_wT [128][32], k>=30 -> 0
        pweT[q] = (k < 30) ? pe_w[k * 128 + n] : (unsigned short)0;
    }
}

// ---------- the fused mega kernel: encode + 3 layers + projector ----------
// ROUND-1 restructure (occupancy + epilogue VALU), resubmitted after infra
// failure in the previous bench attempt:
//  * 64 rows/block, 4 waves, 16 rows/wave (was 128/32). Halves per-lane state
//    (hres 64->32 f32, af 32->16) so unified VGPR+AGPR fits well under 256 ->
//    2-3 waves/SIMD instead of 1 (old kernel's >256 unified regs were the
//    occupancy limiter; cf. the (256,2) spill incident).
//  * MFMA operands SWAPPED: A = weight frags, B = activation frags. A/B frags
//    have identical per-lane layouts (lane&15 -> row/col, (lane>>4)*8 -> k),
//    so all loads are unchanged; but C now holds, per lane, 4 CONSECUTIVE
//    output features of the lane's own row (row = l16's sA row). Epilogues
//    become 2x v_cvt_pk_bf16_f32 + 1x ds_write_b64 instead of 4 scalar
//    rne+ds_write_b16.
//  * den via swapped MFMA + __shfl broadcast (dens LDS buffer removed);
//    ksT read directly from L2 (sKsAll staging removed). LDS 57.8KB -> 24.6KB.
#define LDA 136   // LDS row stride in ushorts (272B = 17*16B)

// A-side (weights) dual-ntile iteration over a 128x128 [n][k] matrix with
// pair prefetch. Epilogue sees: nt (0..7), x (f4v) = features
// nt*16 + qd*4 + i of row rA0.
#define RUN_MM(AF, W, ...) do {                                               \
    const unsigned short* _base = (W) + l16 * 128 + qd * 8;                   \
    s8v _c[8]; s8v _n[8];                                                     \
    _Pragma("unroll")                                                         \
    for (int _k = 0; _k < 4; _k++) {                                          \
        _c[_k]     = *(const s8v*)(_base + _k * 32);                          \
        _c[4 + _k] = *(const s8v*)(_base + 2048 + _k * 32);                   \
    }                                                                         \
    _Pragma("unroll")                                                         \
    for (int _p = 0; _p < 4; _p++) {                                          \
        if (_p < 3) {                                                         \
            const unsigned short* _bp = _base + (_p * 2 + 2) * 2048;          \
            _Pragma("unroll")                                                 \
            for (int _k = 0; _k < 4; _k++) {                                  \
                _n[_k]     = *(const s8v*)(_bp + _k * 32);                    \
                _n[4 + _k] = *(const s8v*)(_bp + 2048 + _k * 32);             \
            }                                                                 \
        }                                                                     \
        f4v _x0 = {0.f,0.f,0.f,0.f}, _x1 = {0.f,0.f,0.f,0.f};                 \
        _Pragma("unroll")                                                     \
        for (int _k = 0; _k < 4; _k++) {                                      \
            _x0 = MFMA_BF16(_c[_k],     AF[_k], _x0, 0, 0, 0);                \
            _x1 = MFMA_BF16(_c[4 + _k], AF[_k], _x1, 0, 0, 0);                \
        }                                                                     \
        { const int nt = _p * 2;     const f4v x = _x0; __VA_ARGS__ }         \
        { const int nt = _p * 2 + 1; const f4v x = _x1; __VA_ARGS__ }         \
        if (_p < 3) {                                                         \
            _Pragma("unroll")                                                 \
            for (int _k = 0; _k < 8; _k++) _c[_k] = _n[_k];                   \
        }                                                                     \
    }                                                                         \
} while (0)

// load B-fragments (this wave's 16-row tile) from sA
#define LOAD_AF(AF) do {                                                      \
    _Pragma("unroll")                                                         \
    for (int _k = 0; _k < 4; _k++)                                            \
        AF[_k] = *(const s8v*)&sA[sArow + _k * 32 + qd * 8];                  \
} while (0)

__global__ __launch_bounds__(256) void mega_kernel(
    const unsigned short* __restrict__ qpts,
    const unsigned short* __restrict__ pweT,
    const unsigned short* __restrict__ pe_b,
    const unsigned short* __restrict__ wqT,
    const unsigned short* __restrict__ waT,
    const unsigned short* __restrict__ ksT,
    const unsigned short* __restrict__ w1T,
    const unsigned short* __restrict__ w2T,
    const unsigned short* __restrict__ bq,
    const unsigned short* __restrict__ bo,
    const unsigned short* __restrict__ b1,
    const unsigned short* __restrict__ b2,
    const unsigned short* __restrict__ pw1T,
    const unsigned short* __restrict__ pb1,
    const unsigned short* __restrict__ pw2,
    const unsigned short* __restrict__ pb2,
    void* __restrict__ outv, const int* __restrict__ flag)
{
    __shared__ __align__(16) unsigned short sA[64 * LDA];   // 17408 B
    __shared__ __align__(16) float biasAll[12 * 128];       // 6144 B
    __shared__ __align__(16) float pebs[128];
    __shared__ __align__(16) float pb1s[64];
    __shared__ float w2s[192];
    __shared__ float pb2s[3];

    int t = threadIdx.x;
    int wvi = t >> 6, ln = t & 63, qd = ln >> 4, l16 = ln & 15;
    int qd4 = qd * 4;
    int row0 = blockIdx.x * 64;
    int rA0 = wvi * 16 + l16;        // this lane's row (within block)
    int sArow = rA0 * LDA;

    // ===== one-time staging =====
    for (int i = t; i < 1536; i += 256) {
        int l = i >> 9, rem = i & 511, which = rem >> 7, c = rem & 127;
        const unsigned short* bsrc = (which == 0) ? bq : (which == 1) ? bo
                                   : (which == 2) ? b1 : b2;
        biasAll[i] = b2f(bsrc[l * 128 + c]);
    }
    if (t < 128) pebs[t] = b2f(pe_b[t]);
    if (t < 64)  pb1s[t] = b2f(pb1[t]);
    if (t < 192) w2s[t] = b2f(pw2[t]);
    if (t < 3)   pb2s[t] = b2f(pb2[t]);
    __syncthreads();     // barrier #1 (the only one before the tail)

    float hres[8][4];    // fp32 residual: features nt*16+qd*4+i of row rA0

    // ===== encode via MFMA: h = sin(feats @ pe_w + pe_b) =====
    // A: pe_wT frags [n][32]; B: this lane's row feats (k = qd*8+j)
    {
        unsigned pq = *(const unsigned*)(qpts + (size_t)(row0 + rA0) * 2);
        s8v ae;
        {
            float f8[8]; feats8(pq, qd, f8);
            unsigned* au = (unsigned*)&ae;
            #pragma unroll
            for (int jj = 0; jj < 4; jj++) au[jj] = pk_bf16(f8[2 * jj], f8[2 * jj + 1]);
        }
        const unsigned short* pb = pweT + l16 * 32 + qd * 8;
        #pragma unroll
        for (int nt = 0; nt < 8; nt++) {
            s8v aw = *(const s8v*)(pb + nt * 512);
            f4v x = {0.f, 0.f, 0.f, 0.f};
            x = MFMA_BF16(aw, ae, x, 0, 0, 0);
            float4 bb = *(const float4*)&pebs[nt * 16 + qd4];
            float h0 = __sinf(x[0] + bb.x);
            float h1 = __sinf(x[1] + bb.y);
            float h2 = __sinf(x[2] + bb.z);
            float h3 = __sinf(x[3] + bb.w);
            hres[nt][0] = h0; hres[nt][1] = h1;
            hres[nt][2] = h2; hres[nt][3] = h3;
            uint2 pk; pk.x = pk_bf16(h0, h1); pk.y = pk_bf16(h2, h3);
            *(uint2*)&sA[sArow + nt * 16 + qd4] = pk;
        }
    }

    s8v af[4];

    // ===== 3 transformer layers (no barriers: each wave owns its 16 rows) =====
    for (int l = 0; l < 3; l++) {
        const float* bql = &biasAll[(l * 4 + 0) * 128];
        const float* bol = &biasAll[(l * 4 + 1) * 128];
        const float* b1l = &biasAll[(l * 4 + 2) * 128];
        const float* b2l = &biasAll[(l * 4 + 3) * 128];

        // mm1: qh = (h @ Wq + bq)^2 -> sA
        LOAD_AF(af);   // h
        RUN_MM(af, wqT + l * 16384, {
            float4 bb = *(const float4*)&bql[nt * 16 + qd4];
            float v0 = x[0] + bb.x, v1 = x[1] + bb.y;
            float v2 = x[2] + bb.z, v3 = x[3] + bb.w;
            uint2 pk; pk.x = pk_bf16(v0 * v0, v1 * v1); pk.y = pk_bf16(v2 * v2, v3 * v3);
            *(uint2*)&sA[sArow + nt * 16 + qd4] = pk;
        });

        // den: d[h] = qh_row . ksum_h via swapped MFMA (A = ksT rows, B = qh).
        // C: col=l16 -> act row, row=qd*4+i -> ksT row (heads live at qd==0).
        LOAD_AF(af);   // qh
        {
            f4v d = {0.f, 0.f, 0.f, 0.f};
            const unsigned short* kb = ksT + l * 2048 + l16 * 128 + qd * 8;
            #pragma unroll
            for (int ks = 0; ks < 4; ks++) {
                s8v kf = *(const s8v*)(kb + ks * 32);
                d = MFMA_BF16(kf, af[ks], d, 0, 0, 0);
            }
            // z_h for my row sits at lane l16 (qd==0 group), reg h; head of
            // k-slice ks == ks. Scale qh fragments in-register.
            #pragma unroll
            for (int ks = 0; ks < 4; ks++) {
                float z = 1.f / (__shfl(d[ks], l16) + 1e-6f);
                unsigned* u = (unsigned*)&af[ks];
                #pragma unroll
                for (int jj = 0; jj < 4; jj++) {
                    unsigned w = u[jj];
                    float lo = __uint_as_float(w << 16) * z;
                    float hi = __uint_as_float(w & 0xffff0000u) * z;
                    u[jj] = pk_bf16(lo, hi);
                }
            }
        }

        // mm2: x = h + (z*qh) @ Wa + bo -> hres(fp32), sA(bf16)
        RUN_MM(af, waT + l * 16384, {
            float4 bb = *(const float4*)&bol[nt * 16 + qd4];
            float v0 = hres[nt][0] + x[0] + bb.x;
            float v1 = hres[nt][1] + x[1] + bb.y;
            float v2 = hres[nt][2] + x[2] + bb.z;
            float v3 = hres[nt][3] + x[3] + bb.w;
            hres[nt][0] = v0; hres[nt][1] = v1;
            hres[nt][2] = v2; hres[nt][3] = v3;
            uint2 pk; pk.x = pk_bf16(v0, v1); pk.y = pk_bf16(v2, v3);
            *(uint2*)&sA[sArow + nt * 16 + qd4] = pk;
        });

        // mm3: t = gelu(x @ W1 + b1) -> sA
        LOAD_AF(af);   // x
        RUN_MM(af, w1T + l * 16384, {
            float4 bb = *(const float4*)&b1l[nt * 16 + qd4];
            uint2 pk;
            pk.x = pk_bf16(gelu_t(x[0] + bb.x), gelu_t(x[1] + bb.y));
            pk.y = pk_bf16(gelu_t(x[2] + bb.z), gelu_t(x[3] + bb.w));
            *(uint2*)&sA[sArow + nt * 16 + qd4] = pk;
        });

        // mm4: h_new = x + t @ W2 + b2 -> hres, sA
        LOAD_AF(af);   // t
        RUN_MM(af, w2T + l * 16384, {
            float4 bb = *(const float4*)&b2l[nt * 16 + qd4];
            float v0 = hres[nt][0] + x[0] + bb.x;
            float v1 = hres[nt][1] + x[1] + bb.y;
            float v2 = hres[nt][2] + x[2] + bb.z;
            float v3 = hres[nt][3] + x[3] + bb.w;
            hres[nt][0] = v0; hres[nt][1] = v1;
            hres[nt][2] = v2; hres[nt][3] = v3;
            uint2 pk; pk.x = pk_bf16(v0, v1); pk.y = pk_bf16(v2, v3);
            *(uint2*)&sA[sArow + nt * 16 + qd4] = pk;
        });
    }

    // ===== final projector: out = gelu(h @ pw1 + pb1) @ pw2 + pb2 =====
    {
        LOAD_AF(af);   // h final
        float* sAf = (float*)sA;   // [64][68] fp32 view (row = 272B = LDA)
        const unsigned short* base = pw1T + l16 * 128 + qd * 8;
        #pragma unroll
        for (int p = 0; p < 2; p++) {
            s8v cA[4], cB[4];
            #pragma unroll
            for (int ks = 0; ks < 4; ks++) {
                cA[ks] = *(const s8v*)(base + (p * 2) * 2048 + ks * 32);
                cB[ks] = *(const s8v*)(base + (p * 2 + 1) * 2048 + ks * 32);
            }
            f4v x0 = {0.f,0.f,0.f,0.f}, x1 = {0.f,0.f,0.f,0.f};
            #pragma unroll
            for (int ks = 0; ks < 4; ks++) {
                x0 = MFMA_BF16(cA[ks], af[ks], x0, 0, 0, 0);
                x1 = MFMA_BF16(cB[ks], af[ks], x1, 0, 0, 0);
            }
            int n0 = (p * 2) * 16 + qd4, n1 = (p * 2 + 1) * 16 + qd4;
            float4 bA = *(const float4*)&pb1s[n0];
            float4 bB = *(const float4*)&pb1s[n1];
            *(float4*)&sAf[rA0 * 68 + n0] = make_float4(
                gelu_t(x0[0] + bA.x), gelu_t(x0[1] + bA.y),
                gelu_t(x0[2] + bA.z), gelu_t(x0[3] + bA.w));
            *(float4*)&sAf[rA0 * 68 + n1] = make_float4(
                gelu_t(x1[0] + bB.x), gelu_t(x1[1] + bB.y),
                gelu_t(x1[2] + bB.z), gelu_t(x1[3] + bB.w));
        }
    }
    __syncthreads();   // barrier #2: cross-wave read below

    {
        const float* sAf = (const float*)sA;
        if (t < 192) {
            int r = t / 3, c = t - r * 3;
            float s = pb2s[c];
            #pragma unroll
            for (int jj = 0; jj < 16; jj++) {
                float4 v = *(const float4*)&sAf[r * 68 + jj * 4];
                s += v.x * w2s[(jj * 4 + 0) * 3 + c] + v.y * w2s[(jj * 4 + 1) * 3 + c]
                   + v.z * w2s[(jj * 4 + 2) * 3 + c] + v.w * w2s[(jj * 4 + 3) * 3 + c];
            }
            size_t o = (size_t)(row0 + r) * 3 + c;
            if (*flag) ((float*)outv)[o] = s;
            else       ((unsigned short*)outv)[o] = f2b(s);
        }
    }
}

// ---------- launch ----------
extern "C" void kernel_launch(void* const* d_in, const int* in_sizes, int n_in,
                              void* d_out, int out_size, void* d_ws, size_t ws_size,
                              hipStream_t stream) {
    const int N = in_sizes[0] / 2;   // 262144
    const int M = in_sizes[1] / 2;   // 4096

    ConvArgs ca;
    int total = 0;
    for (int i = 0; i < 22; i++) { ca.p[i] = d_in[i]; ca.off[i] = total; total += in_sizes[i]; }
    ca.off[22] = total;

    float* ws = (float*)d_ws;
    int* flag = (int*)ws;
    unsigned short* canon = (unsigned short*)(ws + 16);
    size_t canonF = ((size_t)(total + 1) / 2 + 15) & ~(size_t)15;
    float* b_enc = ws + 16 + canonF;                       // M*128
    float* khb   = b_enc + (size_t)M * 128;                // 12*M*32
    float* vhb   = khb + (size_t)12 * M * 32;              // 12*M*32
    float* kvs   = vhb + (size_t)12 * M * 32;              // 12288
    float* kss   = kvs + 12288;                            // 384
    unsigned short* wqT  = (unsigned short*)(kss + 384);   // 3*16384
    unsigned short* waT  = wqT + 49152;
    unsigned short* w1T  = waT + 49152;
    unsigned short* w2T  = w1T + 49152;
    unsigned short* ksT  = w2T + 49152;                    // 3*2048
    unsigned short* pw1T = ksT + 6144;                     // 8192
    unsigned short* pweT = pw1T + 8192;                    // 4096

    const unsigned short* c_qpts = canon + ca.off[0];
    const unsigned short* c_bpts = canon + ca.off[1];
    const unsigned short* c_pew  = canon + ca.off[2];
    const unsigned short* c_peb  = canon + ca.off[3];
    const unsigned short* c_bpew = canon + ca.off[4];
    const unsigned short* c_bpeb = canon + ca.off[5];
    const unsigned short* c_Wq   = canon + ca.off[6];
    const unsigned short* c_bq   = canon + ca.off[7];
    const unsigned short* c_Wk   = canon + ca.off[8];
    const unsigned short* c_bk   = canon + ca.off[9];
    const unsigned short* c_Wv   = canon + ca.off[10];
    const unsigned short* c_bv   = canon + ca.off[11];
    const unsigned short* c_Wo   = canon + ca.off[12];
    const unsigned short* c_bo   = canon + ca.off[13];
    const unsigned short* c_W1   = canon + ca.off[14];
    const unsigned short* c_b1   = canon + ca.off[15];
    const unsigned short* c_W2   = canon + ca.off[16];
    const unsigned short* c_b2   = canon + ca.off[17];
    const unsigned short* c_pw1  = canon + ca.off[18];
    const unsigned short* c_pb1  = canon + ca.off[19];
    const unsigned short* c_pw2  = canon + ca.off[20];
    const unsigned short* c_pb2  = canon + ca.off[21];

    convert_kernel<<<(total + 255) / 256, 256, 0, stream>>>(
        ca, (const unsigned short*)d_in[2], flag, canon, total);

    encode_kernel<<<M / 8, 256, 0, stream>>>(c_bpts, c_bpew, c_bpeb, b_enc);
    khvh_kernel<<<(12 * M * 32) / 256, 256, 0, stream>>>(
        b_enc, c_Wk, c_bk, c_Wv, c_bv, khb, vhb, kvs);
    kvred_kernel<<<96, 1024, 0, stream>>>(khb, vhb, kvs, kss);
    prep_kernel<<<215040 / 256, 256, 0, stream>>>(
        c_Wq, c_W1, c_W2, c_pw1, kvs, kss, c_Wo, c_pew,
        wqT, w1T, w2T, pw1T, waT, ksT, pweT);

    mega_kernel<<<N / 64, 256, 0, stream>>>(
        c_qpts, pweT, c_peb, wqT, waT, ksT, w1T, w2T,
        c_bq, c_bo, c_b1, c_b2, pw1T, c_pb1, c_pw2, c_pb2, d_out, flag);
}

// Round 3
// 421.362 us; speedup vs baseline: 2.2186x; 2.2186x over previous
//
#include <hip/hip_runtime.h>
#include <hip/hip_bf16.h>

// ---------- helpers ----------
__device__ __forceinline__ float b2f(unsigned short u) {
    return __uint_as_float(((unsigned)u) << 16);
}
__device__ __forceinline__ unsigned short f2b(float f) {
    __hip_bfloat16 h = __float2bfloat16(f);
    return *reinterpret_cast<unsigned short*>(&h);
}
// cheap round-to-nearest-even bf16 (no NaN inputs in this pipeline)
__device__ __forceinline__ unsigned short f2b_rne(float f) {
    unsigned u = __float_as_uint(f);
    return (unsigned short)((u + 0x7fffu + ((u >> 16) & 1u)) >> 16);
}
// pack two f32 -> packed 2x bf16 (RNE), single VALU op
__device__ __forceinline__ unsigned pk_bf16(float lo, float hi) {
    unsigned r;
    asm("v_cvt_pk_bf16_f32 %0, %1, %2" : "=v"(r) : "v"(lo), "v"(hi));
    return r;
}
__device__ __forceinline__ float sigm(float v) {
    return 1.f / (1.f + __expf(-v));
}
// tanh-approx GELU (max abs dev from exact ~1e-3; post-W2 contribution <1e-3)
__device__ __forceinline__ float gelu_t(float x) {
    float y = 0.7978845608f * (x + 0.044715f * x * x * x);
    float e = __expf(2.f * y);
    float th = 1.f - 2.f / (e + 1.f);
    return 0.5f * x * (1.f + th);
}

typedef __attribute__((ext_vector_type(8))) short s8v;   // 8 bf16 (4 VGPRs)
typedef __attribute__((ext_vector_type(4))) float f4v;   // 4 fp32 acc

#define MFMA_BF16 __builtin_amdgcn_mfma_f32_16x16x32_bf16

// ---------- 15-feature map (full, for the boundary path) ----------
__device__ __forceinline__ void make_feats(const unsigned short* __restrict__ qpts,
                                           int r, float* __restrict__ f) {
    unsigned pq = *(const unsigned*)(qpts + (size_t)r * 2);
    float x0 = b2f((unsigned short)(pq & 0xffff));
    float x1 = b2f((unsigned short)(pq >> 16));
    const float PI = 3.14159265358979323846f;
    float a0 = x0 - 1.5f, a1 = x1 - 1.5f, c0 = x0 - 4.5f, c1 = x1 - 4.5f;
    f[0] = x0;        f[1] = x1;
    f[2] = x0 * x0;   f[3] = x1 * x1;
    f[4] = a0 * a0;   f[5] = a1 * a1;
    f[6] = c0 * c0;   f[7] = c1 * c1;
    f[8] = sigm(x0);  f[9] = sigm(x1);
    f[10] = sigm(a0); f[11] = sigm(a1);
    f[12] = sigm(c0); f[13] = sigm(c1);
    f[14] = a0;       f[15] = a1;
    f[16] = c0;       f[17] = c1;
    f[18] = __sinf(PI * x0);          f[19] = __sinf(PI * x1);
    f[20] = __cosf(PI * x0);          f[21] = __cosf(PI * x1);
    f[22] = __sinf(PI * 0.25f * x0);  f[23] = __sinf(PI * 0.25f * x1);
    f[24] = __cosf(PI * 0.25f * x0);  f[25] = __cosf(PI * 0.25f * x1);
    f[26] = __sinf(PI * 0.5f * x0);   f[27] = __sinf(PI * 0.5f * x1);
    f[28] = __cosf(PI * 0.5f * x0);   f[29] = __cosf(PI * 0.5f * x1);
}

// 8 features for k = qd*8 .. qd*8+7 (quad-split of the 30-vector, 30/31 -> 0)
__device__ __forceinline__ void feats8(unsigned pq, int qd, float* __restrict__ f8) {
    float x0 = b2f((unsigned short)(pq & 0xffff));
    float x1 = b2f((unsigned short)(pq >> 16));
    const float PI = 3.14159265358979323846f;
    float a0 = x0 - 1.5f, a1 = x1 - 1.5f, c0 = x0 - 4.5f, c1 = x1 - 4.5f;
    if (qd == 0) {
        f8[0] = x0;      f8[1] = x1;
        f8[2] = x0 * x0; f8[3] = x1 * x1;
        f8[4] = a0 * a0; f8[5] = a1 * a1;
        f8[6] = c0 * c0; f8[7] = c1 * c1;
    } else if (qd == 1) {
        f8[0] = sigm(x0); f8[1] = sigm(x1);
        f8[2] = sigm(a0); f8[3] = sigm(a1);
        f8[4] = sigm(c0); f8[5] = sigm(c1);
        f8[6] = a0;       f8[7] = a1;
    } else if (qd == 2) {
        f8[0] = c0; f8[1] = c1;
        f8[2] = __sinf(PI * x0);          f8[3] = __sinf(PI * x1);
        f8[4] = __cosf(PI * x0);          f8[5] = __cosf(PI * x1);
        f8[6] = __sinf(PI * 0.25f * x0);  f8[7] = __sinf(PI * 0.25f * x1);
    } else {
        f8[0] = __cosf(PI * 0.25f * x0);  f8[1] = __cosf(PI * 0.25f * x1);
        f8[2] = __sinf(PI * 0.5f * x0);   f8[3] = __sinf(PI * 0.5f * x1);
        f8[4] = __cosf(PI * 0.5f * x0);   f8[5] = __cosf(PI * 0.5f * x1);
        f8[6] = 0.f;                      f8[7] = 0.f;
    }
}

// ---------- canonicalize all inputs to bf16 (embedded dtype detection) ----------
struct ConvArgs {
    const void* p[22];
    int off[23];
};

__global__ __launch_bounds__(256) void convert_kernel(
    ConvArgs a, const unsigned short* __restrict__ pe_w_raw,
    int* __restrict__ flag, unsigned short* __restrict__ canon, int total)
{
    __shared__ int cnt;
    if (threadIdx.x == 0) cnt = 0;
    __syncthreads();
    float v = b2f(pe_w_raw[threadIdx.x * 2]);
    if (!(fabsf(v) < 1.0f)) atomicAdd(&cnt, 1);
    __syncthreads();
    int isf32 = (cnt >= 16) ? 1 : 0;
    if (blockIdx.x == 0 && threadIdx.x == 0) *flag = isf32;

    int g = blockIdx.x * 256 + threadIdx.x;
    if (g >= total) return;
    int s = 0;
    #pragma unroll
    for (int i = 1; i < 23; i++) s += (g >= a.off[i]) ? 1 : 0;
    int local = g - a.off[s];
    unsigned short r;
    if (isf32) r = f2b(((const float*)a.p[s])[local]);
    else       r = ((const unsigned short*)a.p[s])[local];
    canon[g] = r;
}

// ---------- boundary positional encoding (M rows, fp32 out) ----------
__global__ __launch_bounds__(256) void encode_kernel(
    const unsigned short* __restrict__ pts,
    const unsigned short* __restrict__ w,
    const unsigned short* __restrict__ b,
    float* __restrict__ out)
{
    __shared__ __align__(16) float wsm[30 * 128];
    __shared__ float bs[128];
    int t = threadIdx.x;
    for (int i = t; i < 30 * 128; i += 256) wsm[i] = b2f(w[i]);
    if (t < 128) bs[t] = b2f(b[t]);
    __syncthreads();

    int r = blockIdx.x * 8 + (t >> 5);
    int j = t & 31;
    float f[30];
    make_feats(pts, r, f);
    float s0 = bs[j * 4 + 0], s1 = bs[j * 4 + 1], s2 = bs[j * 4 + 2], s3 = bs[j * 4 + 3];
    #pragma unroll
    for (int ff = 0; ff < 30; ff++) {
        float4 wv = *(const float4*)&wsm[ff * 128 + j * 4];
        float fv = f[ff];
        s0 += fv * wv.x; s1 += fv * wv.y; s2 += fv * wv.z; s3 += fv * wv.w;
    }
    *(float4*)&out[(size_t)r * 128 + j * 4] =
        make_float4(__sinf(s0), __sinf(s1), __sinf(s2), __sinf(s3));
}

// ---------- boundary k/v heads (+ zeroing of kv/ks accumulators) ----------
__global__ __launch_bounds__(256) void khvh_kernel(
    const float* __restrict__ benc,
    const unsigned short* __restrict__ Wk, const unsigned short* __restrict__ bk,
    const unsigned short* __restrict__ Wv, const unsigned short* __restrict__ bv,
    float* __restrict__ kh, float* __restrict__ vh, float* __restrict__ kvz)
{
    int g = blockIdx.x * 256 + threadIdx.x;
    if (g < 12672) kvz[g] = 0.f;   // kvs(12288) + kss(384), contiguous
    int lh = g >> 17;
    int rem = g & 131071;
    int m = rem >> 5;
    int dd = rem & 31;
    const unsigned short* wk = Wk + lh * 4096 + dd;
    const unsigned short* wv = Wv + lh * 4096 + dd;
    const float* br = benc + (size_t)m * 128;
    float ka = 0.f, va = 0.f;
    #pragma unroll 8
    for (int c = 0; c < 128; c++) {
        float bb = br[c];
        ka += bb * b2f(wk[c * 32]);
        va += bb * b2f(wv[c * 32]);
    }
    ka += b2f(bk[lh * 32 + dd]); ka = ka * ka;
    va += b2f(bv[lh * 32 + dd]);
    kh[g] = ka; vh[g] = va;
}

// ---------- reduce over boundary points: kvsum[lh][d][e], ksum[lh][d] ----------
__global__ __launch_bounds__(1024) void kvred_kernel(
    const float* __restrict__ kh, const float* __restrict__ vh,
    float* __restrict__ kvsum, float* __restrict__ ksum)
{
    __shared__ float khs[1024];
    __shared__ float vhs[1024];
    int t = threadIdx.x;
    int lh = blockIdx.x >> 3;
    int part = blockIdx.x & 7;
    int dd = t >> 5, ee = t & 31;
    float kva = 0.f, ksa = 0.f;
    for (int ch = 0; ch < 16; ch++) {
        int base = lh * 131072 + (part * 16 + ch) * 1024;
        khs[t] = kh[base + t];
        vhs[t] = vh[base + t];
        __syncthreads();
        #pragma unroll
        for (int i = 0; i < 32; i++) {
            float kk = khs[i * 32 + dd];
            kva += kk * vhs[i * 32 + ee];
            ksa += kk;
        }
        __syncthreads();
    }
    atomicAdd(&kvsum[lh * 1024 + dd * 32 + ee], kva);
    if (ee == 0) atomicAdd(&ksum[lh * 32 + dd], ksa);
}

// ---------- prep: transposes + Wa fold + Ks + padded pe_wT, one kernel ----------
__global__ __launch_bounds__(256) void prep_kernel(
    const unsigned short* __restrict__ Wq, const unsigned short* __restrict__ W1,
    const unsigned short* __restrict__ W2, const unsigned short* __restrict__ pw1,
    const float* __restrict__ kvs, const float* __restrict__ kss,
    const unsigned short* __restrict__ Wo, const unsigned short* __restrict__ pe_w,
    unsigned short* __restrict__ wqT, unsigned short* __restrict__ w1T,
    unsigned short* __restrict__ w2T, unsigned short* __restrict__ pw1T,
    unsigned short* __restrict__ waT, unsigned short* __restrict__ ksT,
    unsigned short* __restrict__ pweT)
{
    int g = blockIdx.x * 256 + threadIdx.x;
    if (g < 49152) {
        int l = g >> 14, r = g & 16383, n = r >> 7, k = r & 127;
        wqT[g] = Wq[((l * 4 + (n >> 5)) * 128 + k) * 32 + (n & 31)];  // head-interleaved cols
    } else if (g < 98304) {
        int q = g - 49152; int l = q >> 14, r = q & 16383, n = r >> 7, k = r & 127;
        w1T[q] = W1[(l * 128 + k) * 128 + n];
    } else if (g < 147456) {
        int q = g - 98304; int l = q >> 14, r = q & 16383, n = r >> 7, k = r & 127;
        w2T[q] = W2[(l * 128 + k) * 128 + n];
    } else if (g < 155648) {
        int q = g - 147456; int n = q >> 7, k = q & 127;
        pw1T[q] = pw1[k * 64 + n];
    } else if (g < 204800) {
        int q = g - 155648; int l = q >> 14, r = q & 16383, n = r >> 7, k = r & 127;
        int hk = k >> 5, dk = k & 31;
        const float* kvp = kvs + (l * 4 + hk) * 1024 + dk * 32;
        const unsigned short* wop = Wo + (size_t)(l * 128 + hk * 32) * 128 + n;
        float s = 0.f;
        #pragma unroll 8
        for (int j = 0; j < 32; j++) s += kvp[j] * b2f(wop[j * 128]);
        waT[q] = f2b(s);
    } else if (g < 210944) {
        int q = g - 204800; int l = q >> 11, r = q & 2047, n = r >> 7, k = r & 127;
        unsigned short v = 0;
        if (n < 4 && (k >> 5) == n) v = f2b(kss[(l * 4 + n) * 32 + (k & 31)]);
        ksT[q] = v;
    } else if (g < 215040) {
        int q = g - 210944; int n = q >> 5, k = q & 31;   // pe_wT [128][32], k>=30 -> 0
        pweT[q] = (k < 30) ? pe_w[k * 128 + n] : (unsigned short)0;
    }
}

// ---------- the fused mega kernel: encode + 3 layers + projector ----------
// ROUND-3 restructure (post-mortem of R1: per-wave L2 weight streaming is the
// stall; 16 rows/wave halved latency hiding and doubled traffic -> 776us):
//  * 128 rows/block, 4 waves, 32 rows/wave (restores 4 MFMA chains/phase and
//    halves per-row weight traffic).
//  * Weights staged in LDS (wbuf, 32KB) ONCE PER BLOCK per matmul, shared by
//    all 4 waves: weight traffic 8x down vs R1; frag reads become
//    ds_read_b128 (low latency) instead of L2 global loads.
//  * wbuf written PRE-SWIZZLED (XOR byte bits 4-6 with row&7, an involution)
//    so swizzled frag reads are bank-conflict-free-equivalent (the m201/m173
//    both-sides-or-neither rule, reg-staged so dest can be swizzled directly).
//  * sA: no pad (LDA=128), same XOR swizzle -> epilogue uint2 writes spread
//    over 16 banks (was 8 at LDA=136), LOAD_AF reads conflict-free.
//  * den/z-scale is register-only and placed INSIDE the waT staging window so
//    staging latency hides under it.
//  * Swapped MFMA operands + pk_bf16 epilogues kept from R1 (VALU -15%).
// LDS total ~73KB -> 2 blocks/CU (8 waves/CU). Est ~170 VGPR.

// stage one [n][k] bf16 weight matrix into wbuf, pre-swizzled. ITERS = KB/2.
template<int ITERS>
__device__ __forceinline__ void stage_w(const unsigned short* __restrict__ g,
                                        unsigned short* __restrict__ wbuf, int t) {
    #pragma unroll
    for (int i = 0; i < ITERS; i++) {
        int lin = (i * 256 + t) * 16;                  // byte offset, coalesced
        s8v v = *(const s8v*)((const char*)g + lin);
        int sw = lin ^ ((((lin >> 8)) & 7) << 4);      // row&7 XOR into bits 4-6
        *(s8v*)((char*)wbuf + sw) = v;
    }
}

// swizzled weight-fragment read: ntile nt (16 n-cols), k-slice k, lane (qd,l16)
__device__ __forceinline__ s8v wfrag(const unsigned short* __restrict__ wbuf,
                                     int nt, int k, int l16, int qd) {
    int lin = (nt << 12) + (l16 << 8) + (k << 6) + (qd << 4);
    return *(const s8v*)((const char*)wbuf + (lin ^ ((l16 & 7) << 4)));
}

// dual-ntile, dual-rowtile matmul over a 128x128 [n][k] weight matrix in wbuf.
// Epilogue sees: nt (0..7), tile (0/1), x (f4v) = features nt*16+qd*4+i of
// row rA0 + tile*16.
#define RUN_MM_L(AF, ...) do {                                                \
    _Pragma("unroll")                                                         \
    for (int _p = 0; _p < 4; _p++) {                                          \
        f4v _x0 = {0.f,0.f,0.f,0.f}, _x1 = {0.f,0.f,0.f,0.f};                 \
        f4v _y0 = {0.f,0.f,0.f,0.f}, _y1 = {0.f,0.f,0.f,0.f};                 \
        _Pragma("unroll")                                                     \
        for (int _k = 0; _k < 4; _k++) {                                      \
            s8v _wa = wfrag(wbuf, _p * 2,     _k, l16, qd);                   \
            s8v _wb = wfrag(wbuf, _p * 2 + 1, _k, l16, qd);                   \
            _x0 = MFMA_BF16(_wa, AF[0][_k], _x0, 0, 0, 0);                    \
            _x1 = MFMA_BF16(_wa, AF[1][_k], _x1, 0, 0, 0);                    \
            _y0 = MFMA_BF16(_wb, AF[0][_k], _y0, 0, 0, 0);                    \
            _y1 = MFMA_BF16(_wb, AF[1][_k], _y1, 0, 0, 0);                    \
        }                                                                     \
        { const int nt = _p * 2;     const int tile = 0; const f4v x = _x0; __VA_ARGS__ } \
        { const int nt = _p * 2;     const int tile = 1; const f4v x = _x1; __VA_ARGS__ } \
        { const int nt = _p * 2 + 1; const int tile = 0; const f4v x = _y0; __VA_ARGS__ } \
        { const int nt = _p * 2 + 1; const int tile = 1; const f4v x = _y1; __VA_ARGS__ } \
    }                                                                         \
} while (0)

// load activation fragments for this wave's two 16-row tiles from swizzled sA
#define LOAD_AF(AF) do {                                                      \
    _Pragma("unroll")                                                         \
    for (int _t2 = 0; _t2 < 2; _t2++)                                         \
        _Pragma("unroll")                                                     \
        for (int _k = 0; _k < 4; _k++)                                        \
            AF[_t2][_k] = *(const s8v*)(sAB + (rA0 + _t2 * 16) * 256 +        \
                                        (((_k * 64) + (qd * 16)) ^ swzA));    \
} while (0)

__global__ __launch_bounds__(256) void mega_kernel(
    const unsigned short* __restrict__ qpts,
    const unsigned short* __restrict__ pweT,
    const unsigned short* __restrict__ pe_b,
    const unsigned short* __restrict__ wqT,
    const unsigned short* __restrict__ waT,
    const unsigned short* __restrict__ ksT,
    const unsigned short* __restrict__ w1T,
    const unsigned short* __restrict__ w2T,
    const unsigned short* __restrict__ bq,
    const unsigned short* __restrict__ bo,
    const unsigned short* __restrict__ b1,
    const unsigned short* __restrict__ b2,
    const unsigned short* __restrict__ pw1T,
    const unsigned short* __restrict__ pb1,
    const unsigned short* __restrict__ pw2,
    const unsigned short* __restrict__ pb2,
    void* __restrict__ outv, const int* __restrict__ flag)
{
    __shared__ __align__(16) unsigned short sA[128 * 128];   // 32768 B, swizzled
    __shared__ __align__(16) unsigned short wbuf[16384];     // 32768 B, swizzled
    __shared__ __align__(16) float biasAll[12 * 128];        // 6144 B
    __shared__ __align__(16) float pebs[128];
    __shared__ __align__(16) float pb1s[64];
    __shared__ float w2s[192];
    __shared__ float pb2s[3];

    int t = threadIdx.x;
    int wvi = t >> 6, ln = t & 63, qd = ln >> 4, l16 = ln & 15;
    int qd4 = qd * 4;
    int row0 = blockIdx.x * 128;
    int rA0 = wvi * 32 + l16;          // lane's row, tile 0 (tile 1: +16)
    const int swzA = (l16 & 7) << 4;   // sA byte-XOR for this lane's rows
    char* sAB = (char*)sA;

    // ===== one-time staging =====
    for (int i = t; i < 1536; i += 256) {
        int l = i >> 9, rem = i & 511, which = rem >> 7, c = rem & 127;
        const unsigned short* bsrc = (which == 0) ? bq : (which == 1) ? bo
                                   : (which == 2) ? b1 : b2;
        biasAll[i] = b2f(bsrc[l * 128 + c]);
    }
    if (t < 128) pebs[t] = b2f(pe_b[t]);
    if (t < 64)  pb1s[t] = b2f(pb1[t]);
    if (t < 192) w2s[t] = b2f(pw2[t]);
    if (t < 3)   pb2s[t] = b2f(pb2[t]);
    __syncthreads();

    // stage first weight matrix; encode runs inside this window
    stage_w<8>(wqT, wbuf, t);

    float hres[2][8][4];   // fp32 residual: [tile][nt][i]

    // ===== encode via MFMA: h = sin(feats @ pe_w + pe_b) =====
    {
        unsigned pq0 = *(const unsigned*)(qpts + (size_t)(row0 + rA0) * 2);
        unsigned pq1 = *(const unsigned*)(qpts + (size_t)(row0 + rA0 + 16) * 2);
        s8v ae0, ae1;
        {
            float f8[8]; feats8(pq0, qd, f8);
            unsigned* au = (unsigned*)&ae0;
            #pragma unroll
            for (int jj = 0; jj < 4; jj++) au[jj] = pk_bf16(f8[2 * jj], f8[2 * jj + 1]);
        }
        {
            float f8[8]; feats8(pq1, qd, f8);
            unsigned* au = (unsigned*)&ae1;
            #pragma unroll
            for (int jj = 0; jj < 4; jj++) au[jj] = pk_bf16(f8[2 * jj], f8[2 * jj + 1]);
        }
        const unsigned short* pb = pweT + l16 * 32 + qd * 8;
        #pragma unroll
        for (int nt = 0; nt < 8; nt++) {
            s8v aw = *(const s8v*)(pb + nt * 512);
            f4v x0 = {0.f, 0.f, 0.f, 0.f}, x1 = {0.f, 0.f, 0.f, 0.f};
            x0 = MFMA_BF16(aw, ae0, x0, 0, 0, 0);
            x1 = MFMA_BF16(aw, ae1, x1, 0, 0, 0);
            float4 bb = *(const float4*)&pebs[nt * 16 + qd4];
            float h0 = __sinf(x0[0] + bb.x), h1 = __sinf(x0[1] + bb.y);
            float h2 = __sinf(x0[2] + bb.z), h3 = __sinf(x0[3] + bb.w);
            hres[0][nt][0] = h0; hres[0][nt][1] = h1;
            hres[0][nt][2] = h2; hres[0][nt][3] = h3;
            uint2 pk0; pk0.x = pk_bf16(h0, h1); pk0.y = pk_bf16(h2, h3);
            *(uint2*)(sAB + rA0 * 256 + ((nt * 32 + qd * 8) ^ swzA)) = pk0;
            float g0 = __sinf(x1[0] + bb.x), g1 = __sinf(x1[1] + bb.y);
            float g2 = __sinf(x1[2] + bb.z), g3 = __sinf(x1[3] + bb.w);
            hres[1][nt][0] = g0; hres[1][nt][1] = g1;
            hres[1][nt][2] = g2; hres[1][nt][3] = g3;
            uint2 pk1; pk1.x = pk_bf16(g0, g1); pk1.y = pk_bf16(g2, g3);
            *(uint2*)(sAB + (rA0 + 16) * 256 + ((nt * 32 + qd * 8) ^ swzA)) = pk1;
        }
    }

    s8v af[2][4];

    // ===== 3 transformer layers =====
    for (int l = 0; l < 3; l++) {
        const float* bql = &biasAll[(l * 4 + 0) * 128];
        const float* bol = &biasAll[(l * 4 + 1) * 128];
        const float* b1l = &biasAll[(l * 4 + 2) * 128];
        const float* b2l = &biasAll[(l * 4 + 3) * 128];

        // mm1: qh = (h @ Wq + bq)^2 -> sA     (wbuf = wqT[l], staged)
        LOAD_AF(af);   // h
        __syncthreads();                 // wqT staged (l=0) / wbuf free->staged
        if (l > 0) { /* wbuf already holds wqT[l], staged at end of prev layer */ }
        RUN_MM_L(af, {
            float4 bb = *(const float4*)&bql[nt * 16 + qd4];
            float v0 = x[0] + bb.x, v1 = x[1] + bb.y;
            float v2 = x[2] + bb.z, v3 = x[3] + bb.w;
            uint2 pk; pk.x = pk_bf16(v0 * v0, v1 * v1); pk.y = pk_bf16(v2 * v2, v3 * v3);
            *(uint2*)(sAB + (rA0 + tile * 16) * 256 + ((nt * 32 + qd * 8) ^ swzA)) = pk;
        });

        // den window: load qh + ks frags, then stage waT while den computes
        LOAD_AF(af);   // qh (own rows, same wave -> no barrier needed)
        s8v kf[4];
        {
            const unsigned short* kb = ksT + l * 2048 + l16 * 128 + qd * 8;
            #pragma unroll
            for (int ks = 0; ks < 4; ks++) kf[ks] = *(const s8v*)(kb + ks * 32);
        }
        __syncthreads();                 // all waves done reading wqT from wbuf
        stage_w<8>(waT + l * 16384, wbuf, t);
        // den: register-only compute overlapping the staging
        #pragma unroll
        for (int tile = 0; tile < 2; tile++) {
            f4v d = {0.f, 0.f, 0.f, 0.f};
            #pragma unroll
            for (int ks = 0; ks < 4; ks++) d = MFMA_BF16(kf[ks], af[tile][ks], d, 0, 0, 0);
            #pragma unroll
            for (int ks = 0; ks < 4; ks++) {
                float z = 1.f / (__shfl(d[ks], l16) + 1e-6f);
                unsigned* u = (unsigned*)&af[tile][ks];
                #pragma unroll
                for (int jj = 0; jj < 4; jj++) {
                    unsigned w = u[jj];
                    float lo = __uint_as_float(w << 16) * z;
                    float hi = __uint_as_float(w & 0xffff0000u) * z;
                    u[jj] = pk_bf16(lo, hi);
                }
            }
        }
        __syncthreads();                 // waT staged

        // mm2: x = h + (z*qh) @ Wa + bo -> hres(fp32), sA(bf16)
        RUN_MM_L(af, {
            float4 bb = *(const float4*)&bol[nt * 16 + qd4];
            float v0 = hres[tile][nt][0] + x[0] + bb.x;
            float v1 = hres[tile][nt][1] + x[1] + bb.y;
            float v2 = hres[tile][nt][2] + x[2] + bb.z;
            float v3 = hres[tile][nt][3] + x[3] + bb.w;
            hres[tile][nt][0] = v0; hres[tile][nt][1] = v1;
            hres[tile][nt][2] = v2; hres[tile][nt][3] = v3;
            uint2 pk; pk.x = pk_bf16(v0, v1); pk.y = pk_bf16(v2, v3);
            *(uint2*)(sAB + (rA0 + tile * 16) * 256 + ((nt * 32 + qd * 8) ^ swzA)) = pk;
        });

        // mm3: t = gelu(x @ W1 + b1) -> sA
        LOAD_AF(af);   // x
        __syncthreads();                 // all waves done reading waT
        stage_w<8>(w1T + l * 16384, wbuf, t);
        __syncthreads();                 // w1T staged
        RUN_MM_L(af, {
            float4 bb = *(const float4*)&b1l[nt * 16 + qd4];
            uint2 pk;
            pk.x = pk_bf16(gelu_t(x[0] + bb.x), gelu_t(x[1] + bb.y));
            pk.y = pk_bf16(gelu_t(x[2] + bb.z), gelu_t(x[3] + bb.w));
            *(uint2*)(sAB + (rA0 + tile * 16) * 256 + ((nt * 32 + qd * 8) ^ swzA)) = pk;
        });

        // mm4: h_new = x + t @ W2 + b2 -> hres, sA
        LOAD_AF(af);   // t
        __syncthreads();                 // all waves done reading w1T
        stage_w<8>(w2T + l * 16384, wbuf, t);
        __syncthreads();                 // w2T staged
        RUN_MM_L(af, {
            float4 bb = *(const float4*)&b2l[nt * 16 + qd4];
            float v0 = hres[tile][nt][0] + x[0] + bb.x;
            float v1 = hres[tile][nt][1] + x[1] + bb.y;
            float v2 = hres[tile][nt][2] + x[2] + bb.z;
            float v3 = hres[tile][nt][3] + x[3] + bb.w;
            hres[tile][nt][0] = v0; hres[tile][nt][1] = v1;
            hres[tile][nt][2] = v2; hres[tile][nt][3] = v3;
            uint2 pk; pk.x = pk_bf16(v0, v1); pk.y = pk_bf16(v2, v3);
            *(uint2*)(sAB + (rA0 + tile * 16) * 256 + ((nt * 32 + qd * 8) ^ swzA)) = pk;
        });

        // stage next matmul's weights (wqT[l+1] or pw1T) behind this layer
        LOAD_AF(af);   // h_new (used by next mm1 / projector)
        __syncthreads();                 // all waves done reading w2T
        if (l < 2) stage_w<8>(wqT + (l + 1) * 16384, wbuf, t);
        else       stage_w<4>(pw1T, wbuf, t);
        // note: matching "staged" barrier is the one at the top of the next
        // mm1 (after its LOAD_AF) or before the projector below.
    }

    // ===== final projector: out = gelu(h @ pw1 + pb1) @ pw2 + pb2 =====
    __syncthreads();                     // pw1T staged
    {
        float* sAf = (float*)sA;         // fp32 view [128][64], own rows only
        const int fsw = (l16 & 7) << 1;  // float4-granule XOR for bank spread
        #pragma unroll
        for (int p = 0; p < 2; p++) {
            f4v y0 = {0.f,0.f,0.f,0.f}, y1 = {0.f,0.f,0.f,0.f};
            f4v y2 = {0.f,0.f,0.f,0.f}, y3 = {0.f,0.f,0.f,0.f};
            #pragma unroll
            for (int ks = 0; ks < 4; ks++) {
                s8v wA = wfrag(wbuf, p * 2,     ks, l16, qd);
                s8v wB = wfrag(wbuf, p * 2 + 1, ks, l16, qd);
                y0 = MFMA_BF16(wA, af[0][ks], y0, 0, 0, 0);
                y1 = MFMA_BF16(wA, af[1][ks], y1, 0, 0, 0);
                y2 = MFMA_BF16(wB, af[0][ks], y2, 0, 0, 0);
                y3 = MFMA_BF16(wB, af[1][ks], y3, 0, 0, 0);
            }
            int n0 = (p * 2) * 16 + qd4, n1 = (p * 2 + 1) * 16 + qd4;
            float4 bA = *(const float4*)&pb1s[n0];
            float4 bB = *(const float4*)&pb1s[n1];
            int f0 = ((p * 2) * 4 + qd) ^ fsw, f1 = ((p * 2 + 1) * 4 + qd) ^ fsw;
            *(float4*)&sAf[rA0 * 64 + f0 * 4] = make_float4(
                gelu_t(y0[0] + bA.x), gelu_t(y0[1] + bA.y),
                gelu_t(y0[2] + bA.z), gelu_t(y0[3] + bA.w));
            *(float4*)&sAf[(rA0 + 16) * 64 + f0 * 4] = make_float4(
                gelu_t(y1[0] + bA.x), gelu_t(y1[1] + bA.y),
                gelu_t(y1[2] + bA.z), gelu_t(y1[3] + bA.w));
            *(float4*)&sAf[rA0 * 64 + f1 * 4] = make_float4(
                gelu_t(y2[0] + bB.x), gelu_t(y2[1] + bB.y),
                gelu_t(y2[2] + bB.z), gelu_t(y2[3] + bB.w));
            *(float4*)&sAf[(rA0 + 16) * 64 + f1 * 4] = make_float4(
                gelu_t(y3[0] + bB.x), gelu_t(y3[1] + bB.y),
                gelu_t(y3[2] + bB.z), gelu_t(y3[3] + bB.w));
        }
    }
    __syncthreads();   // cross-wave read below

    {
        const float* sAf = (const float*)sA;
        for (int idx = t; idx < 384; idx += 256) {
            int r = idx / 3, c = idx - r * 3;
            int rsw = (r & 7) << 1;
            float s = pb2s[c];
            #pragma unroll
            for (int jj = 0; jj < 16; jj++) {
                float4 v = *(const float4*)&sAf[r * 64 + (jj ^ rsw) * 4];
                s += v.x * w2s[(jj * 4 + 0) * 3 + c] + v.y * w2s[(jj * 4 + 1) * 3 + c]
                   + v.z * w2s[(jj * 4 + 2) * 3 + c] + v.w * w2s[(jj * 4 + 3) * 3 + c];
            }
            size_t o = (size_t)(row0 + r) * 3 + c;
            if (*flag) ((float*)outv)[o] = s;
            else       ((unsigned short*)outv)[o] = f2b(s);
        }
    }
}

// ---------- launch ----------
extern "C" void kernel_launch(void* const* d_in, const int* in_sizes, int n_in,
                              void* d_out, int out_size, void* d_ws, size_t ws_size,
                              hipStream_t stream) {
    const int N = in_sizes[0] / 2;   // 262144
    const int M = in_sizes[1] / 2;   // 4096

    ConvArgs ca;
    int total = 0;
    for (int i = 0; i < 22; i++) { ca.p[i] = d_in[i]; ca.off[i] = total; total += in_sizes[i]; }
    ca.off[22] = total;

    float* ws = (float*)d_ws;
    int* flag = (int*)ws;
    unsigned short* canon = (unsigned short*)(ws + 16);
    size_t canonF = ((size_t)(total + 1) / 2 + 15) & ~(size_t)15;
    float* b_enc = ws + 16 + canonF;                       // M*128
    float* khb   = b_enc + (size_t)M * 128;                // 12*M*32
    float* vhb   = khb + (size_t)12 * M * 32;              // 12*M*32
    float* kvs   = vhb + (size_t)12 * M * 32;              // 12288
    float* kss   = kvs + 12288;                            // 384
    unsigned short* wqT  = (unsigned short*)(kss + 384);   // 3*16384
    unsigned short* waT  = wqT + 49152;
    unsigned short* w1T  = waT + 49152;
    unsigned short* w2T  = w1T + 49152;
    unsigned short* ksT  = w2T + 49152;                    // 3*2048
    unsigned short* pw1T = ksT + 6144;                     // 8192
    unsigned short* pweT = pw1T + 8192;                    // 4096

    const unsigned short* c_qpts = canon + ca.off[0];
    const unsigned short* c_bpts = canon + ca.off[1];
    const unsigned short* c_pew  = canon + ca.off[2];
    const unsigned short* c_peb  = canon + ca.off[3];
    const unsigned short* c_bpew = canon + ca.off[4];
    const unsigned short* c_bpeb = canon + ca.off[5];
    const unsigned short* c_Wq   = canon + ca.off[6];
    const unsigned short* c_bq   = canon + ca.off[7];
    const unsigned short* c_Wk   = canon + ca.off[8];
    const unsigned short* c_bk   = canon + ca.off[9];
    const unsigned short* c_Wv   = canon + ca.off[10];
    const unsigned short* c_bv   = canon + ca.off[11];
    const unsigned short* c_Wo   = canon + ca.off[12];
    const unsigned short* c_bo   = canon + ca.off[13];
    const unsigned short* c_W1   = canon + ca.off[14];
    const unsigned short* c_b1   = canon + ca.off[15];
    const unsigned short* c_W2   = canon + ca.off[16];
    const unsigned short* c_b2   = canon + ca.off[17];
    const unsigned short* c_pw1  = canon + ca.off[18];
    const unsigned short* c_pb1  = canon + ca.off[19];
    const unsigned short* c_pw2  = canon + ca.off[20];
    const unsigned short* c_pb2  = canon + ca.off[21];

    convert_kernel<<<(total + 255) / 256, 256, 0, stream>>>(
        ca, (const unsigned short*)d_in[2], flag, canon, total);

    encode_kernel<<<M / 8, 256, 0, stream>>>(c_bpts, c_bpew, c_bpeb, b_enc);
    khvh_kernel<<<(12 * M * 32) / 256, 256, 0, stream>>>(
        b_enc, c_Wk, c_bk, c_Wv, c_bv, khb, vhb, kvs);
    kvred_kernel<<<96, 1024, 0, stream>>>(khb, vhb, kvs, kss);
    prep_kernel<<<215040 / 256, 256, 0, stream>>>(
        c_Wq, c_W1, c_W2, c_pw1, kvs, kss, c_Wo, c_pew,
        wqT, w1T, w2T, pw1T, waT, ksT, pweT);

    mega_kernel<<<N / 128, 256, 0, stream>>>(
        c_qpts, pweT, c_peb, wqT, waT, ksT, w1T, w2T,
        c_bq, c_bo, c_b1, c_b2, pw1T, c_pb1, c_pw2, c_pb2, d_out, flag);
}

// Round 5
// 415.107 us; speedup vs baseline: 2.2520x; 1.0151x over previous
//
#include <hip/hip_runtime.h>
#include <hip/hip_bf16.h>

// ---------- helpers ----------
__device__ __forceinline__ float b2f(unsigned short u) {
    return __uint_as_float(((unsigned)u) << 16);
}
__device__ __forceinline__ unsigned short f2b(float f) {
    __hip_bfloat16 h = __float2bfloat16(f);
    return *reinterpret_cast<unsigned short*>(&h);
}
// pack two f32 -> packed 2x bf16 (RNE), single VALU op
__device__ __forceinline__ unsigned pk_bf16(float lo, float hi) {
    unsigned r;
    asm("v_cvt_pk_bf16_f32 %0, %1, %2" : "=v"(r) : "v"(lo), "v"(hi));
    return r;
}
__device__ __forceinline__ float sigm(float v) {
    return 1.f / (1.f + __expf(-v));
}
// lean tanh-approx GELU: g = x*(1-r), r = 1/(1+exp(2y)), 2y = x*(c1 + c2*x^2)
// (same tanh approximation as before, ~8 VALU ops vs 13)
__device__ __forceinline__ float gelu_l(float x) {
    float x2 = x * x;
    float y2 = x * __builtin_fmaf(0.0713548163f, x2, 1.5957691216f);
    float e  = __expf(y2);
    float r  = __builtin_amdgcn_rcpf(e + 1.f);
    return x - x * r;
}

typedef __attribute__((ext_vector_type(8))) short s8v;   // 8 bf16 (4 VGPRs)
typedef __attribute__((ext_vector_type(4))) float f4v;   // 4 fp32 acc

#define MFMA_BF16 __builtin_amdgcn_mfma_f32_16x16x32_bf16

__device__ __forceinline__ s8v mkfrag(unsigned a, unsigned b, unsigned c, unsigned d) {
    union { unsigned u[4]; s8v v; } x;
    x.u[0] = a; x.u[1] = b; x.u[2] = c; x.u[3] = d;
    return x.v;
}

// sigma: slot s -> actual column. s{i[1:0],qd[1:0],ntlo,nthi[1:0]} ->
// c{i[1:0], ntlo, qd[1:0], nthi[1:0]}. Bijective bit permutation.
// With weight ROWS stored at slots (row n_actual at slot sigma^-1), the MFMA
// C output of slot (nt,qd,i) is actual col (nt>>1)*32 + qd*8 + (nt&1)*4 + i,
// which makes each lane's C exactly the next mm's B-fragment (lane-local).
__device__ __forceinline__ int fmap(int s) {
    return (s & ~31) | (((s >> 2) & 3) << 3) | (((s >> 4) & 1) << 2) | (s & 3);
}

// ---------- 15-feature map (full, for the boundary path) ----------
__device__ __forceinline__ void make_feats(const unsigned short* __restrict__ qpts,
                                           int r, float* __restrict__ f) {
    unsigned pq = *(const unsigned*)(qpts + (size_t)r * 2);
    float x0 = b2f((unsigned short)(pq & 0xffff));
    float x1 = b2f((unsigned short)(pq >> 16));
    const float PI = 3.14159265358979323846f;
    float a0 = x0 - 1.5f, a1 = x1 - 1.5f, c0 = x0 - 4.5f, c1 = x1 - 4.5f;
    f[0] = x0;        f[1] = x1;
    f[2] = x0 * x0;   f[3] = x1 * x1;
    f[4] = a0 * a0;   f[5] = a1 * a1;
    f[6] = c0 * c0;   f[7] = c1 * c1;
    f[8] = sigm(x0);  f[9] = sigm(x1);
    f[10] = sigm(a0); f[11] = sigm(a1);
    f[12] = sigm(c0); f[13] = sigm(c1);
    f[14] = a0;       f[15] = a1;
    f[16] = c0;       f[17] = c1;
    f[18] = __sinf(PI * x0);          f[19] = __sinf(PI * x1);
    f[20] = __cosf(PI * x0);          f[21] = __cosf(PI * x1);
    f[22] = __sinf(PI * 0.25f * x0);  f[23] = __sinf(PI * 0.25f * x1);
    f[24] = __cosf(PI * 0.25f * x0);  f[25] = __cosf(PI * 0.25f * x1);
    f[26] = __sinf(PI * 0.5f * x0);   f[27] = __sinf(PI * 0.5f * x1);
    f[28] = __cosf(PI * 0.5f * x0);   f[29] = __cosf(PI * 0.5f * x1);
}

// 8 features for k = qd*8 .. qd*8+7 (quad-split of the 30-vector, 30/31 -> 0)
__device__ __forceinline__ void feats8(unsigned pq, int qd, float* __restrict__ f8) {
    float x0 = b2f((unsigned short)(pq & 0xffff));
    float x1 = b2f((unsigned short)(pq >> 16));
    const float PI = 3.14159265358979323846f;
    float a0 = x0 - 1.5f, a1 = x1 - 1.5f, c0 = x0 - 4.5f, c1 = x1 - 4.5f;
    if (qd == 0) {
        f8[0] = x0;      f8[1] = x1;
        f8[2] = x0 * x0; f8[3] = x1 * x1;
        f8[4] = a0 * a0; f8[5] = a1 * a1;
        f8[6] = c0 * c0; f8[7] = c1 * c1;
    } else if (qd == 1) {
        f8[0] = sigm(x0); f8[1] = sigm(x1);
        f8[2] = sigm(a0); f8[3] = sigm(a1);
        f8[4] = sigm(c0); f8[5] = sigm(c1);
        f8[6] = a0;       f8[7] = a1;
    } else if (qd == 2) {
        f8[0] = c0; f8[1] = c1;
        f8[2] = __sinf(PI * x0);          f8[3] = __sinf(PI * x1);
        f8[4] = __cosf(PI * x0);          f8[5] = __cosf(PI * x1);
        f8[6] = __sinf(PI * 0.25f * x0);  f8[7] = __sinf(PI * 0.25f * x1);
    } else {
        f8[0] = __cosf(PI * 0.25f * x0);  f8[1] = __cosf(PI * 0.25f * x1);
        f8[2] = __sinf(PI * 0.5f * x0);   f8[3] = __sinf(PI * 0.5f * x1);
        f8[4] = __cosf(PI * 0.5f * x0);   f8[5] = __cosf(PI * 0.5f * x1);
        f8[6] = 0.f;                      f8[7] = 0.f;
    }
}

// ---------- canonicalize all inputs to bf16 (embedded dtype detection) ----------
struct ConvArgs {
    const void* p[22];
    int off[23];
};

__global__ __launch_bounds__(256) void convert_kernel(
    ConvArgs a, const unsigned short* __restrict__ pe_w_raw,
    int* __restrict__ flag, unsigned short* __restrict__ canon, int total)
{
    __shared__ int cnt;
    if (threadIdx.x == 0) cnt = 0;
    __syncthreads();
    float v = b2f(pe_w_raw[threadIdx.x * 2]);
    if (!(fabsf(v) < 1.0f)) atomicAdd(&cnt, 1);
    __syncthreads();
    int isf32 = (cnt >= 16) ? 1 : 0;
    if (blockIdx.x == 0 && threadIdx.x == 0) *flag = isf32;

    int g = blockIdx.x * 256 + threadIdx.x;
    if (g >= total) return;
    int s = 0;
    #pragma unroll
    for (int i = 1; i < 23; i++) s += (g >= a.off[i]) ? 1 : 0;
    int local = g - a.off[s];
    unsigned short r;
    if (isf32) r = f2b(((const float*)a.p[s])[local]);
    else       r = ((const unsigned short*)a.p[s])[local];
    canon[g] = r;
}

// ---------- boundary positional encoding (M rows, fp32 out) ----------
__global__ __launch_bounds__(256) void encode_kernel(
    const unsigned short* __restrict__ pts,
    const unsigned short* __restrict__ w,
    const unsigned short* __restrict__ b,
    float* __restrict__ out)
{
    __shared__ __align__(16) float wsm[30 * 128];
    __shared__ float bs[128];
    int t = threadIdx.x;
    for (int i = t; i < 30 * 128; i += 256) wsm[i] = b2f(w[i]);
    if (t < 128) bs[t] = b2f(b[t]);
    __syncthreads();

    int r = blockIdx.x * 8 + (t >> 5);
    int j = t & 31;
    float f[30];
    make_feats(pts, r, f);
    float s0 = bs[j * 4 + 0], s1 = bs[j * 4 + 1], s2 = bs[j * 4 + 2], s3 = bs[j * 4 + 3];
    #pragma unroll
    for (int ff = 0; ff < 30; ff++) {
        float4 wv = *(const float4*)&wsm[ff * 128 + j * 4];
        float fv = f[ff];
        s0 += fv * wv.x; s1 += fv * wv.y; s2 += fv * wv.z; s3 += fv * wv.w;
    }
    *(float4*)&out[(size_t)r * 128 + j * 4] =
        make_float4(__sinf(s0), __sinf(s1), __sinf(s2), __sinf(s3));
}

// ---------- boundary k/v heads (+ zeroing of kv/ks accumulators) ----------
__global__ __launch_bounds__(256) void khvh_kernel(
    const float* __restrict__ benc,
    const unsigned short* __restrict__ Wk, const unsigned short* __restrict__ bk,
    const unsigned short* __restrict__ Wv, const unsigned short* __restrict__ bv,
    float* __restrict__ kh, float* __restrict__ vh, float* __restrict__ kvz)
{
    int g = blockIdx.x * 256 + threadIdx.x;
    if (g < 12672) kvz[g] = 0.f;   // kvs(12288) + kss(384), contiguous
    int lh = g >> 17;
    int rem = g & 131071;
    int m = rem >> 5;
    int dd = rem & 31;
    const unsigned short* wk = Wk + lh * 4096 + dd;
    const unsigned short* wv = Wv + lh * 4096 + dd;
    const float* br = benc + (size_t)m * 128;
    float ka = 0.f, va = 0.f;
    #pragma unroll 8
    for (int c = 0; c < 128; c++) {
        float bb = br[c];
        ka += bb * b2f(wk[c * 32]);
        va += bb * b2f(wv[c * 32]);
    }
    ka += b2f(bk[lh * 32 + dd]); ka = ka * ka;
    va += b2f(bv[lh * 32 + dd]);
    kh[g] = ka; vh[g] = va;
}

// ---------- reduce over boundary points: kvsum[lh][d][e], ksum[lh][d] ----------
__global__ __launch_bounds__(1024) void kvred_kernel(
    const float* __restrict__ kh, const float* __restrict__ vh,
    float* __restrict__ kvsum, float* __restrict__ ksum)
{
    __shared__ float khs[1024];
    __shared__ float vhs[1024];
    int t = threadIdx.x;
    int lh = blockIdx.x >> 3;
    int part = blockIdx.x & 7;
    int dd = t >> 5, ee = t & 31;
    float kva = 0.f, ksa = 0.f;
    for (int ch = 0; ch < 16; ch++) {
        int base = lh * 131072 + (part * 16 + ch) * 1024;
        khs[t] = kh[base + t];
        vhs[t] = vh[base + t];
        __syncthreads();
        #pragma unroll
        for (int i = 0; i < 32; i++) {
            float kk = khs[i * 32 + dd];
            kva += kk * vhs[i * 32 + ee];
            ksa += kk;
        }
        __syncthreads();
    }
    atomicAdd(&kvsum[lh * 1024 + dd * 32 + ee], kva);
    if (ee == 0) atomicAdd(&ksum[lh * 32 + dd], ksa);
}

// ---------- prep: transposes (sigma-permuted rows) + Wa fold + Ks ----------
// wqT/waT/w1T/w2T/pweT rows are stored at SLOT positions: slot n holds actual
// weight row fmap(n). ksT and pw1T stay linear (den / projector don't feed
// another MFMA through the rename path... pw1T's C is consumed by the fp32
// tail which uses actual-col indexing directly).
__global__ __launch_bounds__(256) void prep_kernel(
    const unsigned short* __restrict__ Wq, const unsigned short* __restrict__ W1,
    const unsigned short* __restrict__ W2, const unsigned short* __restrict__ pw1,
    const float* __restrict__ kvs, const float* __restrict__ kss,
    const unsigned short* __restrict__ Wo, const unsigned short* __restrict__ pe_w,
    unsigned short* __restrict__ wqT, unsigned short* __restrict__ w1T,
    unsigned short* __restrict__ w2T, unsigned short* __restrict__ pw1T,
    unsigned short* __restrict__ waT, unsigned short* __restrict__ ksT,
    unsigned short* __restrict__ pweT)
{
    int g = blockIdx.x * 256 + threadIdx.x;
    if (g < 49152) {
        int l = g >> 14, r = g & 16383, n = r >> 7, k = r & 127;
        int na = fmap(n);   // head-interleaved actual col
        wqT[g] = Wq[((l * 4 + (na >> 5)) * 128 + k) * 32 + (na & 31)];
    } else if (g < 98304) {
        int q = g - 49152; int l = q >> 14, r = q & 16383, n = r >> 7, k = r & 127;
        w1T[q] = W1[(l * 128 + k) * 128 + fmap(n)];
    } else if (g < 147456) {
        int q = g - 98304; int l = q >> 14, r = q & 16383, n = r >> 7, k = r & 127;
        w2T[q] = W2[(l * 128 + k) * 128 + fmap(n)];
    } else if (g < 155648) {
        int q = g - 147456; int n = q >> 7, k = q & 127;
        pw1T[q] = pw1[k * 64 + n];                       // linear (no sigma)
    } else if (g < 204800) {
        int q = g - 155648; int l = q >> 14, r = q & 16383, n = r >> 7, k = r & 127;
        int na = fmap(n);
        int hk = k >> 5, dk = k & 31;
        const float* kvp = kvs + (l * 4 + hk) * 1024 + dk * 32;
        const unsigned short* wop = Wo + (size_t)(l * 128 + hk * 32) * 128 + na;
        float s = 0.f;
        #pragma unroll 8
        for (int j = 0; j < 32; j++) s += kvp[j] * b2f(wop[j * 128]);
        waT[q] = f2b(s);
    } else if (g < 210944) {
        int q = g - 204800; int l = q >> 11, r = q & 2047, n = r >> 7, k = r & 127;
        unsigned short v = 0;
        if (n < 4 && (k >> 5) == n) v = f2b(kss[(l * 4 + n) * 32 + (k & 31)]);
        ksT[q] = v;                                      // linear (no sigma)
    } else if (g < 215040) {
        int q = g - 210944; int n = q >> 5, k = q & 31;  // pe_wT [128 slot][32]
        pweT[q] = (k < 30) ? pe_w[k * 128 + fmap(n)] : (unsigned short)0;
    }
}

// ---------- the fused mega kernel: encode + 3 layers + projector ----------
// ROUND-4 (resubmit after infra failure): sigma weight-row permutation ->
// C-to-B is pure register renaming. The activation LDS round-trip (epilogue
// writes + LOAD_AF reads, the 25M bank conflicts and a large share of R3's
// 62% VALUBusy) is eliminated: activations live entirely in registers (pkd
// packed bf16 + hres fp32). sA deleted; projector tail = per-lane dot +
// shfl_xor reduce over qd group. LDS in the layer loop = wbuf staging +
// broadcast bias reads only. B-frags are captured into bf0/bf1 BEFORE the
// p-loop, so the epilogue can overwrite pkd in place.

// stage split: loads (issue early, anywhere) / writes (after wbuf-free barrier)
template<int ITERS>
__device__ __forceinline__ void load_w(const unsigned short* __restrict__ g,
                                       int t, s8v* __restrict__ r) {
    #pragma unroll
    for (int i = 0; i < ITERS; i++)
        r[i] = *(const s8v*)((const char*)g + (size_t)(i * 256 + t) * 16);
}
template<int ITERS>
__device__ __forceinline__ void write_w(unsigned short* __restrict__ wbuf,
                                        int t, const s8v* __restrict__ r) {
    #pragma unroll
    for (int i = 0; i < ITERS; i++) {
        int lin = (i * 256 + t) * 16;
        int sw = lin ^ (((lin >> 8) & 7) << 4);   // row&7 XOR into byte bits 4-6
        *(s8v*)((char*)wbuf + sw) = r[i];
    }
}

// swizzled weight-fragment read: ntile nt, k-slice k, lane (qd,l16)
__device__ __forceinline__ s8v wfrag(const unsigned short* __restrict__ wbuf,
                                     int nt, int k, int l16, int qd) {
    int lin = (nt << 12) + (l16 << 8) + (k << 6) + (qd << 4);
    return *(const s8v*)((const char*)wbuf + (lin ^ ((l16 & 7) << 4)));
}

// dual-ntile, dual-rowtile matmul; B-frags renamed from pkd (sigma layout).
// Epilogue sees: nt (0..7), tile (0/1), x (f4v) = slot (nt,qd,i) of row
// rA0 + tile*16; actual col = cb + i with cb below.
#define MM_BODY(EPI...) do {                                                  \
    s8v bf0[4], bf1[4];                                                       \
    _Pragma("unroll")                                                         \
    for (int _s = 0; _s < 4; _s++) {                                          \
        bf0[_s] = mkfrag(pkd[0][2*_s][0], pkd[0][2*_s][1],                    \
                         pkd[0][2*_s+1][0], pkd[0][2*_s+1][1]);               \
        bf1[_s] = mkfrag(pkd[1][2*_s][0], pkd[1][2*_s][1],                    \
                         pkd[1][2*_s+1][0], pkd[1][2*_s+1][1]);               \
    }                                                                         \
    _Pragma("unroll")                                                         \
    for (int _p = 0; _p < 4; _p++) {                                          \
        f4v _x0 = {0.f,0.f,0.f,0.f}, _x1 = _x0, _y0 = _x0, _y1 = _x0;         \
        _Pragma("unroll")                                                     \
        for (int _k = 0; _k < 4; _k++) {                                      \
            s8v _wa = wfrag(wbuf, _p * 2,     _k, l16, qd);                   \
            s8v _wb = wfrag(wbuf, _p * 2 + 1, _k, l16, qd);                   \
            _x0 = MFMA_BF16(_wa, bf0[_k], _x0, 0, 0, 0);                      \
            _x1 = MFMA_BF16(_wa, bf1[_k], _x1, 0, 0, 0);                      \
            _y0 = MFMA_BF16(_wb, bf0[_k], _y0, 0, 0, 0);                      \
            _y1 = MFMA_BF16(_wb, bf1[_k], _y1, 0, 0, 0);                      \
        }                                                                     \
        { const int nt = _p * 2;     const int tile = 0; const f4v x = _x0; EPI } \
        { const int nt = _p * 2;     const int tile = 1; const f4v x = _x1; EPI } \
        { const int nt = _p * 2 + 1; const int tile = 0; const f4v x = _y0; EPI } \
        { const int nt = _p * 2 + 1; const int tile = 1; const f4v x = _y1; EPI } \
    }                                                                         \
} while (0)

#define CBDEF int cb = ((nt >> 1) << 5) + (qd << 3) + ((nt & 1) << 2)

__global__ __launch_bounds__(256) void mega_kernel(
    const unsigned short* __restrict__ qpts,
    const unsigned short* __restrict__ pweT,
    const unsigned short* __restrict__ pe_b,
    const unsigned short* __restrict__ wqT,
    const unsigned short* __restrict__ waT,
    const unsigned short* __restrict__ ksT,
    const unsigned short* __restrict__ w1T,
    const unsigned short* __restrict__ w2T,
    const unsigned short* __restrict__ bq,
    const unsigned short* __restrict__ bo,
    const unsigned short* __restrict__ b1,
    const unsigned short* __restrict__ b2,
    const unsigned short* __restrict__ pw1T,
    const unsigned short* __restrict__ pb1,
    const unsigned short* __restrict__ pw2,
    const unsigned short* __restrict__ pb2,
    void* __restrict__ outv, const int* __restrict__ flag)
{
    __shared__ __align__(16) unsigned short wbuf[16384];   // 32768 B, swizzled
    __shared__ __align__(16) float biasAll[12 * 128];      // 6144 B (actual-col order)
    __shared__ __align__(16) float pebs[128];
    __shared__ __align__(16) float pb1s[64];
    __shared__ __align__(16) float w2s4[256];              // w2 cols padded to float4
    __shared__ float pb2s[3];

    int t = threadIdx.x;
    int wvi = t >> 6, ln = t & 63, qd = ln >> 4, l16 = ln & 15;
    int row0 = blockIdx.x * 128;
    int rA0 = wvi * 32 + l16;        // lane's row, tile 0 (tile 1: +16)

    // ===== one-time staging =====
    for (int i = t; i < 1536; i += 256) {
        int l = i >> 9, rem = i & 511, which = rem >> 7, c = rem & 127;
        const unsigned short* bsrc = (which == 0) ? bq : (which == 1) ? bo
                                   : (which == 2) ? b1 : b2;
        biasAll[i] = b2f(bsrc[l * 128 + c]);
    }
    if (t < 128) pebs[t] = b2f(pe_b[t]);
    if (t < 64)  pb1s[t] = b2f(pb1[t]);
    if (t < 64) {
        w2s4[t * 4 + 0] = b2f(pw2[t * 3 + 0]);
        w2s4[t * 4 + 1] = b2f(pw2[t * 3 + 1]);
        w2s4[t * 4 + 2] = b2f(pw2[t * 3 + 2]);
        w2s4[t * 4 + 3] = 0.f;
    }
    if (t < 3) pb2s[t] = b2f(pb2[t]);
    __syncthreads();

    s8v sreg[8];
    // stage wq[0]; encode runs between write and barrier to overlap stores
    load_w<8>(wqT, t, sreg);
    write_w<8>(wbuf, t, sreg);   // no prior readers -> no barrier needed first

    unsigned pkd[2][8][2];   // packed bf16 activations, slot layout
    float hres[2][8][4];     // fp32 residual, slot layout

    // ===== encode via MFMA: h = sin(feats @ pe_w + pe_b), pweT sigma'd =====
    {
        unsigned pq0 = *(const unsigned*)(qpts + (size_t)(row0 + rA0) * 2);
        unsigned pq1 = *(const unsigned*)(qpts + (size_t)(row0 + rA0 + 16) * 2);
        s8v ae0, ae1;
        {
            float f8[8]; feats8(pq0, qd, f8);
            unsigned* au = (unsigned*)&ae0;
            #pragma unroll
            for (int jj = 0; jj < 4; jj++) au[jj] = pk_bf16(f8[2 * jj], f8[2 * jj + 1]);
        }
        {
            float f8[8]; feats8(pq1, qd, f8);
            unsigned* au = (unsigned*)&ae1;
            #pragma unroll
            for (int jj = 0; jj < 4; jj++) au[jj] = pk_bf16(f8[2 * jj], f8[2 * jj + 1]);
        }
        const unsigned short* pb = pweT + l16 * 32 + qd * 8;
        #pragma unroll
        for (int nt = 0; nt < 8; nt++) {
            s8v aw = *(const s8v*)(pb + nt * 512);
            f4v x0 = {0.f, 0.f, 0.f, 0.f}, x1 = {0.f, 0.f, 0.f, 0.f};
            x0 = MFMA_BF16(aw, ae0, x0, 0, 0, 0);
            x1 = MFMA_BF16(aw, ae1, x1, 0, 0, 0);
            CBDEF;
            float4 bb = *(const float4*)&pebs[cb];
            float h0 = __sinf(x0[0] + bb.x), h1 = __sinf(x0[1] + bb.y);
            float h2 = __sinf(x0[2] + bb.z), h3 = __sinf(x0[3] + bb.w);
            hres[0][nt][0] = h0; hres[0][nt][1] = h1;
            hres[0][nt][2] = h2; hres[0][nt][3] = h3;
            pkd[0][nt][0] = pk_bf16(h0, h1);
            pkd[0][nt][1] = pk_bf16(h2, h3);
            float g0 = __sinf(x1[0] + bb.x), g1 = __sinf(x1[1] + bb.y);
            float g2 = __sinf(x1[2] + bb.z), g3 = __sinf(x1[3] + bb.w);
            hres[1][nt][0] = g0; hres[1][nt][1] = g1;
            hres[1][nt][2] = g2; hres[1][nt][3] = g3;
            pkd[1][nt][0] = pk_bf16(g0, g1);
            pkd[1][nt][1] = pk_bf16(g2, g3);
        }
    }
    __syncthreads();   // wq[0] staged

    // ===== 3 transformer layers =====
    for (int l = 0; l < 3; l++) {
        const float* bql = &biasAll[(l * 4 + 0) * 128];
        const float* bol = &biasAll[(l * 4 + 1) * 128];
        const float* b1l = &biasAll[(l * 4 + 2) * 128];
        const float* b2l = &biasAll[(l * 4 + 3) * 128];

        // mm1: qh = (h @ Wq + bq)^2 -> pkd (in place)
        MM_BODY({
            CBDEF;
            float4 bb = *(const float4*)&bql[cb];
            float v0 = x[0] + bb.x, v1 = x[1] + bb.y;
            float v2 = x[2] + bb.z, v3 = x[3] + bb.w;
            pkd[tile][nt][0] = pk_bf16(v0 * v0, v1 * v1);
            pkd[tile][nt][1] = pk_bf16(v2 * v2, v3 * v3);
        });

        // den window: kf + next-weight loads issued, den overlaps latency
        s8v kf[4];
        {
            const unsigned short* kb = ksT + l * 2048 + l16 * 128 + qd * 8;
            #pragma unroll
            for (int ks = 0; ks < 4; ks++) kf[ks] = *(const s8v*)(kb + ks * 32);
        }
        load_w<8>(waT + l * 16384, t, sreg);
        // den: d[h] = qh_row . ksum_h (A = ksT rows, B = qh rename); z-scale pkd
        #pragma unroll
        for (int tile = 0; tile < 2; tile++) {
            f4v d = {0.f, 0.f, 0.f, 0.f};
            #pragma unroll
            for (int ks = 0; ks < 4; ks++) {
                s8v b = mkfrag(pkd[tile][2 * ks][0], pkd[tile][2 * ks][1],
                               pkd[tile][2 * ks + 1][0], pkd[tile][2 * ks + 1][1]);
                d = MFMA_BF16(kf[ks], b, d, 0, 0, 0);
            }
            #pragma unroll
            for (int ks = 0; ks < 4; ks++) {
                float z = 1.f / (__shfl(d[ks], l16) + 1e-6f);
                #pragma unroll
                for (int h2 = 0; h2 < 2; h2++) {
                    #pragma unroll
                    for (int j = 0; j < 2; j++) {
                        unsigned w = pkd[tile][2 * ks + h2][j];
                        float lo = __uint_as_float(w << 16) * z;
                        float hi = __uint_as_float(w & 0xffff0000u) * z;
                        pkd[tile][2 * ks + h2][j] = pk_bf16(lo, hi);
                    }
                }
            }
        }
        __syncthreads();                 // all waves done reading wq[l]
        write_w<8>(wbuf, t, sreg);
        __syncthreads();                 // waT staged

        // mm2: x = h + (z*qh) @ Wa + bo -> hres, pkd
        MM_BODY({
            CBDEF;
            float4 bb = *(const float4*)&bol[cb];
            float v0 = hres[tile][nt][0] + x[0] + bb.x;
            float v1 = hres[tile][nt][1] + x[1] + bb.y;
            float v2 = hres[tile][nt][2] + x[2] + bb.z;
            float v3 = hres[tile][nt][3] + x[3] + bb.w;
            hres[tile][nt][0] = v0; hres[tile][nt][1] = v1;
            hres[tile][nt][2] = v2; hres[tile][nt][3] = v3;
            pkd[tile][nt][0] = pk_bf16(v0, v1);
            pkd[tile][nt][1] = pk_bf16(v2, v3);
        });
        load_w<8>(w1T + l * 16384, t, sreg);
        __syncthreads();
        write_w<8>(wbuf, t, sreg);
        __syncthreads();                 // w1T staged

        // mm3: t = gelu(x @ W1 + b1) -> pkd
        MM_BODY({
            CBDEF;
            float4 bb = *(const float4*)&b1l[cb];
            float g0 = gelu_l(x[0] + bb.x), g1 = gelu_l(x[1] + bb.y);
            float g2 = gelu_l(x[2] + bb.z), g3 = gelu_l(x[3] + bb.w);
            pkd[tile][nt][0] = pk_bf16(g0, g1);
            pkd[tile][nt][1] = pk_bf16(g2, g3);
        });
        load_w<8>(w2T + l * 16384, t, sreg);
        __syncthreads();
        write_w<8>(wbuf, t, sreg);
        __syncthreads();                 // w2T staged

        // mm4: h_new = x + t @ W2 + b2 -> hres, pkd
        MM_BODY({
            CBDEF;
            float4 bb = *(const float4*)&b2l[cb];
            float v0 = hres[tile][nt][0] + x[0] + bb.x;
            float v1 = hres[tile][nt][1] + x[1] + bb.y;
            float v2 = hres[tile][nt][2] + x[2] + bb.z;
            float v3 = hres[tile][nt][3] + x[3] + bb.w;
            hres[tile][nt][0] = v0; hres[tile][nt][1] = v1;
            hres[tile][nt][2] = v2; hres[tile][nt][3] = v3;
            pkd[tile][nt][0] = pk_bf16(v0, v1);
            pkd[tile][nt][1] = pk_bf16(v2, v3);
        });
        if (l < 2) {
            load_w<8>(wqT + (l + 1) * 16384, t, sreg);
            __syncthreads();
            write_w<8>(wbuf, t, sreg);
        } else {
            load_w<4>(pw1T, t, sreg);
            __syncthreads();
            write_w<4>(wbuf, t, sreg);
        }
        __syncthreads();                 // next weights staged
    }

    // ===== final projector: out = gelu(h @ pw1 + pb1) @ pw2 + pb2 =====
    {
        s8v bf0[4], bf1[4];
        #pragma unroll
        for (int ks = 0; ks < 4; ks++) {
            bf0[ks] = mkfrag(pkd[0][2 * ks][0], pkd[0][2 * ks][1],
                             pkd[0][2 * ks + 1][0], pkd[0][2 * ks + 1][1]);
            bf1[ks] = mkfrag(pkd[1][2 * ks][0], pkd[1][2 * ks][1],
                             pkd[1][2 * ks + 1][0], pkd[1][2 * ks + 1][1]);
        }
        float pt0[3] = {0.f, 0.f, 0.f}, pt1[3] = {0.f, 0.f, 0.f};
        #pragma unroll
        for (int p = 0; p < 2; p++) {
            f4v y00 = {0.f,0.f,0.f,0.f}, y01 = y00, y10 = y00, y11 = y00;
            #pragma unroll
            for (int ks = 0; ks < 4; ks++) {
                s8v wa = wfrag(wbuf, p * 2,     ks, l16, qd);
                s8v wb = wfrag(wbuf, p * 2 + 1, ks, l16, qd);
                y00 = MFMA_BF16(wa, bf0[ks], y00, 0, 0, 0);
                y01 = MFMA_BF16(wa, bf1[ks], y01, 0, 0, 0);
                y10 = MFMA_BF16(wb, bf0[ks], y10, 0, 0, 0);
                y11 = MFMA_BF16(wb, bf1[ks], y11, 0, 0, 0);
            }
            #pragma unroll
            for (int e = 0; e < 2; e++) {
                int c0 = (p * 2 + e) * 16 + qd * 4;   // pw1T linear -> actual col
                float4 bb = *(const float4*)&pb1s[c0];
                f4v ya = e ? y10 : y00;   // tile 0
                f4v yb = e ? y11 : y01;   // tile 1
                #pragma unroll
                for (int i = 0; i < 4; i++) {
                    float bbi = (i == 0) ? bb.x : (i == 1) ? bb.y : (i == 2) ? bb.z : bb.w;
                    float4 w = *(const float4*)&w2s4[(c0 + i) * 4];
                    float ga = gelu_l(ya[i] + bbi);
                    float gb = gelu_l(yb[i] + bbi);
                    pt0[0] = fmaf(ga, w.x, pt0[0]);
                    pt0[1] = fmaf(ga, w.y, pt0[1]);
                    pt0[2] = fmaf(ga, w.z, pt0[2]);
                    pt1[0] = fmaf(gb, w.x, pt1[0]);
                    pt1[1] = fmaf(gb, w.y, pt1[1]);
                    pt1[2] = fmaf(gb, w.z, pt1[2]);
                }
            }
        }
        // reduce over the qd group (lane bits 4-5), then lane qd==0 stores
        #pragma unroll
        for (int c = 0; c < 3; c++) {
            pt0[c] += __shfl_xor(pt0[c], 16); pt0[c] += __shfl_xor(pt0[c], 32);
            pt1[c] += __shfl_xor(pt1[c], 16); pt1[c] += __shfl_xor(pt1[c], 32);
            pt0[c] += pb2s[c]; pt1[c] += pb2s[c];
        }
        if (ln < 16) {
            size_t r0 = (size_t)(row0 + rA0) * 3;
            size_t r1 = (size_t)(row0 + rA0 + 16) * 3;
            if (*flag) {
                float* o = (float*)outv;
                o[r0] = pt0[0]; o[r0 + 1] = pt0[1]; o[r0 + 2] = pt0[2];
                o[r1] = pt1[0]; o[r1 + 1] = pt1[1]; o[r1 + 2] = pt1[2];
            } else {
                unsigned short* o = (unsigned short*)outv;
                o[r0] = f2b(pt0[0]); o[r0 + 1] = f2b(pt0[1]); o[r0 + 2] = f2b(pt0[2]);
                o[r1] = f2b(pt1[0]); o[r1 + 1] = f2b(pt1[1]); o[r1 + 2] = f2b(pt1[2]);
            }
        }
    }
}

// ---------- launch ----------
extern "C" void kernel_launch(void* const* d_in, const int* in_sizes, int n_in,
                              void* d_out, int out_size, void* d_ws, size_t ws_size,
                              hipStream_t stream) {
    const int N = in_sizes[0] / 2;   // 262144
    const int M = in_sizes[1] / 2;   // 4096

    ConvArgs ca;
    int total = 0;
    for (int i = 0; i < 22; i++) { ca.p[i] = d_in[i]; ca.off[i] = total; total += in_sizes[i]; }
    ca.off[22] = total;

    float* ws = (float*)d_ws;
    int* flag = (int*)ws;
    unsigned short* canon = (unsigned short*)(ws + 16);
    size_t canonF = ((size_t)(total + 1) / 2 + 15) & ~(size_t)15;
    float* b_enc = ws + 16 + canonF;                       // M*128
    float* khb   = b_enc + (size_t)M * 128;                // 12*M*32
    float* vhb   = khb + (size_t)12 * M * 32;              // 12*M*32
    float* kvs   = vhb + (size_t)12 * M * 32;              // 12288
    float* kss   = kvs + 12288;                            // 384
    unsigned short* wqT  = (unsigned short*)(kss + 384);   // 3*16384
    unsigned short* waT  = wqT + 49152;
    unsigned short* w1T  = waT + 49152;
    unsigned short* w2T  = w1T + 49152;
    unsigned short* ksT  = w2T + 49152;                    // 3*2048
    unsigned short* pw1T = ksT + 6144;                     // 8192
    unsigned short* pweT = pw1T + 8192;                    // 4096

    const unsigned short* c_qpts = canon + ca.off[0];
    const unsigned short* c_bpts = canon + ca.off[1];
    const unsigned short* c_pew  = canon + ca.off[2];
    const unsigned short* c_peb  = canon + ca.off[3];
    const unsigned short* c_bpew = canon + ca.off[4];
    const unsigned short* c_bpeb = canon + ca.off[5];
    const unsigned short* c_Wq   = canon + ca.off[6];
    const unsigned short* c_bq   = canon + ca.off[7];
    const unsigned short* c_Wk   = canon + ca.off[8];
    const unsigned short* c_bk   = canon + ca.off[9];
    const unsigned short* c_Wv   = canon + ca.off[10];
    const unsigned short* c_bv   = canon + ca.off[11];
    const unsigned short* c_Wo   = canon + ca.off[12];
    const unsigned short* c_bo   = canon + ca.off[13];
    const unsigned short* c_W1   = canon + ca.off[14];
    const unsigned short* c_b1   = canon + ca.off[15];
    const unsigned short* c_W2   = canon + ca.off[16];
    const unsigned short* c_b2   = canon + ca.off[17];
    const unsigned short* c_pw1  = canon + ca.off[18];
    const unsigned short* c_pb1  = canon + ca.off[19];
    const unsigned short* c_pw2  = canon + ca.off[20];
    const unsigned short* c_pb2  = canon + ca.off[21];

    convert_kernel<<<(total + 255) / 256, 256, 0, stream>>>(
        ca, (const unsigned short*)d_in[2], flag, canon, total);

    encode_kernel<<<M / 8, 256, 0, stream>>>(c_bpts, c_bpew, c_bpeb, b_enc);
    khvh_kernel<<<(12 * M * 32) / 256, 256, 0, stream>>>(
        b_enc, c_Wk, c_bk, c_Wv, c_bv, khb, vhb, kvs);
    kvred_kernel<<<96, 1024, 0, stream>>>(khb, vhb, kvs, kss);
    prep_kernel<<<215040 / 256, 256, 0, stream>>>(
        c_Wq, c_W1, c_W2, c_pw1, kvs, kss, c_Wo, c_pew,
        wqT, w1T, w2T, pw1T, waT, ksT, pweT);

    mega_kernel<<<N / 128, 256, 0, stream>>>(
        c_qpts, pweT, c_peb, wqT, waT, ksT, w1T, w2T,
        c_bq, c_bo, c_b1, c_b2, pw1T, c_pb1, c_pw2, c_pb2, d_out, flag);
}

// Round 6
// 364.557 us; speedup vs baseline: 2.5643x; 1.1387x over previous
//
#include <hip/hip_runtime.h>
#include <hip/hip_bf16.h>

// ---------- helpers ----------
__device__ __forceinline__ float b2f(unsigned short u) {
    return __uint_as_float(((unsigned)u) << 16);
}
__device__ __forceinline__ unsigned short f2b(float f) {
    __hip_bfloat16 h = __float2bfloat16(f);
    return *reinterpret_cast<unsigned short*>(&h);
}
// pack two f32 -> packed 2x bf16 (RNE), single VALU op
__device__ __forceinline__ unsigned pk_bf16(float lo, float hi) {
    unsigned r;
    asm("v_cvt_pk_bf16_f32 %0, %1, %2" : "=v"(r) : "v"(lo), "v"(hi));
    return r;
}
// hardware exp2 (v_exp_f32 computes 2^x)
__device__ __forceinline__ float exp2_hw(float x) {
    float r;
    asm("v_exp_f32 %0, %1" : "=v"(r) : "v"(x));
    return r;
}
__device__ __forceinline__ float sigm(float v) {
    return 1.f / (1.f + __expf(-v));
}
// lean tanh-approx GELU, exp2 form: g = x - x/(1+2^(x*(c1+c2*x^2)))
// c1 = 2*0.7978845608*log2e, c2 = 2*0.7978845608*0.044715*log2e
__device__ __forceinline__ float gelu_l(float x) {
    float x2 = x * x;
    float y  = x * __builtin_fmaf(0.10294535f, x2, 2.3022137f);
    float e  = exp2_hw(y);
    float r  = __builtin_amdgcn_rcpf(e + 1.f);
    return __builtin_fmaf(-x, r, x);
}

typedef __attribute__((ext_vector_type(8))) short s8v;   // 8 bf16 (4 VGPRs)
typedef __attribute__((ext_vector_type(4))) float f4v;   // 4 fp32 acc

#define MFMA_BF16 __builtin_amdgcn_mfma_f32_16x16x32_bf16

__device__ __forceinline__ s8v mkfrag(unsigned a, unsigned b, unsigned c, unsigned d) {
    union { unsigned u[4]; s8v v; } x;
    x.u[0] = a; x.u[1] = b; x.u[2] = c; x.u[3] = d;
    return x.v;
}

// sigma: slot s -> actual column. s{i[1:0],qd[1:0],ntlo,nthi[1:0]} ->
// c{i[1:0], ntlo, qd[1:0], nthi[1:0]}. Bijective bit permutation.
// With weight ROWS stored at slots (row n_actual at slot sigma^-1), the MFMA
// C output of slot (nt,qd,i) is actual col (nt>>1)*32 + qd*8 + (nt&1)*4 + i,
// which makes each lane's C exactly the next mm's B-fragment (lane-local).
__device__ __forceinline__ int fmap(int s) {
    return (s & ~31) | (((s >> 2) & 3) << 3) | (((s >> 4) & 1) << 2) | (s & 3);
}
// inverse LDS bank swizzle applied in GLOBAL memory (ushort index involution):
// gll copies linearly, wfrag reads with byte XOR ((l16&7)<<4); pre-permuting
// the source by the same involution makes both sides consistent (rule: linear
// dest + inverse-swz source + swz on read).
__device__ __forceinline__ int swz_q(int q) {
    return q ^ (((q >> 7) & 7) << 3);
}

// ---------- 15-feature map (full, for the boundary path) ----------
__device__ __forceinline__ void make_feats(const unsigned short* __restrict__ qpts,
                                           int r, float* __restrict__ f) {
    unsigned pq = *(const unsigned*)(qpts + (size_t)r * 2);
    float x0 = b2f((unsigned short)(pq & 0xffff));
    float x1 = b2f((unsigned short)(pq >> 16));
    const float PI = 3.14159265358979323846f;
    float a0 = x0 - 1.5f, a1 = x1 - 1.5f, c0 = x0 - 4.5f, c1 = x1 - 4.5f;
    f[0] = x0;        f[1] = x1;
    f[2] = x0 * x0;   f[3] = x1 * x1;
    f[4] = a0 * a0;   f[5] = a1 * a1;
    f[6] = c0 * c0;   f[7] = c1 * c1;
    f[8] = sigm(x0);  f[9] = sigm(x1);
    f[10] = sigm(a0); f[11] = sigm(a1);
    f[12] = sigm(c0); f[13] = sigm(c1);
    f[14] = a0;       f[15] = a1;
    f[16] = c0;       f[17] = c1;
    f[18] = __sinf(PI * x0);          f[19] = __sinf(PI * x1);
    f[20] = __cosf(PI * x0);          f[21] = __cosf(PI * x1);
    f[22] = __sinf(PI * 0.25f * x0);  f[23] = __sinf(PI * 0.25f * x1);
    f[24] = __cosf(PI * 0.25f * x0);  f[25] = __cosf(PI * 0.25f * x1);
    f[26] = __sinf(PI * 0.5f * x0);   f[27] = __sinf(PI * 0.5f * x1);
    f[28] = __cosf(PI * 0.5f * x0);   f[29] = __cosf(PI * 0.5f * x1);
}

// 8 features for k = qd*8 .. qd*8+7 (quad-split of the 30-vector, 30/31 -> 0)
__device__ __forceinline__ void feats8(unsigned pq, int qd, float* __restrict__ f8) {
    float x0 = b2f((unsigned short)(pq & 0xffff));
    float x1 = b2f((unsigned short)(pq >> 16));
    const float PI = 3.14159265358979323846f;
    float a0 = x0 - 1.5f, a1 = x1 - 1.5f, c0 = x0 - 4.5f, c1 = x1 - 4.5f;
    if (qd == 0) {
        f8[0] = x0;      f8[1] = x1;
        f8[2] = x0 * x0; f8[3] = x1 * x1;
        f8[4] = a0 * a0; f8[5] = a1 * a1;
        f8[6] = c0 * c0; f8[7] = c1 * c1;
    } else if (qd == 1) {
        f8[0] = sigm(x0); f8[1] = sigm(x1);
        f8[2] = sigm(a0); f8[3] = sigm(a1);
        f8[4] = sigm(c0); f8[5] = sigm(c1);
        f8[6] = a0;       f8[7] = a1;
    } else if (qd == 2) {
        f8[0] = c0; f8[1] = c1;
        f8[2] = __sinf(PI * x0);          f8[3] = __sinf(PI * x1);
        f8[4] = __cosf(PI * x0);          f8[5] = __cosf(PI * x1);
        f8[6] = __sinf(PI * 0.25f * x0);  f8[7] = __sinf(PI * 0.25f * x1);
    } else {
        f8[0] = __cosf(PI * 0.25f * x0);  f8[1] = __cosf(PI * 0.25f * x1);
        f8[2] = __sinf(PI * 0.5f * x0);   f8[3] = __sinf(PI * 0.5f * x1);
        f8[4] = __cosf(PI * 0.5f * x0);   f8[5] = __cosf(PI * 0.5f * x1);
        f8[6] = 0.f;                      f8[7] = 0.f;
    }
}

// ---------- canonicalize all inputs to bf16 (embedded dtype detection) ----------
struct ConvArgs {
    const void* p[22];
    int off[23];
};

__global__ __launch_bounds__(256) void convert_kernel(
    ConvArgs a, const unsigned short* __restrict__ pe_w_raw,
    int* __restrict__ flag, unsigned short* __restrict__ canon, int total)
{
    __shared__ int cnt;
    if (threadIdx.x == 0) cnt = 0;
    __syncthreads();
    float v = b2f(pe_w_raw[threadIdx.x * 2]);
    if (!(fabsf(v) < 1.0f)) atomicAdd(&cnt, 1);
    __syncthreads();
    int isf32 = (cnt >= 16) ? 1 : 0;
    if (blockIdx.x == 0 && threadIdx.x == 0) *flag = isf32;

    int g = blockIdx.x * 256 + threadIdx.x;
    if (g >= total) return;
    int s = 0;
    #pragma unroll
    for (int i = 1; i < 23; i++) s += (g >= a.off[i]) ? 1 : 0;
    int local = g - a.off[s];
    unsigned short r;
    if (isf32) r = f2b(((const float*)a.p[s])[local]);
    else       r = ((const unsigned short*)a.p[s])[local];
    canon[g] = r;
}

// ---------- boundary positional encoding (M rows, fp32 out) ----------
__global__ __launch_bounds__(256) void encode_kernel(
    const unsigned short* __restrict__ pts,
    const unsigned short* __restrict__ w,
    const unsigned short* __restrict__ b,
    float* __restrict__ out)
{
    __shared__ __align__(16) float wsm[30 * 128];
    __shared__ float bs[128];
    int t = threadIdx.x;
    for (int i = t; i < 30 * 128; i += 256) wsm[i] = b2f(w[i]);
    if (t < 128) bs[t] = b2f(b[t]);
    __syncthreads();

    int r = blockIdx.x * 8 + (t >> 5);
    int j = t & 31;
    float f[30];
    make_feats(pts, r, f);
    float s0 = bs[j * 4 + 0], s1 = bs[j * 4 + 1], s2 = bs[j * 4 + 2], s3 = bs[j * 4 + 3];
    #pragma unroll
    for (int ff = 0; ff < 30; ff++) {
        float4 wv = *(const float4*)&wsm[ff * 128 + j * 4];
        float fv = f[ff];
        s0 += fv * wv.x; s1 += fv * wv.y; s2 += fv * wv.z; s3 += fv * wv.w;
    }
    *(float4*)&out[(size_t)r * 128 + j * 4] =
        make_float4(__sinf(s0), __sinf(s1), __sinf(s2), __sinf(s3));
}

// ---------- boundary k/v heads (+ zeroing of kv/ks accumulators) ----------
__global__ __launch_bounds__(256) void khvh_kernel(
    const float* __restrict__ benc,
    const unsigned short* __restrict__ Wk, const unsigned short* __restrict__ bk,
    const unsigned short* __restrict__ Wv, const unsigned short* __restrict__ bv,
    float* __restrict__ kh, float* __restrict__ vh, float* __restrict__ kvz)
{
    int g = blockIdx.x * 256 + threadIdx.x;
    if (g < 12672) kvz[g] = 0.f;   // kvs(12288) + kss(384), contiguous
    int lh = g >> 17;
    int rem = g & 131071;
    int m = rem >> 5;
    int dd = rem & 31;
    const unsigned short* wk = Wk + lh * 4096 + dd;
    const unsigned short* wv = Wv + lh * 4096 + dd;
    const float* br = benc + (size_t)m * 128;
    float ka = 0.f, va = 0.f;
    #pragma unroll 8
    for (int c = 0; c < 128; c++) {
        float bb = br[c];
        ka += bb * b2f(wk[c * 32]);
        va += bb * b2f(wv[c * 32]);
    }
    ka += b2f(bk[lh * 32 + dd]); ka = ka * ka;
    va += b2f(bv[lh * 32 + dd]);
    kh[g] = ka; vh[g] = va;
}

// ---------- reduce over boundary points: kvsum[lh][d][e], ksum[lh][d] ----------
__global__ __launch_bounds__(1024) void kvred_kernel(
    const float* __restrict__ kh, const float* __restrict__ vh,
    float* __restrict__ kvsum, float* __restrict__ ksum)
{
    __shared__ float khs[1024];
    __shared__ float vhs[1024];
    int t = threadIdx.x;
    int lh = blockIdx.x >> 3;
    int part = blockIdx.x & 7;
    int dd = t >> 5, ee = t & 31;
    float kva = 0.f, ksa = 0.f;
    for (int ch = 0; ch < 16; ch++) {
        int base = lh * 131072 + (part * 16 + ch) * 1024;
        khs[t] = kh[base + t];
        vhs[t] = vh[base + t];
        __syncthreads();
        #pragma unroll
        for (int i = 0; i < 32; i++) {
            float kk = khs[i * 32 + dd];
            kva += kk * vhs[i * 32 + ee];
            ksa += kk;
        }
        __syncthreads();
    }
    atomicAdd(&kvsum[lh * 1024 + dd * 32 + ee], kva);
    if (ee == 0) atomicAdd(&ksum[lh * 32 + dd], ksa);
}

// ---------- prep: sigma rows + PRE-SWIZZLED storage + Wa fold + Ks ----------
// The five wbuf-staged matrices (wqT/waT/w1T/w2T/pw1T) are stored with the
// ushort-index involution swz_q applied, so a LINEAR global_load_lds copy
// followed by the XOR-swizzled wfrag read reconstructs the logical layout.
// ksT and pweT are read from global directly (no swizzle).
__global__ __launch_bounds__(256) void prep_kernel(
    const unsigned short* __restrict__ Wq, const unsigned short* __restrict__ W1,
    const unsigned short* __restrict__ W2, const unsigned short* __restrict__ pw1,
    const float* __restrict__ kvs, const float* __restrict__ kss,
    const unsigned short* __restrict__ Wo, const unsigned short* __restrict__ pe_w,
    unsigned short* __restrict__ wqT, unsigned short* __restrict__ w1T,
    unsigned short* __restrict__ w2T, unsigned short* __restrict__ pw1T,
    unsigned short* __restrict__ waT, unsigned short* __restrict__ ksT,
    unsigned short* __restrict__ pweT)
{
    int g = blockIdx.x * 256 + threadIdx.x;
    if (g < 49152) {
        int l = g >> 14, q = swz_q(g & 16383), n = q >> 7, k = q & 127;
        int na = fmap(n);   // head-interleaved actual col
        wqT[g] = Wq[((l * 4 + (na >> 5)) * 128 + k) * 32 + (na & 31)];
    } else if (g < 98304) {
        int q0 = g - 49152; int l = q0 >> 14, q = swz_q(q0 & 16383), n = q >> 7, k = q & 127;
        w1T[q0] = W1[(l * 128 + k) * 128 + fmap(n)];
    } else if (g < 147456) {
        int q0 = g - 98304; int l = q0 >> 14, q = swz_q(q0 & 16383), n = q >> 7, k = q & 127;
        w2T[q0] = W2[(l * 128 + k) * 128 + fmap(n)];
    } else if (g < 155648) {
        int q0 = g - 147456; int q = swz_q(q0), n = q >> 7, k = q & 127;
        pw1T[q0] = pw1[k * 64 + n];                      // linear cols (no sigma)
    } else if (g < 204800) {
        int q0 = g - 155648; int l = q0 >> 14, q = swz_q(q0 & 16383), n = q >> 7, k = q & 127;
        int na = fmap(n);
        int hk = k >> 5, dk = k & 31;
        const float* kvp = kvs + (l * 4 + hk) * 1024 + dk * 32;
        const unsigned short* wop = Wo + (size_t)(l * 128 + hk * 32) * 128 + na;
        float s = 0.f;
        #pragma unroll 8
        for (int j = 0; j < 32; j++) s += kvp[j] * b2f(wop[j * 128]);
        waT[q0] = f2b(s);
    } else if (g < 210944) {
        int q = g - 204800; int l = q >> 11, r = q & 2047, n = r >> 7, k = r & 127;
        unsigned short v = 0;
        if (n < 4 && (k >> 5) == n) v = f2b(kss[(l * 4 + n) * 32 + (k & 31)]);
        ksT[q] = v;                                      // linear (no swizzle)
    } else if (g < 215040) {
        int q = g - 210944; int n = q >> 5, k = q & 31;  // pe_wT [128 slot][32]
        pweT[q] = (k < 30) ? pe_w[k * 128 + fmap(n)] : (unsigned short)0;
    }
}

// ---------- the fused mega kernel: encode + 3 layers + projector ----------
// ROUND-6 (post-mortem of R5: occupancy collapsed to 1 wave/SIMD — sreg[8]
// pushed unified VGPR+AGPR past 256):
//  * Staging via __builtin_amdgcn_global_load_lds width=16 into a
//    DOUBLE-BUFFERED wbuf[2] (64KB). sreg deleted (-32 VGPR -> 2 waves/SIMD),
//    staging is ~free of VALU, and each gll issue runs a FULL mm before its
//    draining barrier (4 barriers/layer, every load latency covered).
//  * Weights are PRE-SWIZZLED in global by prep (swz_q involution) so the
//    linear gll write + XOR wfrag read are consistent (rule #21).
//  * exp2-form GELU (log2e folded into constants; v_exp_f32 is 2^x).
//  * Everything else from R4/R5 kept: sigma C->B register renaming, pkd/hres
//    register-resident activations, per-lane projector tail.

template<int ITERS>
__device__ __forceinline__ void stage_gll(const unsigned short* __restrict__ g,
                                          unsigned short* __restrict__ lbase,
                                          int wvi, int ln) {
    const char* gp = (const char*)g + wvi * 1024 + ln * 16;
    char* lp = (char*)lbase + wvi * 1024;     // wave-uniform LDS base
    #pragma unroll
    for (int i = 0; i < ITERS; i++) {
        __builtin_amdgcn_global_load_lds(
            (const __attribute__((address_space(1))) unsigned int*)(gp + i * 4096),
            (__attribute__((address_space(3))) unsigned int*)(lp + i * 4096),
            16, 0, 0);
    }
}

// swizzled weight-fragment read: ntile nt, k-slice k, lane (qd,l16)
__device__ __forceinline__ s8v wfrag(const unsigned short* __restrict__ wb,
                                     int nt, int k, int l16, int qd) {
    int lin = (nt << 12) + (l16 << 8) + (k << 6) + (qd << 4);
    return *(const s8v*)((const char*)wb + (lin ^ ((l16 & 7) << 4)));
}

// dual-ntile, dual-rowtile matmul; B-frags renamed from pkd (sigma layout).
// Epilogue sees: nt (0..7), tile (0/1), x (f4v) = slot (nt,qd,i) of row
// rA0 + tile*16; actual col = cb + i with cb below.
#define MM_BODY(WB, EPI...) do {                                              \
    s8v bf0[4], bf1[4];                                                       \
    _Pragma("unroll")                                                         \
    for (int _s = 0; _s < 4; _s++) {                                          \
        bf0[_s] = mkfrag(pkd[0][2*_s][0], pkd[0][2*_s][1],                    \
                         pkd[0][2*_s+1][0], pkd[0][2*_s+1][1]);               \
        bf1[_s] = mkfrag(pkd[1][2*_s][0], pkd[1][2*_s][1],                    \
                         pkd[1][2*_s+1][0], pkd[1][2*_s+1][1]);               \
    }                                                                         \
    _Pragma("unroll")                                                         \
    for (int _p = 0; _p < 4; _p++) {                                          \
        f4v _x0 = {0.f,0.f,0.f,0.f}, _x1 = _x0, _y0 = _x0, _y1 = _x0;         \
        _Pragma("unroll")                                                     \
        for (int _k = 0; _k < 4; _k++) {                                      \
            s8v _wa = wfrag(WB, _p * 2,     _k, l16, qd);                     \
            s8v _wb = wfrag(WB, _p * 2 + 1, _k, l16, qd);                     \
            _x0 = MFMA_BF16(_wa, bf0[_k], _x0, 0, 0, 0);                      \
            _x1 = MFMA_BF16(_wa, bf1[_k], _x1, 0, 0, 0);                      \
            _y0 = MFMA_BF16(_wb, bf0[_k], _y0, 0, 0, 0);                      \
            _y1 = MFMA_BF16(_wb, bf1[_k], _y1, 0, 0, 0);                      \
        }                                                                     \
        { const int nt = _p * 2;     const int tile = 0; const f4v x = _x0; EPI } \
        { const int nt = _p * 2;     const int tile = 1; const f4v x = _x1; EPI } \
        { const int nt = _p * 2 + 1; const int tile = 0; const f4v x = _y0; EPI } \
        { const int nt = _p * 2 + 1; const int tile = 1; const f4v x = _y1; EPI } \
    }                                                                         \
} while (0)

#define CBDEF int cb = ((nt >> 1) << 5) + (qd << 3) + ((nt & 1) << 2)

__global__ __launch_bounds__(256) void mega_kernel(
    const unsigned short* __restrict__ qpts,
    const unsigned short* __restrict__ pweT,
    const unsigned short* __restrict__ pe_b,
    const unsigned short* __restrict__ wqT,
    const unsigned short* __restrict__ waT,
    const unsigned short* __restrict__ ksT,
    const unsigned short* __restrict__ w1T,
    const unsigned short* __restrict__ w2T,
    const unsigned short* __restrict__ bq,
    const unsigned short* __restrict__ bo,
    const unsigned short* __restrict__ b1,
    const unsigned short* __restrict__ b2,
    const unsigned short* __restrict__ pw1T,
    const unsigned short* __restrict__ pb1,
    const unsigned short* __restrict__ pw2,
    const unsigned short* __restrict__ pb2,
    void* __restrict__ outv, const int* __restrict__ flag)
{
    __shared__ __align__(16) unsigned short wbuf[2][16384];  // 65536 B, dbuf
    __shared__ __align__(16) float biasAll[12 * 128];        // 6144 B
    __shared__ __align__(16) float pebs[128];
    __shared__ __align__(16) float pb1s[64];
    __shared__ __align__(16) float w2s4[256];                // w2 cols padded
    __shared__ float pb2s[3];

    int t = threadIdx.x;
    int wvi = t >> 6, ln = t & 63, qd = ln >> 4, l16 = ln & 15;
    int row0 = blockIdx.x * 128;
    int rA0 = wvi * 32 + l16;        // lane's row, tile 0 (tile 1: +16)
    unsigned short* wb0 = &wbuf[0][0];
    unsigned short* wb1 = &wbuf[1][0];

    // issue wq[0] -> buf0 immediately (latency covered by bias staging)
    stage_gll<8>(wqT, wb0, wvi, ln);

    // ===== one-time staging =====
    for (int i = t; i < 1536; i += 256) {
        int l = i >> 9, rem = i & 511, which = rem >> 7, c = rem & 127;
        const unsigned short* bsrc = (which == 0) ? bq : (which == 1) ? bo
                                   : (which == 2) ? b1 : b2;
        biasAll[i] = b2f(bsrc[l * 128 + c]);
    }
    if (t < 128) pebs[t] = b2f(pe_b[t]);
    if (t < 64)  pb1s[t] = b2f(pb1[t]);
    if (t < 64) {
        w2s4[t * 4 + 0] = b2f(pw2[t * 3 + 0]);
        w2s4[t * 4 + 1] = b2f(pw2[t * 3 + 1]);
        w2s4[t * 4 + 2] = b2f(pw2[t * 3 + 2]);
        w2s4[t * 4 + 3] = 0.f;
    }
    if (t < 3) pb2s[t] = b2f(pb2[t]);
    __syncthreads();   // drains wq[0] gll; bias tables visible

    // issue waT[0] -> buf1; encode covers its latency
    stage_gll<8>(waT, wb1, wvi, ln);

    unsigned pkd[2][8][2];   // packed bf16 activations, slot layout
    float hres[2][8][4];     // fp32 residual, slot layout

    // ===== encode via MFMA: h = sin(feats @ pe_w + pe_b), pweT sigma'd =====
    {
        unsigned pq0 = *(const unsigned*)(qpts + (size_t)(row0 + rA0) * 2);
        unsigned pq1 = *(const unsigned*)(qpts + (size_t)(row0 + rA0 + 16) * 2);
        s8v ae0, ae1;
        {
            float f8[8]; feats8(pq0, qd, f8);
            unsigned* au = (unsigned*)&ae0;
            #pragma unroll
            for (int jj = 0; jj < 4; jj++) au[jj] = pk_bf16(f8[2 * jj], f8[2 * jj + 1]);
        }
        {
            float f8[8]; feats8(pq1, qd, f8);
            unsigned* au = (unsigned*)&ae1;
            #pragma unroll
            for (int jj = 0; jj < 4; jj++) au[jj] = pk_bf16(f8[2 * jj], f8[2 * jj + 1]);
        }
        const unsigned short* pb = pweT + l16 * 32 + qd * 8;
        #pragma unroll
        for (int nt = 0; nt < 8; nt++) {
            s8v aw = *(const s8v*)(pb + nt * 512);
            f4v x0 = {0.f, 0.f, 0.f, 0.f}, x1 = {0.f, 0.f, 0.f, 0.f};
            x0 = MFMA_BF16(aw, ae0, x0, 0, 0, 0);
            x1 = MFMA_BF16(aw, ae1, x1, 0, 0, 0);
            CBDEF;
            float4 bb = *(const float4*)&pebs[cb];
            float h0 = __sinf(x0[0] + bb.x), h1 = __sinf(x0[1] + bb.y);
            float h2 = __sinf(x0[2] + bb.z), h3 = __sinf(x0[3] + bb.w);
            hres[0][nt][0] = h0; hres[0][nt][1] = h1;
            hres[0][nt][2] = h2; hres[0][nt][3] = h3;
            pkd[0][nt][0] = pk_bf16(h0, h1);
            pkd[0][nt][1] = pk_bf16(h2, h3);
            float g0 = __sinf(x1[0] + bb.x), g1 = __sinf(x1[1] + bb.y);
            float g2 = __sinf(x1[2] + bb.z), g3 = __sinf(x1[3] + bb.w);
            hres[1][nt][0] = g0; hres[1][nt][1] = g1;
            hres[1][nt][2] = g2; hres[1][nt][3] = g3;
            pkd[1][nt][0] = pk_bf16(g0, g1);
            pkd[1][nt][1] = pk_bf16(g2, g3);
        }
    }

    // ===== 3 transformer layers (double-buffered weight pipeline) =====
    // invariant at layer top: buf0 = wq[l] resident; waT[l] in flight -> buf1
    for (int l = 0; l < 3; l++) {
        const float* bql = &biasAll[(l * 4 + 0) * 128];
        const float* bol = &biasAll[(l * 4 + 1) * 128];
        const float* b1l = &biasAll[(l * 4 + 2) * 128];
        const float* b2l = &biasAll[(l * 4 + 3) * 128];

        // issue kf loads early (resident by den)
        s8v kf[4];
        {
            const unsigned short* kb = ksT + l * 2048 + l16 * 128 + qd * 8;
            #pragma unroll
            for (int ks = 0; ks < 4; ks++) kf[ks] = *(const s8v*)(kb + ks * 32);
        }

        // mm1: qh = (h @ Wq + bq)^2 -> pkd (reads buf0)
        MM_BODY(wb0, {
            CBDEF;
            float4 bb = *(const float4*)&bql[cb];
            float v0 = x[0] + bb.x, v1 = x[1] + bb.y;
            float v2 = x[2] + bb.z, v3 = x[3] + bb.w;
            pkd[tile][nt][0] = pk_bf16(v0 * v0, v1 * v1);
            pkd[tile][nt][1] = pk_bf16(v2 * v2, v3 * v3);
        });
        __syncthreads();                 // B1: buf0 free; waT[l] drained
        stage_gll<8>(w1T + l * 16384, wb0, wvi, ln);

        // den: d[h] = qh_row . ksum_h (A = ksT rows, B = qh rename); z-scale
        #pragma unroll
        for (int tile = 0; tile < 2; tile++) {
            f4v d = {0.f, 0.f, 0.f, 0.f};
            #pragma unroll
            for (int ks = 0; ks < 4; ks++) {
                s8v b = mkfrag(pkd[tile][2 * ks][0], pkd[tile][2 * ks][1],
                               pkd[tile][2 * ks + 1][0], pkd[tile][2 * ks + 1][1]);
                d = MFMA_BF16(kf[ks], b, d, 0, 0, 0);
            }
            #pragma unroll
            for (int ks = 0; ks < 4; ks++) {
                float z = 1.f / (__shfl(d[ks], l16) + 1e-6f);
                #pragma unroll
                for (int h2 = 0; h2 < 2; h2++) {
                    #pragma unroll
                    for (int j = 0; j < 2; j++) {
                        unsigned w = pkd[tile][2 * ks + h2][j];
                        float lo = __uint_as_float(w << 16) * z;
                        float hi = __uint_as_float(w & 0xffff0000u) * z;
                        pkd[tile][2 * ks + h2][j] = pk_bf16(lo, hi);
                    }
                }
            }
        }

        // mm2: x = h + (z*qh) @ Wa + bo -> hres, pkd (reads buf1, drained @B1)
        MM_BODY(wb1, {
            CBDEF;
            float4 bb = *(const float4*)&bol[cb];
            float v0 = hres[tile][nt][0] + x[0] + bb.x;
            float v1 = hres[tile][nt][1] + x[1] + bb.y;
            float v2 = hres[tile][nt][2] + x[2] + bb.z;
            float v3 = hres[tile][nt][3] + x[3] + bb.w;
            hres[tile][nt][0] = v0; hres[tile][nt][1] = v1;
            hres[tile][nt][2] = v2; hres[tile][nt][3] = v3;
            pkd[tile][nt][0] = pk_bf16(v0, v1);
            pkd[tile][nt][1] = pk_bf16(v2, v3);
        });
        __syncthreads();                 // B2: buf1 free; w1T drained
        stage_gll<8>(w2T + l * 16384, wb1, wvi, ln);

        // mm3: t = gelu(x @ W1 + b1) -> pkd (reads buf0)
        MM_BODY(wb0, {
            CBDEF;
            float4 bb = *(const float4*)&b1l[cb];
            float g0 = gelu_l(x[0] + bb.x), g1 = gelu_l(x[1] + bb.y);
            float g2 = gelu_l(x[2] + bb.z), g3 = gelu_l(x[3] + bb.w);
            pkd[tile][nt][0] = pk_bf16(g0, g1);
            pkd[tile][nt][1] = pk_bf16(g2, g3);
        });
        __syncthreads();                 // B3: buf0 free; w2T drained
        if (l < 2) stage_gll<8>(wqT + (l + 1) * 16384, wb0, wvi, ln);
        else       stage_gll<4>(pw1T, wb0, wvi, ln);

        // mm4: h_new = x + t @ W2 + b2 -> hres, pkd (reads buf1)
        MM_BODY(wb1, {
            CBDEF;
            float4 bb = *(const float4*)&b2l[cb];
            float v0 = hres[tile][nt][0] + x[0] + bb.x;
            float v1 = hres[tile][nt][1] + x[1] + bb.y;
            float v2 = hres[tile][nt][2] + x[2] + bb.z;
            float v3 = hres[tile][nt][3] + x[3] + bb.w;
            hres[tile][nt][0] = v0; hres[tile][nt][1] = v1;
            hres[tile][nt][2] = v2; hres[tile][nt][3] = v3;
            pkd[tile][nt][0] = pk_bf16(v0, v1);
            pkd[tile][nt][1] = pk_bf16(v2, v3);
        });
        __syncthreads();                 // B4: buf1 free; wq[l+1]/pw1T drained
        if (l < 2) stage_gll<8>(waT + (l + 1) * 16384, wb1, wvi, ln);
    }

    // ===== final projector: out = gelu(h @ pw1 + pb1) @ pw2 + pb2 =====
    // buf0 holds pw1T (drained at the last B4)
    {
        s8v bf0[4], bf1[4];
        #pragma unroll
        for (int ks = 0; ks < 4; ks++) {
            bf0[ks] = mkfrag(pkd[0][2 * ks][0], pkd[0][2 * ks][1],
                             pkd[0][2 * ks + 1][0], pkd[0][2 * ks + 1][1]);
            bf1[ks] = mkfrag(pkd[1][2 * ks][0], pkd[1][2 * ks][1],
                             pkd[1][2 * ks + 1][0], pkd[1][2 * ks + 1][1]);
        }
        float pt0[3] = {0.f, 0.f, 0.f}, pt1[3] = {0.f, 0.f, 0.f};
        #pragma unroll
        for (int p = 0; p < 2; p++) {
            f4v y00 = {0.f,0.f,0.f,0.f}, y01 = y00, y10 = y00, y11 = y00;
            #pragma unroll
            for (int ks = 0; ks < 4; ks++) {
                s8v wa = wfrag(wb0, p * 2,     ks, l16, qd);
                s8v wb = wfrag(wb0, p * 2 + 1, ks, l16, qd);
                y00 = MFMA_BF16(wa, bf0[ks], y00, 0, 0, 0);
                y01 = MFMA_BF16(wa, bf1[ks], y01, 0, 0, 0);
                y10 = MFMA_BF16(wb, bf0[ks], y10, 0, 0, 0);
                y11 = MFMA_BF16(wb, bf1[ks], y11, 0, 0, 0);
            }
            #pragma unroll
            for (int e = 0; e < 2; e++) {
                int c0 = (p * 2 + e) * 16 + qd * 4;   // pw1T linear -> actual col
                float4 bb = *(const float4*)&pb1s[c0];
                f4v ya = e ? y10 : y00;   // tile 0
                f4v yb = e ? y11 : y01;   // tile 1
                #pragma unroll
                for (int i = 0; i < 4; i++) {
                    float bbi = (i == 0) ? bb.x : (i == 1) ? bb.y : (i == 2) ? bb.z : bb.w;
                    float4 w = *(const float4*)&w2s4[(c0 + i) * 4];
                    float ga = gelu_l(ya[i] + bbi);
                    float gb = gelu_l(yb[i] + bbi);
                    pt0[0] = fmaf(ga, w.x, pt0[0]);
                    pt0[1] = fmaf(ga, w.y, pt0[1]);
                    pt0[2] = fmaf(ga, w.z, pt0[2]);
                    pt1[0] = fmaf(gb, w.x, pt1[0]);
                    pt1[1] = fmaf(gb, w.y, pt1[1]);
                    pt1[2] = fmaf(gb, w.z, pt1[2]);
                }
            }
        }
        // reduce over the qd group (lane bits 4-5), then lane qd==0 stores
        #pragma unroll
        for (int c = 0; c < 3; c++) {
            pt0[c] += __shfl_xor(pt0[c], 16); pt0[c] += __shfl_xor(pt0[c], 32);
            pt1[c] += __shfl_xor(pt1[c], 16); pt1[c] += __shfl_xor(pt1[c], 32);
            pt0[c] += pb2s[c]; pt1[c] += pb2s[c];
        }
        if (ln < 16) {
            size_t r0 = (size_t)(row0 + rA0) * 3;
            size_t r1 = (size_t)(row0 + rA0 + 16) * 3;
            if (*flag) {
                float* o = (float*)outv;
                o[r0] = pt0[0]; o[r0 + 1] = pt0[1]; o[r0 + 2] = pt0[2];
                o[r1] = pt1[0]; o[r1 + 1] = pt1[1]; o[r1 + 2] = pt1[2];
            } else {
                unsigned short* o = (unsigned short*)outv;
                o[r0] = f2b(pt0[0]); o[r0 + 1] = f2b(pt0[1]); o[r0 + 2] = f2b(pt0[2]);
                o[r1] = f2b(pt1[0]); o[r1 + 1] = f2b(pt1[1]); o[r1 + 2] = f2b(pt1[2]);
            }
        }
    }
}

// ---------- launch ----------
extern "C" void kernel_launch(void* const* d_in, const int* in_sizes, int n_in,
                              void* d_out, int out_size, void* d_ws, size_t ws_size,
                              hipStream_t stream) {
    const int N = in_sizes[0] / 2;   // 262144
    const int M = in_sizes[1] / 2;   // 4096

    ConvArgs ca;
    int total = 0;
    for (int i = 0; i < 22; i++) { ca.p[i] = d_in[i]; ca.off[i] = total; total += in_sizes[i]; }
    ca.off[22] = total;

    float* ws = (float*)d_ws;
    int* flag = (int*)ws;
    unsigned short* canon = (unsigned short*)(ws + 16);
    size_t canonF = ((size_t)(total + 1) / 2 + 15) & ~(size_t)15;
    float* b_enc = ws + 16 + canonF;                       // M*128
    float* khb   = b_enc + (size_t)M * 128;                // 12*M*32
    float* vhb   = khb + (size_t)12 * M * 32;              // 12*M*32
    float* kvs   = vhb + (size_t)12 * M * 32;              // 12288
    float* kss   = kvs + 12288;                            // 384
    unsigned short* wqT  = (unsigned short*)(kss + 384);   // 3*16384
    unsigned short* waT  = wqT + 49152;
    unsigned short* w1T  = waT + 49152;
    unsigned short* w2T  = w1T + 49152;
    unsigned short* ksT  = w2T + 49152;                    // 3*2048
    unsigned short* pw1T = ksT + 6144;                     // 8192
    unsigned short* pweT = pw1T + 8192;                    // 4096

    const unsigned short* c_qpts = canon + ca.off[0];
    const unsigned short* c_bpts = canon + ca.off[1];
    const unsigned short* c_pew  = canon + ca.off[2];
    const unsigned short* c_peb  = canon + ca.off[3];
    const unsigned short* c_bpew = canon + ca.off[4];
    const unsigned short* c_bpeb = canon + ca.off[5];
    const unsigned short* c_Wq   = canon + ca.off[6];
    const unsigned short* c_bq   = canon + ca.off[7];
    const unsigned short* c_Wk   = canon + ca.off[8];
    const unsigned short* c_bk   = canon + ca.off[9];
    const unsigned short* c_Wv   = canon + ca.off[10];
    const unsigned short* c_bv   = canon + ca.off[11];
    const unsigned short* c_Wo   = canon + ca.off[12];
    const unsigned short* c_bo   = canon + ca.off[13];
    const unsigned short* c_W1   = canon + ca.off[14];
    const unsigned short* c_b1   = canon + ca.off[15];
    const unsigned short* c_W2   = canon + ca.off[16];
    const unsigned short* c_b2   = canon + ca.off[17];
    const unsigned short* c_pw1  = canon + ca.off[18];
    const unsigned short* c_pb1  = canon + ca.off[19];
    const unsigned short* c_pw2  = canon + ca.off[20];
    const unsigned short* c_pb2  = canon + ca.off[21];

    convert_kernel<<<(total + 255) / 256, 256, 0, stream>>>(
        ca, (const unsigned short*)d_in[2], flag, canon, total);

    encode_kernel<<<M / 8, 256, 0, stream>>>(c_bpts, c_bpew, c_bpeb, b_enc);
    khvh_kernel<<<(12 * M * 32) / 256, 256, 0, stream>>>(
        b_enc, c_Wk, c_bk, c_Wv, c_bv, khb, vhb, kvs);
    kvred_kernel<<<96, 1024, 0, stream>>>(khb, vhb, kvs, kss);
    prep_kernel<<<215040 / 256, 256, 0, stream>>>(
        c_Wq, c_W1, c_W2, c_pw1, kvs, kss, c_Wo, c_pew,
        wqT, w1T, w2T, pw1T, waT, ksT, pweT);

    mega_kernel<<<N / 128, 256, 0, stream>>>(
        c_qpts, pweT, c_peb, wqT, waT, ksT, w1T, w2T,
        c_bq, c_bo, c_b1, c_b2, pw1T, c_pb1, c_pw2, c_pb2, d_out, flag);
}

// Round 7
// 357.443 us; speedup vs baseline: 2.6153x; 1.0199x over previous
//
#include <hip/hip_runtime.h>
#include <hip/hip_bf16.h>

// ---------- helpers ----------
__device__ __forceinline__ float b2f(unsigned short u) {
    return __uint_as_float(((unsigned)u) << 16);
}
__device__ __forceinline__ unsigned short f2b(float f) {
    __hip_bfloat16 h = __float2bfloat16(f);
    return *reinterpret_cast<unsigned short*>(&h);
}
// pack two f32 -> packed 2x bf16 (RNE), single VALU op
__device__ __forceinline__ unsigned pk_bf16(float lo, float hi) {
    unsigned r;
    asm("v_cvt_pk_bf16_f32 %0, %1, %2" : "=v"(r) : "v"(lo), "v"(hi));
    return r;
}
// hardware exp2 (v_exp_f32 computes 2^x)
__device__ __forceinline__ float exp2_hw(float x) {
    float r;
    asm("v_exp_f32 %0, %1" : "=v"(r) : "v"(x));
    return r;
}
__device__ __forceinline__ float sigm(float v) {
    return 1.f / (1.f + __expf(-v));
}
// lean tanh-approx GELU, exp2 form: g = x - x/(1+2^(x*(c1+c2*x^2)))
__device__ __forceinline__ float gelu_l(float x) {
    float x2 = x * x;
    float y  = x * __builtin_fmaf(0.10294535f, x2, 2.3022137f);
    float e  = exp2_hw(y);
    float r  = __builtin_amdgcn_rcpf(e + 1.f);
    return __builtin_fmaf(-x, r, x);
}

typedef __attribute__((ext_vector_type(8))) short s8v;   // 8 bf16 (4 VGPRs)
typedef __attribute__((ext_vector_type(4))) float f4v;   // 4 fp32 acc
typedef __attribute__((ext_vector_type(2))) float f2v;   // fp32 pair (v_pk_*)

#define MFMA_BF16 __builtin_amdgcn_mfma_f32_16x16x32_bf16

__device__ __forceinline__ s8v mkfrag(unsigned a, unsigned b, unsigned c, unsigned d) {
    union { unsigned u[4]; s8v v; } x;
    x.u[0] = a; x.u[1] = b; x.u[2] = c; x.u[3] = d;
    return x.v;
}

// sigma: slot s -> actual column. s{i[1:0],qd[1:0],ntlo,nthi[1:0]} ->
// c{i[1:0], ntlo, qd[1:0], nthi[1:0]}. Bijective bit permutation.
// With weight ROWS stored at slots, the MFMA C output of slot (nt,qd,i) is
// actual col (nt>>1)*32 + qd*8 + (nt&1)*4 + i -> each lane's C is exactly
// the next mm's B-fragment (lane-local renaming, no LDS round-trip).
__device__ __forceinline__ int fmap(int s) {
    return (s & ~31) | (((s >> 2) & 3) << 3) | (((s >> 4) & 1) << 2) | (s & 3);
}
// inverse LDS bank swizzle applied in GLOBAL memory (ushort index involution):
// gll copies linearly, wfrag reads with byte XOR ((l16&7)<<4); pre-permuting
// the source by the same involution keeps both sides consistent.
__device__ __forceinline__ int swz_q(int q) {
    return q ^ (((q >> 7) & 7) << 3);
}

// ---------- 15-feature map (full, for the boundary path) ----------
__device__ __forceinline__ void make_feats(const unsigned short* __restrict__ qpts,
                                           int r, float* __restrict__ f) {
    unsigned pq = *(const unsigned*)(qpts + (size_t)r * 2);
    float x0 = b2f((unsigned short)(pq & 0xffff));
    float x1 = b2f((unsigned short)(pq >> 16));
    const float PI = 3.14159265358979323846f;
    float a0 = x0 - 1.5f, a1 = x1 - 1.5f, c0 = x0 - 4.5f, c1 = x1 - 4.5f;
    f[0] = x0;        f[1] = x1;
    f[2] = x0 * x0;   f[3] = x1 * x1;
    f[4] = a0 * a0;   f[5] = a1 * a1;
    f[6] = c0 * c0;   f[7] = c1 * c1;
    f[8] = sigm(x0);  f[9] = sigm(x1);
    f[10] = sigm(a0); f[11] = sigm(a1);
    f[12] = sigm(c0); f[13] = sigm(c1);
    f[14] = a0;       f[15] = a1;
    f[16] = c0;       f[17] = c1;
    f[18] = __sinf(PI * x0);          f[19] = __sinf(PI * x1);
    f[20] = __cosf(PI * x0);          f[21] = __cosf(PI * x1);
    f[22] = __sinf(PI * 0.25f * x0);  f[23] = __sinf(PI * 0.25f * x1);
    f[24] = __cosf(PI * 0.25f * x0);  f[25] = __cosf(PI * 0.25f * x1);
    f[26] = __sinf(PI * 0.5f * x0);   f[27] = __sinf(PI * 0.5f * x1);
    f[28] = __cosf(PI * 0.5f * x0);   f[29] = __cosf(PI * 0.5f * x1);
}

// 8 features for k = qd*8 .. qd*8+7 (quad-split of the 30-vector, 30/31 -> 0)
__device__ __forceinline__ void feats8(unsigned pq, int qd, float* __restrict__ f8) {
    float x0 = b2f((unsigned short)(pq & 0xffff));
    float x1 = b2f((unsigned short)(pq >> 16));
    const float PI = 3.14159265358979323846f;
    float a0 = x0 - 1.5f, a1 = x1 - 1.5f, c0 = x0 - 4.5f, c1 = x1 - 4.5f;
    if (qd == 0) {
        f8[0] = x0;      f8[1] = x1;
        f8[2] = x0 * x0; f8[3] = x1 * x1;
        f8[4] = a0 * a0; f8[5] = a1 * a1;
        f8[6] = c0 * c0; f8[7] = c1 * c1;
    } else if (qd == 1) {
        f8[0] = sigm(x0); f8[1] = sigm(x1);
        f8[2] = sigm(a0); f8[3] = sigm(a1);
        f8[4] = sigm(c0); f8[5] = sigm(c1);
        f8[6] = a0;       f8[7] = a1;
    } else if (qd == 2) {
        f8[0] = c0; f8[1] = c1;
        f8[2] = __sinf(PI * x0);          f8[3] = __sinf(PI * x1);
        f8[4] = __cosf(PI * x0);          f8[5] = __cosf(PI * x1);
        f8[6] = __sinf(PI * 0.25f * x0);  f8[7] = __sinf(PI * 0.25f * x1);
    } else {
        f8[0] = __cosf(PI * 0.25f * x0);  f8[1] = __cosf(PI * 0.25f * x1);
        f8[2] = __sinf(PI * 0.5f * x0);   f8[3] = __sinf(PI * 0.5f * x1);
        f8[4] = __cosf(PI * 0.5f * x0);   f8[5] = __cosf(PI * 0.5f * x1);
        f8[6] = 0.f;                      f8[7] = 0.f;
    }
}

// ---------- canonicalize all inputs to bf16 (embedded dtype detection) ----------
struct ConvArgs {
    const void* p[22];
    int off[23];
};

__global__ __launch_bounds__(256) void convert_kernel(
    ConvArgs a, const unsigned short* __restrict__ pe_w_raw,
    int* __restrict__ flag, unsigned short* __restrict__ canon, int total)
{
    __shared__ int cnt;
    if (threadIdx.x == 0) cnt = 0;
    __syncthreads();
    float v = b2f(pe_w_raw[threadIdx.x * 2]);
    if (!(fabsf(v) < 1.0f)) atomicAdd(&cnt, 1);
    __syncthreads();
    int isf32 = (cnt >= 16) ? 1 : 0;
    if (blockIdx.x == 0 && threadIdx.x == 0) *flag = isf32;

    int g = blockIdx.x * 256 + threadIdx.x;
    if (g >= total) return;
    int s = 0;
    #pragma unroll
    for (int i = 1; i < 23; i++) s += (g >= a.off[i]) ? 1 : 0;
    int local = g - a.off[s];
    unsigned short r;
    if (isf32) r = f2b(((const float*)a.p[s])[local]);
    else       r = ((const unsigned short*)a.p[s])[local];
    canon[g] = r;
}

// ---------- boundary positional encoding (M rows, fp32 out) ----------
__global__ __launch_bounds__(256) void encode_kernel(
    const unsigned short* __restrict__ pts,
    const unsigned short* __restrict__ w,
    const unsigned short* __restrict__ b,
    float* __restrict__ out)
{
    __shared__ __align__(16) float wsm[30 * 128];
    __shared__ float bs[128];
    int t = threadIdx.x;
    for (int i = t; i < 30 * 128; i += 256) wsm[i] = b2f(w[i]);
    if (t < 128) bs[t] = b2f(b[t]);
    __syncthreads();

    int r = blockIdx.x * 8 + (t >> 5);
    int j = t & 31;
    float f[30];
    make_feats(pts, r, f);
    float s0 = bs[j * 4 + 0], s1 = bs[j * 4 + 1], s2 = bs[j * 4 + 2], s3 = bs[j * 4 + 3];
    #pragma unroll
    for (int ff = 0; ff < 30; ff++) {
        float4 wv = *(const float4*)&wsm[ff * 128 + j * 4];
        float fv = f[ff];
        s0 += fv * wv.x; s1 += fv * wv.y; s2 += fv * wv.z; s3 += fv * wv.w;
    }
    *(float4*)&out[(size_t)r * 128 + j * 4] =
        make_float4(__sinf(s0), __sinf(s1), __sinf(s2), __sinf(s3));
}

// ---------- boundary k/v heads (+ zeroing of kv/ks accumulators) ----------
__global__ __launch_bounds__(256) void khvh_kernel(
    const float* __restrict__ benc,
    const unsigned short* __restrict__ Wk, const unsigned short* __restrict__ bk,
    const unsigned short* __restrict__ Wv, const unsigned short* __restrict__ bv,
    float* __restrict__ kh, float* __restrict__ vh, float* __restrict__ kvz)
{
    int g = blockIdx.x * 256 + threadIdx.x;
    if (g < 12672) kvz[g] = 0.f;   // kvs(12288) + kss(384), contiguous
    int lh = g >> 17;
    int rem = g & 131071;
    int m = rem >> 5;
    int dd = rem & 31;
    const unsigned short* wk = Wk + lh * 4096 + dd;
    const unsigned short* wv = Wv + lh * 4096 + dd;
    const float* br = benc + (size_t)m * 128;
    float ka = 0.f, va = 0.f;
    #pragma unroll 8
    for (int c = 0; c < 128; c++) {
        float bb = br[c];
        ka += bb * b2f(wk[c * 32]);
        va += bb * b2f(wv[c * 32]);
    }
    ka += b2f(bk[lh * 32 + dd]); ka = ka * ka;
    va += b2f(bv[lh * 32 + dd]);
    kh[g] = ka; vh[g] = va;
}

// ---------- reduce over boundary points: kvsum[lh][d][e], ksum[lh][d] ----------
__global__ __launch_bounds__(1024) void kvred_kernel(
    const float* __restrict__ kh, const float* __restrict__ vh,
    float* __restrict__ kvsum, float* __restrict__ ksum)
{
    __shared__ float khs[1024];
    __shared__ float vhs[1024];
    int t = threadIdx.x;
    int lh = blockIdx.x >> 3;
    int part = blockIdx.x & 7;
    int dd = t >> 5, ee = t & 31;
    float kva = 0.f, ksa = 0.f;
    for (int ch = 0; ch < 16; ch++) {
        int base = lh * 131072 + (part * 16 + ch) * 1024;
        khs[t] = kh[base + t];
        vhs[t] = vh[base + t];
        __syncthreads();
        #pragma unroll
        for (int i = 0; i < 32; i++) {
            float kk = khs[i * 32 + dd];
            kva += kk * vhs[i * 32 + ee];
            ksa += kk;
        }
        __syncthreads();
    }
    atomicAdd(&kvsum[lh * 1024 + dd * 32 + ee], kva);
    if (ee == 0) atomicAdd(&ksum[lh * 32 + dd], ksa);
}

// ---------- prep: sigma rows + PRE-SWIZZLED storage + Wa fold + Ks ----------
__global__ __launch_bounds__(256) void prep_kernel(
    const unsigned short* __restrict__ Wq, const unsigned short* __restrict__ W1,
    const unsigned short* __restrict__ W2, const unsigned short* __restrict__ pw1,
    const float* __restrict__ kvs, const float* __restrict__ kss,
    const unsigned short* __restrict__ Wo, const unsigned short* __restrict__ pe_w,
    unsigned short* __restrict__ wqT, unsigned short* __restrict__ w1T,
    unsigned short* __restrict__ w2T, unsigned short* __restrict__ pw1T,
    unsigned short* __restrict__ waT, unsigned short* __restrict__ ksT,
    unsigned short* __restrict__ pweT)
{
    int g = blockIdx.x * 256 + threadIdx.x;
    if (g < 49152) {
        int l = g >> 14, q = swz_q(g & 16383), n = q >> 7, k = q & 127;
        int na = fmap(n);   // head-interleaved actual col
        wqT[g] = Wq[((l * 4 + (na >> 5)) * 128 + k) * 32 + (na & 31)];
    } else if (g < 98304) {
        int q0 = g - 49152; int l = q0 >> 14, q = swz_q(q0 & 16383), n = q >> 7, k = q & 127;
        w1T[q0] = W1[(l * 128 + k) * 128 + fmap(n)];
    } else if (g < 147456) {
        int q0 = g - 98304; int l = q0 >> 14, q = swz_q(q0 & 16383), n = q >> 7, k = q & 127;
        w2T[q0] = W2[(l * 128 + k) * 128 + fmap(n)];
    } else if (g < 155648) {
        int q0 = g - 147456; int q = swz_q(q0), n = q >> 7, k = q & 127;
        pw1T[q0] = pw1[k * 64 + n];                      // linear cols (no sigma)
    } else if (g < 204800) {
        int q0 = g - 155648; int l = q0 >> 14, q = swz_q(q0 & 16383), n = q >> 7, k = q & 127;
        int na = fmap(n);
        int hk = k >> 5, dk = k & 31;
        const float* kvp = kvs + (l * 4 + hk) * 1024 + dk * 32;
        const unsigned short* wop = Wo + (size_t)(l * 128 + hk * 32) * 128 + na;
        float s = 0.f;
        #pragma unroll 8
        for (int j = 0; j < 32; j++) s += kvp[j] * b2f(wop[j * 128]);
        waT[q0] = f2b(s);
    } else if (g < 210944) {
        int q = g - 204800; int l = q >> 11, r = q & 2047, n = r >> 7, k = r & 127;
        unsigned short v = 0;
        if (n < 4 && (k >> 5) == n) v = f2b(kss[(l * 4 + n) * 32 + (k & 31)]);
        ksT[q] = v;                                      // linear (no swizzle)
    } else if (g < 215040) {
        int q = g - 210944; int n = q >> 5, k = q & 31;  // pe_wT [128 slot][32]
        pweT[q] = (k < 30) ? pe_w[k * 128 + fmap(n)] : (unsigned short)0;
    }
}

// ---------- the fused mega kernel: encode + 3 layers + projector ----------
// ROUND-7 (post-mortem of R6: MFMA 26 + VALU 57 = 83% combined; LDS 73.7KB
// capped occupancy at ~1.7 blocks/CU, VALU issue-bound):
//  * HALF-MATRIX staging: wbuf = 2 x 16KB (buf0 = ntiles 0-3, buf1 = 4-7,
//    roles fixed). Per mm: compute h0 | barrier (drains h1) | issue next.h0 |
//    compute h1 | barrier | issue next.h1. LDS 73.7 -> 40KB => 4 blocks/CU
//    (VGPR 124 <= 128 => 4 waves/SIMD), doubling co-residency to fill the
//    17% stall and overlap VALU<->MFMA across blocks.
//  * f2v (float2 ext-vector) epilogue math => backend emits v_pk_add_f32 /
//    v_pk_mul_f32: bias+residual+square pair-ops halved. hres stored as f2v.
//  * GELU kept scalar (trans-bound; keeps register pressure flat).

template<int ITERS>
__device__ __forceinline__ void stage_gll(const unsigned short* __restrict__ g,
                                          unsigned short* __restrict__ lbase,
                                          int wvi, int ln) {
    const char* gp = (const char*)g + wvi * 1024 + ln * 16;
    char* lp = (char*)lbase + wvi * 1024;     // wave-uniform LDS base
    #pragma unroll
    for (int i = 0; i < ITERS; i++) {
        __builtin_amdgcn_global_load_lds(
            (const __attribute__((address_space(1))) unsigned int*)(gp + i * 4096),
            (__attribute__((address_space(3))) unsigned int*)(lp + i * 4096),
            16, 0, 0);
    }
}

// swizzled weight-fragment read from a 16KB HALF buffer: local ntile ntl
// (0-3), k-slice k, lane (qd,l16)
__device__ __forceinline__ s8v wfrag(const unsigned short* __restrict__ wb,
                                     int ntl, int k, int l16, int qd) {
    int lin = (ntl << 12) + (l16 << 8) + (k << 6) + (qd << 4);
    return *(const s8v*)((const char*)wb + (lin ^ ((l16 & 7) << 4)));
}

// capture pkd into MFMA B-fragments (sigma layout -> pure register renaming)
#define CAPTURE() do {                                                        \
    _Pragma("unroll")                                                         \
    for (int _s = 0; _s < 4; _s++) {                                          \
        bf0[_s] = mkfrag(pkd[0][2*_s][0], pkd[0][2*_s][1],                    \
                         pkd[0][2*_s+1][0], pkd[0][2*_s+1][1]);               \
        bf1[_s] = mkfrag(pkd[1][2*_s][0], pkd[1][2*_s][1],                    \
                         pkd[1][2*_s+1][0], pkd[1][2*_s+1][1]);               \
    }                                                                         \
} while (0)

// one HALF of a matmul: p = PB, PB+1 (PB=0: ntiles 0-3 from buf0; PB=2:
// ntiles 4-7 from buf1). Epilogue sees nt (global ntile), tile, x.
#define MM_HALF(WB, PB, EPI...) do {                                          \
    _Pragma("unroll")                                                         \
    for (int _pp = 0; _pp < 2; _pp++) {                                       \
        const int _p = (PB) + _pp;                                            \
        f4v _x0 = {0.f,0.f,0.f,0.f}, _x1 = _x0, _y0 = _x0, _y1 = _x0;         \
        _Pragma("unroll")                                                     \
        for (int _k = 0; _k < 4; _k++) {                                      \
            s8v _wa = wfrag(WB, (_p * 2) & 3,     _k, l16, qd);               \
            s8v _wb = wfrag(WB, (_p * 2 + 1) & 3, _k, l16, qd);               \
            _x0 = MFMA_BF16(_wa, bf0[_k], _x0, 0, 0, 0);                      \
            _x1 = MFMA_BF16(_wa, bf1[_k], _x1, 0, 0, 0);                      \
            _y0 = MFMA_BF16(_wb, bf0[_k], _y0, 0, 0, 0);                      \
            _y1 = MFMA_BF16(_wb, bf1[_k], _y1, 0, 0, 0);                      \
        }                                                                     \
        { const int nt = _p * 2;     const int tile = 0; const f4v x = _x0; EPI } \
        { const int nt = _p * 2;     const int tile = 1; const f4v x = _x1; EPI } \
        { const int nt = _p * 2 + 1; const int tile = 0; const f4v x = _y0; EPI } \
        { const int nt = _p * 2 + 1; const int tile = 1; const f4v x = _y1; EPI } \
    }                                                                         \
} while (0)

#define CBDEF int cb = ((nt >> 1) << 5) + (qd << 3) + ((nt & 1) << 2)

__global__ __launch_bounds__(256) void mega_kernel(
    const unsigned short* __restrict__ qpts,
    const unsigned short* __restrict__ pweT,
    const unsigned short* __restrict__ pe_b,
    const unsigned short* __restrict__ wqT,
    const unsigned short* __restrict__ waT,
    const unsigned short* __restrict__ ksT,
    const unsigned short* __restrict__ w1T,
    const unsigned short* __restrict__ w2T,
    const unsigned short* __restrict__ bq,
    const unsigned short* __restrict__ bo,
    const unsigned short* __restrict__ b1,
    const unsigned short* __restrict__ b2,
    const unsigned short* __restrict__ pw1T,
    const unsigned short* __restrict__ pb1,
    const unsigned short* __restrict__ pw2,
    const unsigned short* __restrict__ pb2,
    void* __restrict__ outv, const int* __restrict__ flag)
{
    __shared__ __align__(16) unsigned short wbuf[2][8192];   // 2 x 16KB halves
    __shared__ __align__(16) float biasAll[12 * 128];        // 6144 B
    __shared__ __align__(16) float pebs[128];
    __shared__ __align__(16) float pb1s[64];
    __shared__ __align__(16) float w2s4[256];                // w2 cols padded
    __shared__ float pb2s[3];

    int t = threadIdx.x;
    int wvi = t >> 6, ln = t & 63, qd = ln >> 4, l16 = ln & 15;
    int row0 = blockIdx.x * 128;
    int rA0 = wvi * 32 + l16;        // lane's row, tile 0 (tile 1: +16)
    unsigned short* wb0 = &wbuf[0][0];
    unsigned short* wb1 = &wbuf[1][0];

    // issue wq[0].h0 -> buf0 immediately (latency covered by bias staging)
    stage_gll<4>(wqT, wb0, wvi, ln);

    // ===== one-time staging =====
    for (int i = t; i < 1536; i += 256) {
        int l = i >> 9, rem = i & 511, which = rem >> 7, c = rem & 127;
        const unsigned short* bsrc = (which == 0) ? bq : (which == 1) ? bo
                                   : (which == 2) ? b1 : b2;
        biasAll[i] = b2f(bsrc[l * 128 + c]);
    }
    if (t < 128) pebs[t] = b2f(pe_b[t]);
    if (t < 64)  pb1s[t] = b2f(pb1[t]);
    if (t < 64) {
        w2s4[t * 4 + 0] = b2f(pw2[t * 3 + 0]);
        w2s4[t * 4 + 1] = b2f(pw2[t * 3 + 1]);
        w2s4[t * 4 + 2] = b2f(pw2[t * 3 + 2]);
        w2s4[t * 4 + 3] = 0.f;
    }
    if (t < 3) pb2s[t] = b2f(pb2[t]);
    __syncthreads();   // drains wq.h0; bias tables visible

    // issue wq[0].h1 -> buf1; encode covers its latency
    stage_gll<4>(wqT + 8192, wb1, wvi, ln);

    unsigned pkd[2][8][2];   // packed bf16 activations, slot layout
    f2v hresv[2][8][2];      // fp32 residual pairs, slot layout

    // ===== encode via MFMA: h = sin(feats @ pe_w + pe_b), pweT sigma'd =====
    {
        unsigned pq0 = *(const unsigned*)(qpts + (size_t)(row0 + rA0) * 2);
        unsigned pq1 = *(const unsigned*)(qpts + (size_t)(row0 + rA0 + 16) * 2);
        s8v ae0, ae1;
        {
            float f8[8]; feats8(pq0, qd, f8);
            unsigned* au = (unsigned*)&ae0;
            #pragma unroll
            for (int jj = 0; jj < 4; jj++) au[jj] = pk_bf16(f8[2 * jj], f8[2 * jj + 1]);
        }
        {
            float f8[8]; feats8(pq1, qd, f8);
            unsigned* au = (unsigned*)&ae1;
            #pragma unroll
            for (int jj = 0; jj < 4; jj++) au[jj] = pk_bf16(f8[2 * jj], f8[2 * jj + 1]);
        }
        const unsigned short* pb = pweT + l16 * 32 + qd * 8;
        #pragma unroll
        for (int nt = 0; nt < 8; nt++) {
            s8v aw = *(const s8v*)(pb + nt * 512);
            f4v x0 = {0.f, 0.f, 0.f, 0.f}, x1 = {0.f, 0.f, 0.f, 0.f};
            x0 = MFMA_BF16(aw, ae0, x0, 0, 0, 0);
            x1 = MFMA_BF16(aw, ae1, x1, 0, 0, 0);
            CBDEF;
            float4 bb = *(const float4*)&pebs[cb];
            float h0 = __sinf(x0[0] + bb.x), h1 = __sinf(x0[1] + bb.y);
            float h2 = __sinf(x0[2] + bb.z), h3 = __sinf(x0[3] + bb.w);
            f2v ha = {h0, h1}, hb = {h2, h3};
            hresv[0][nt][0] = ha; hresv[0][nt][1] = hb;
            pkd[0][nt][0] = pk_bf16(h0, h1);
            pkd[0][nt][1] = pk_bf16(h2, h3);
            float g0 = __sinf(x1[0] + bb.x), g1 = __sinf(x1[1] + bb.y);
            float g2 = __sinf(x1[2] + bb.z), g3 = __sinf(x1[3] + bb.w);
            f2v ga = {g0, g1}, gb = {g2, g3};
            hresv[1][nt][0] = ga; hresv[1][nt][1] = gb;
            pkd[1][nt][0] = pk_bf16(g0, g1);
            pkd[1][nt][1] = pk_bf16(g2, g3);
        }
    }

    s8v bf0[4], bf1[4];

    // epilogue bodies (f2v pair math -> v_pk_add/mul_f32)
    #define EPI_MM1 {                                                         \
        CBDEF;                                                                \
        float4 bb = *(const float4*)&bql[cb];                                 \
        f2v xa = {x[0], x[1]}, xb = {x[2], x[3]};                             \
        f2v ba = {bb.x, bb.y}, bc = {bb.z, bb.w};                             \
        f2v va = xa + ba, vb = xb + bc;                                       \
        f2v sa = va * va, sb = vb * vb;                                       \
        pkd[tile][nt][0] = pk_bf16(sa[0], sa[1]);                             \
        pkd[tile][nt][1] = pk_bf16(sb[0], sb[1]);                             \
    }
    #define EPI_RES(BIAS) {                                                   \
        CBDEF;                                                                \
        float4 bb = *(const float4*)&BIAS[cb];                                \
        f2v xa = {x[0], x[1]}, xb = {x[2], x[3]};                             \
        f2v ba = {bb.x, bb.y}, bc = {bb.z, bb.w};                             \
        f2v va = hresv[tile][nt][0] + xa + ba;                                \
        f2v vb = hresv[tile][nt][1] + xb + bc;                                \
        hresv[tile][nt][0] = va; hresv[tile][nt][1] = vb;                     \
        pkd[tile][nt][0] = pk_bf16(va[0], va[1]);                             \
        pkd[tile][nt][1] = pk_bf16(vb[0], vb[1]);                             \
    }
    #define EPI_GELU {                                                        \
        CBDEF;                                                                \
        float4 bb = *(const float4*)&b1l[cb];                                 \
        float g0 = gelu_l(x[0] + bb.x), g1 = gelu_l(x[1] + bb.y);             \
        float g2 = gelu_l(x[2] + bb.z), g3 = gelu_l(x[3] + bb.w);             \
        pkd[tile][nt][0] = pk_bf16(g0, g1);                                   \
        pkd[tile][nt][1] = pk_bf16(g2, g3);                                   \
    }

    // ===== 3 transformer layers (half-matrix double-buffer pipeline) =====
    // invariant at each mm start: buf0 = M.h0 resident, buf1 = M.h1 in flight
    for (int l = 0; l < 3; l++) {
        const float* bql = &biasAll[(l * 4 + 0) * 128];
        const float* bol = &biasAll[(l * 4 + 1) * 128];
        const float* b1l = &biasAll[(l * 4 + 2) * 128];
        const float* b2l = &biasAll[(l * 4 + 3) * 128];

        // kf loads issued early (resident by den)
        s8v kf[4];
        {
            const unsigned short* kb = ksT + l * 2048 + l16 * 128 + qd * 8;
            #pragma unroll
            for (int ks = 0; ks < 4; ks++) kf[ks] = *(const s8v*)(kb + ks * 32);
        }

        // mm1: qh = (h @ Wq + bq)^2
        CAPTURE();
        MM_HALF(wb0, 0, EPI_MM1);
        __syncthreads();                          // wq.h1 drained; buf0 free
        stage_gll<4>(waT + l * 16384, wb0, wvi, ln);
        MM_HALF(wb1, 2, EPI_MM1);
        __syncthreads();                          // wa.h0 drained; buf1 free
        stage_gll<4>(waT + l * 16384 + 8192, wb1, wvi, ln);

        // den: d[h] = qh_row . ksum_h (register MFMA); z-scale pkd in place
        #pragma unroll
        for (int tile = 0; tile < 2; tile++) {
            f4v d = {0.f, 0.f, 0.f, 0.f};
            #pragma unroll
            for (int ks = 0; ks < 4; ks++) {
                s8v b = mkfrag(pkd[tile][2 * ks][0], pkd[tile][2 * ks][1],
                               pkd[tile][2 * ks + 1][0], pkd[tile][2 * ks + 1][1]);
                d = MFMA_BF16(kf[ks], b, d, 0, 0, 0);
            }
            #pragma unroll
            for (int ks = 0; ks < 4; ks++) {
                float z = 1.f / (__shfl(d[ks], l16) + 1e-6f);
                #pragma unroll
                for (int h2 = 0; h2 < 2; h2++) {
                    #pragma unroll
                    for (int j = 0; j < 2; j++) {
                        unsigned w = pkd[tile][2 * ks + h2][j];
                        float lo = __uint_as_float(w << 16) * z;
                        float hi = __uint_as_float(w & 0xffff0000u) * z;
                        pkd[tile][2 * ks + h2][j] = pk_bf16(lo, hi);
                    }
                }
            }
        }

        // mm2: x = h + (z*qh) @ Wa + bo
        CAPTURE();
        MM_HALF(wb0, 0, EPI_RES(bol));
        __syncthreads();                          // wa.h1 drained; buf0 free
        stage_gll<4>(w1T + l * 16384, wb0, wvi, ln);
        MM_HALF(wb1, 2, EPI_RES(bol));
        __syncthreads();                          // w1.h0 drained; buf1 free
        stage_gll<4>(w1T + l * 16384 + 8192, wb1, wvi, ln);

        // mm3: t = gelu(x @ W1 + b1)
        CAPTURE();
        MM_HALF(wb0, 0, EPI_GELU);
        __syncthreads();                          // w1.h1 drained; buf0 free
        stage_gll<4>(w2T + l * 16384, wb0, wvi, ln);
        MM_HALF(wb1, 2, EPI_GELU);
        __syncthreads();                          // w2.h0 drained; buf1 free
        stage_gll<4>(w2T + l * 16384 + 8192, wb1, wvi, ln);

        // mm4: h_new = x + t @ W2 + b2
        CAPTURE();
        MM_HALF(wb0, 0, EPI_RES(b2l));
        __syncthreads();                          // w2.h1 drained; buf0 free
        if (l < 2) stage_gll<4>(wqT + (l + 1) * 16384, wb0, wvi, ln);
        else       stage_gll<4>(pw1T, wb0, wvi, ln);
        MM_HALF(wb1, 2, EPI_RES(b2l));
        __syncthreads();                          // next.h0 drained; buf1 free
        if (l < 2) stage_gll<4>(wqT + (l + 1) * 16384 + 8192, wb1, wvi, ln);
    }

    // ===== final projector: out = gelu(h @ pw1 + pb1) @ pw2 + pb2 =====
    // buf0 holds pw1T (16KB = local ntiles 0-3), drained at the last barrier
    {
        CAPTURE();
        float pt0[3] = {0.f, 0.f, 0.f}, pt1[3] = {0.f, 0.f, 0.f};
        #pragma unroll
        for (int p = 0; p < 2; p++) {
            f4v y00 = {0.f,0.f,0.f,0.f}, y01 = y00, y10 = y00, y11 = y00;
            #pragma unroll
            for (int ks = 0; ks < 4; ks++) {
                s8v wa = wfrag(wb0, p * 2,     ks, l16, qd);
                s8v wb = wfrag(wb0, p * 2 + 1, ks, l16, qd);
                y00 = MFMA_BF16(wa, bf0[ks], y00, 0, 0, 0);
                y01 = MFMA_BF16(wa, bf1[ks], y01, 0, 0, 0);
                y10 = MFMA_BF16(wb, bf0[ks], y10, 0, 0, 0);
                y11 = MFMA_BF16(wb, bf1[ks], y11, 0, 0, 0);
            }
            #pragma unroll
            for (int e = 0; e < 2; e++) {
                int c0 = (p * 2 + e) * 16 + qd * 4;   // pw1T linear -> actual col
                float4 bb = *(const float4*)&pb1s[c0];
                f4v ya = e ? y10 : y00;   // tile 0
                f4v yb = e ? y11 : y01;   // tile 1
                #pragma unroll
                for (int i = 0; i < 4; i++) {
                    float bbi = (i == 0) ? bb.x : (i == 1) ? bb.y : (i == 2) ? bb.z : bb.w;
                    float4 w = *(const float4*)&w2s4[(c0 + i) * 4];
                    float ga = gelu_l(ya[i] + bbi);
                    float gb = gelu_l(yb[i] + bbi);
                    pt0[0] = fmaf(ga, w.x, pt0[0]);
                    pt0[1] = fmaf(ga, w.y, pt0[1]);
                    pt0[2] = fmaf(ga, w.z, pt0[2]);
                    pt1[0] = fmaf(gb, w.x, pt1[0]);
                    pt1[1] = fmaf(gb, w.y, pt1[1]);
                    pt1[2] = fmaf(gb, w.z, pt1[2]);
                }
            }
        }
        // reduce over the qd group (lane bits 4-5), then lane qd==0 stores
        #pragma unroll
        for (int c = 0; c < 3; c++) {
            pt0[c] += __shfl_xor(pt0[c], 16); pt0[c] += __shfl_xor(pt0[c], 32);
            pt1[c] += __shfl_xor(pt1[c], 16); pt1[c] += __shfl_xor(pt1[c], 32);
            pt0[c] += pb2s[c]; pt1[c] += pb2s[c];
        }
        if (ln < 16) {
            size_t r0 = (size_t)(row0 + rA0) * 3;
            size_t r1 = (size_t)(row0 + rA0 + 16) * 3;
            if (*flag) {
                float* o = (float*)outv;
                o[r0] = pt0[0]; o[r0 + 1] = pt0[1]; o[r0 + 2] = pt0[2];
                o[r1] = pt1[0]; o[r1 + 1] = pt1[1]; o[r1 + 2] = pt1[2];
            } else {
                unsigned short* o = (unsigned short*)outv;
                o[r0] = f2b(pt0[0]); o[r0 + 1] = f2b(pt0[1]); o[r0 + 2] = f2b(pt0[2]);
                o[r1] = f2b(pt1[0]); o[r1 + 1] = f2b(pt1[1]); o[r1 + 2] = f2b(pt1[2]);
            }
        }
    }
}

// ---------- launch ----------
extern "C" void kernel_launch(void* const* d_in, const int* in_sizes, int n_in,
                              void* d_out, int out_size, void* d_ws, size_t ws_size,
                              hipStream_t stream) {
    const int N = in_sizes[0] / 2;   // 262144
    const int M = in_sizes[1] / 2;   // 4096

    ConvArgs ca;
    int total = 0;
    for (int i = 0; i < 22; i++) { ca.p[i] = d_in[i]; ca.off[i] = total; total += in_sizes[i]; }
    ca.off[22] = total;

    float* ws = (float*)d_ws;
    int* flag = (int*)ws;
    unsigned short* canon = (unsigned short*)(ws + 16);
    size_t canonF = ((size_t)(total + 1) / 2 + 15) & ~(size_t)15;
    float* b_enc = ws + 16 + canonF;                       // M*128
    float* khb   = b_enc + (size_t)M * 128;                // 12*M*32
    float* vhb   = khb + (size_t)12 * M * 32;              // 12*M*32
    float* kvs   = vhb + (size_t)12 * M * 32;              // 12288
    float* kss   = kvs + 12288;                            // 384
    unsigned short* wqT  = (unsigned short*)(kss + 384);   // 3*16384
    unsigned short* waT  = wqT + 49152;
    unsigned short* w1T  = waT + 49152;
    unsigned short* w2T  = w1T + 49152;
    unsigned short* ksT  = w2T + 49152;                    // 3*2048
    unsigned short* pw1T = ksT + 6144;                     // 8192
    unsigned short* pweT = pw1T + 8192;                    // 4096

    const unsigned short* c_qpts = canon + ca.off[0];
    const unsigned short* c_bpts = canon + ca.off[1];
    const unsigned short* c_pew  = canon + ca.off[2];
    const unsigned short* c_peb  = canon + ca.off[3];
    const unsigned short* c_bpew = canon + ca.off[4];
    const unsigned short* c_bpeb = canon + ca.off[5];
    const unsigned short* c_Wq   = canon + ca.off[6];
    const unsigned short* c_bq   = canon + ca.off[7];
    const unsigned short* c_Wk   = canon + ca.off[8];
    const unsigned short* c_bk   = canon + ca.off[9];
    const unsigned short* c_Wv   = canon + ca.off[10];
    const unsigned short* c_bv   = canon + ca.off[11];
    const unsigned short* c_Wo   = canon + ca.off[12];
    const unsigned short* c_bo   = canon + ca.off[13];
    const unsigned short* c_W1   = canon + ca.off[14];
    const unsigned short* c_b1   = canon + ca.off[15];
    const unsigned short* c_W2   = canon + ca.off[16];
    const unsigned short* c_b2   = canon + ca.off[17];
    const unsigned short* c_pw1  = canon + ca.off[18];
    const unsigned short* c_pb1  = canon + ca.off[19];
    const unsigned short* c_pw2  = canon + ca.off[20];
    const unsigned short* c_pb2  = canon + ca.off[21];

    convert_kernel<<<(total + 255) / 256, 256, 0, stream>>>(
        ca, (const unsigned short*)d_in[2], flag, canon, total);

    encode_kernel<<<M / 8, 256, 0, stream>>>(c_bpts, c_bpew, c_bpeb, b_enc);
    khvh_kernel<<<(12 * M * 32) / 256, 256, 0, stream>>>(
        b_enc, c_Wk, c_bk, c_Wv, c_bv, khb, vhb, kvs);
    kvred_kernel<<<96, 1024, 0, stream>>>(khb, vhb, kvs, kss);
    prep_kernel<<<215040 / 256, 256, 0, stream>>>(
        c_Wq, c_W1, c_W2, c_pw1, kvs, kss, c_Wo, c_pew,
        wqT, w1T, w2T, pw1T, waT, ksT, pweT);

    mega_kernel<<<N / 128, 256, 0, stream>>>(
        c_qpts, pweT, c_peb, wqT, waT, ksT, w1T, w2T,
        c_bq, c_bo, c_b1, c_b2, pw1T, c_pb1, c_pw2, c_pb2, d_out, flag);
}

// Round 8
// 356.929 us; speedup vs baseline: 2.6191x; 1.0014x over previous
//
#include <hip/hip_runtime.h>
#include <hip/hip_bf16.h>

// ---------- helpers ----------
__device__ __forceinline__ float b2f(unsigned short u) {
    return __uint_as_float(((unsigned)u) << 16);
}
__device__ __forceinline__ unsigned short f2b(float f) {
    __hip_bfloat16 h = __float2bfloat16(f);
    return *reinterpret_cast<unsigned short*>(&h);
}
// pack two f32 -> packed 2x bf16 (RNE), single VALU op
__device__ __forceinline__ unsigned pk_bf16(float lo, float hi) {
    unsigned r;
    asm("v_cvt_pk_bf16_f32 %0, %1, %2" : "=v"(r) : "v"(lo), "v"(hi));
    return r;
}
// hardware exp2 (v_exp_f32 computes 2^x)
__device__ __forceinline__ float exp2_hw(float x) {
    float r;
    asm("v_exp_f32 %0, %1" : "=v"(r) : "v"(x));
    return r;
}
__device__ __forceinline__ float sigm(float v) {
    return 1.f / (1.f + __expf(-v));
}
// lean tanh-approx GELU, exp2 form: g = x - x/(1+2^(x*(c1+c2*x^2)))
__device__ __forceinline__ float gelu_l(float x) {
    float x2 = x * x;
    float y  = x * __builtin_fmaf(0.10294535f, x2, 2.3022137f);
    float e  = exp2_hw(y);
    float r  = __builtin_amdgcn_rcpf(e + 1.f);
    return __builtin_fmaf(-x, r, x);
}

typedef __attribute__((ext_vector_type(8))) short s8v;   // 8 bf16 (4 VGPRs)
typedef __attribute__((ext_vector_type(4))) float f4v;   // 4 fp32 acc
typedef __attribute__((ext_vector_type(2))) float f2v;   // fp32 pair (v_pk_*)

#define MFMA_BF16 __builtin_amdgcn_mfma_f32_16x16x32_bf16

__device__ __forceinline__ s8v mkfrag(unsigned a, unsigned b, unsigned c, unsigned d) {
    union { unsigned u[4]; s8v v; } x;
    x.u[0] = a; x.u[1] = b; x.u[2] = c; x.u[3] = d;
    return x.v;
}

// dtype detection (replaces convert_kernel): same decision rule as the old
// convert (256 samples of pe_w's even ushorts interpreted as bf16; >=16
// "not small" => f32). Wave-level ballot => wave-uniform, deterministic,
// identical in every kernel. Safe for both dtypes (idx <= 510 < 3840).
__device__ __forceinline__ int detect_f32(const unsigned short* __restrict__ raw) {
    int ln = threadIdx.x & 63;
    int c = 0;
    #pragma unroll
    for (int j = 0; j < 4; j++) {
        float v = b2f(raw[(ln * 4 + j) * 2]);
        unsigned long long m = __ballot(!(fabsf(v) < 1.0f));
        c += __popcll(m);
    }
    return c >= 16;
}

// sigma: slot s -> actual column. s{i[1:0],qd[1:0],ntlo,nthi[1:0]} ->
// c{i[1:0], ntlo, qd[1:0], nthi[1:0]}. Bijective bit permutation.
// With weight ROWS stored at slots, the MFMA C output of slot (nt,qd,i) is
// actual col (nt>>1)*32 + qd*8 + (nt&1)*4 + i -> each lane's C is exactly
// the next mm's B-fragment (lane-local renaming, no LDS round-trip).
__device__ __forceinline__ int fmap(int s) {
    return (s & ~31) | (((s >> 2) & 3) << 3) | (((s >> 4) & 1) << 2) | (s & 3);
}
// inverse LDS bank swizzle applied in GLOBAL memory (ushort index involution):
// gll copies linearly, wfrag reads with byte XOR ((l16&7)<<4); pre-permuting
// the source by the same involution keeps both sides consistent.
__device__ __forceinline__ int swz_q(int q) {
    return q ^ (((q >> 7) & 7) << 3);
}

// ---------- 15-feature map on raw (x0,x1) ----------
__device__ __forceinline__ void make_feats2(float x0, float x1, float* __restrict__ f) {
    const float PI = 3.14159265358979323846f;
    float a0 = x0 - 1.5f, a1 = x1 - 1.5f, c0 = x0 - 4.5f, c1 = x1 - 4.5f;
    f[0] = x0;        f[1] = x1;
    f[2] = x0 * x0;   f[3] = x1 * x1;
    f[4] = a0 * a0;   f[5] = a1 * a1;
    f[6] = c0 * c0;   f[7] = c1 * c1;
    f[8] = sigm(x0);  f[9] = sigm(x1);
    f[10] = sigm(a0); f[11] = sigm(a1);
    f[12] = sigm(c0); f[13] = sigm(c1);
    f[14] = a0;       f[15] = a1;
    f[16] = c0;       f[17] = c1;
    f[18] = __sinf(PI * x0);          f[19] = __sinf(PI * x1);
    f[20] = __cosf(PI * x0);          f[21] = __cosf(PI * x1);
    f[22] = __sinf(PI * 0.25f * x0);  f[23] = __sinf(PI * 0.25f * x1);
    f[24] = __cosf(PI * 0.25f * x0);  f[25] = __cosf(PI * 0.25f * x1);
    f[26] = __sinf(PI * 0.5f * x0);   f[27] = __sinf(PI * 0.5f * x1);
    f[28] = __cosf(PI * 0.5f * x0);   f[29] = __cosf(PI * 0.5f * x1);
}

// 8 features for k = qd*8 .. qd*8+7 (quad-split of the 30-vector, 30/31 -> 0)
__device__ __forceinline__ void feats8(float x0, float x1, int qd, float* __restrict__ f8) {
    const float PI = 3.14159265358979323846f;
    float a0 = x0 - 1.5f, a1 = x1 - 1.5f, c0 = x0 - 4.5f, c1 = x1 - 4.5f;
    if (qd == 0) {
        f8[0] = x0;      f8[1] = x1;
        f8[2] = x0 * x0; f8[3] = x1 * x1;
        f8[4] = a0 * a0; f8[5] = a1 * a1;
        f8[6] = c0 * c0; f8[7] = c1 * c1;
    } else if (qd == 1) {
        f8[0] = sigm(x0); f8[1] = sigm(x1);
        f8[2] = sigm(a0); f8[3] = sigm(a1);
        f8[4] = sigm(c0); f8[5] = sigm(c1);
        f8[6] = a0;       f8[7] = a1;
    } else if (qd == 2) {
        f8[0] = c0; f8[1] = c1;
        f8[2] = __sinf(PI * x0);          f8[3] = __sinf(PI * x1);
        f8[4] = __cosf(PI * x0);          f8[5] = __cosf(PI * x1);
        f8[6] = __sinf(PI * 0.25f * x0);  f8[7] = __sinf(PI * 0.25f * x1);
    } else {
        f8[0] = __cosf(PI * 0.25f * x0);  f8[1] = __cosf(PI * 0.25f * x1);
        f8[2] = __sinf(PI * 0.5f * x0);   f8[3] = __sinf(PI * 0.5f * x1);
        f8[4] = __cosf(PI * 0.5f * x0);   f8[5] = __cosf(PI * 0.5f * x1);
        f8[6] = 0.f;                      f8[7] = 0.f;
    }
}

// raw accessors: explicit uniform branch (NEVER speculate the wrong-dtype
// load -- it can be OOB on the smaller buffer).
__device__ __forceinline__ float ldr(const unsigned short* __restrict__ p, int idx, int isf32) {
    float v;
    if (isf32) v = ((const float*)p)[idx];
    else       v = b2f(p[idx]);
    return v;
}
__device__ __forceinline__ unsigned short ldb(const unsigned short* __restrict__ p, int idx, int isf32) {
    unsigned short v;
    if (isf32) v = f2b(((const float*)p)[idx]);
    else       v = p[idx];
    return v;
}

// ---------- boundary positional encoding (raw inputs, + kvs/kss zeroing) ----------
__global__ __launch_bounds__(256) void encode_kernel(
    const unsigned short* __restrict__ pts_raw,
    const unsigned short* __restrict__ w_raw,
    const unsigned short* __restrict__ b_raw,
    const unsigned short* __restrict__ pe_w_raw,
    float* __restrict__ out, float* __restrict__ kvz)
{
    int isf32 = detect_f32(pe_w_raw);
    __shared__ __align__(16) float wsm[30 * 128];
    __shared__ float bs[128];
    int t = threadIdx.x;
    int g = blockIdx.x * 256 + t;
    if (g < 12672) kvz[g] = 0.f;   // kvs(12288) + kss(384), contiguous

    if (isf32) {
        const float* w = (const float*)w_raw;
        for (int i = t; i < 30 * 128; i += 256) wsm[i] = w[i];
        if (t < 128) bs[t] = ((const float*)b_raw)[t];
    } else {
        for (int i = t; i < 30 * 128; i += 256) wsm[i] = b2f(w_raw[i]);
        if (t < 128) bs[t] = b2f(b_raw[t]);
    }
    __syncthreads();

    int r = blockIdx.x * 8 + (t >> 5);
    int j = t & 31;
    float x0, x1;
    if (isf32) {
        float2 p = ((const float2*)pts_raw)[r];
        x0 = p.x; x1 = p.y;
    } else {
        unsigned pq = ((const unsigned*)pts_raw)[r];
        x0 = b2f((unsigned short)(pq & 0xffff));
        x1 = b2f((unsigned short)(pq >> 16));
    }
    float f[30];
    make_feats2(x0, x1, f);
    float s0 = bs[j * 4 + 0], s1 = bs[j * 4 + 1], s2 = bs[j * 4 + 2], s3 = bs[j * 4 + 3];
    #pragma unroll
    for (int ff = 0; ff < 30; ff++) {
        float4 wv = *(const float4*)&wsm[ff * 128 + j * 4];
        float fv = f[ff];
        s0 += fv * wv.x; s1 += fv * wv.y; s2 += fv * wv.z; s3 += fv * wv.w;
    }
    *(float4*)&out[(size_t)r * 128 + j * 4] =
        make_float4(__sinf(s0), __sinf(s1), __sinf(s2), __sinf(s3));
}

// ---------- FUSED k/v heads + reduction (was khvh + kvred + 25MB round-trip) ----------
// grid 384 = 12 (l,h) x 32 parts of 128 m-rows; 1024 threads.
// Per 32-row chunk: phase A computes kh/vh straight into LDS (same coalesced
// pattern as the old khvh: lanes dd consecutive on weights, benc row
// broadcast); phase B does the kvred reduction from LDS. atomicAdd at end.
__global__ __launch_bounds__(1024) void khvred_kernel(
    const float* __restrict__ benc,
    const unsigned short* __restrict__ Wk_raw, const unsigned short* __restrict__ bk_raw,
    const unsigned short* __restrict__ Wv_raw, const unsigned short* __restrict__ bv_raw,
    const unsigned short* __restrict__ pe_w_raw,
    float* __restrict__ kvsum, float* __restrict__ ksum)
{
    int isf32 = detect_f32(pe_w_raw);
    __shared__ float khs[1024];
    __shared__ float vhs[1024];
    int t = threadIdx.x;
    int lh = blockIdx.x >> 5;        // 0..11
    int part = blockIdx.x & 31;      // 32 x 128 rows
    int mm = t >> 5, dd = t & 31;    // phase A roles
    int dd2 = t >> 5, ee = t & 31;   // phase B roles
    float kva = 0.f, ksa = 0.f;

    for (int ch = 0; ch < 4; ch++) {
        int m = part * 128 + ch * 32 + mm;
        const float* br = benc + (size_t)m * 128;
        float ka, va;
        if (isf32) {
            const float* wk = (const float*)Wk_raw + lh * 4096 + dd;
            const float* wv = (const float*)Wv_raw + lh * 4096 + dd;
            float a = 0.f, b = 0.f;
            #pragma unroll 8
            for (int c = 0; c < 128; c++) {
                float bb = br[c];
                a += bb * wk[c * 32];
                b += bb * wv[c * 32];
            }
            ka = a + ((const float*)bk_raw)[lh * 32 + dd];
            va = b + ((const float*)bv_raw)[lh * 32 + dd];
        } else {
            const unsigned short* wk = Wk_raw + lh * 4096 + dd;
            const unsigned short* wv = Wv_raw + lh * 4096 + dd;
            float a = 0.f, b = 0.f;
            #pragma unroll 8
            for (int c = 0; c < 128; c++) {
                float bb = br[c];
                a += bb * b2f(wk[c * 32]);
                b += bb * b2f(wv[c * 32]);
            }
            ka = a + b2f(bk_raw[lh * 32 + dd]);
            va = b + b2f(bv_raw[lh * 32 + dd]);
        }
        ka = ka * ka;
        khs[mm * 32 + dd] = ka;
        vhs[mm * 32 + dd] = va;
        __syncthreads();
        #pragma unroll
        for (int i = 0; i < 32; i++) {
            float kk = khs[i * 32 + dd2];
            kva += kk * vhs[i * 32 + ee];
            ksa += kk;
        }
        __syncthreads();
    }
    atomicAdd(&kvsum[lh * 1024 + dd2 * 32 + ee], kva);
    if (ee == 0) atomicAdd(&ksum[lh * 32 + dd2], ksa);
}

// ---------- prep: sigma rows + PRE-SWIZZLED storage + Wa fold + Ks (raw in) ----------
__global__ __launch_bounds__(256) void prep_kernel(
    const unsigned short* __restrict__ Wq, const unsigned short* __restrict__ W1,
    const unsigned short* __restrict__ W2, const unsigned short* __restrict__ pw1,
    const float* __restrict__ kvs, const float* __restrict__ kss,
    const unsigned short* __restrict__ Wo, const unsigned short* __restrict__ pe_w,
    unsigned short* __restrict__ wqT, unsigned short* __restrict__ w1T,
    unsigned short* __restrict__ w2T, unsigned short* __restrict__ pw1T,
    unsigned short* __restrict__ waT, unsigned short* __restrict__ ksT,
    unsigned short* __restrict__ pweT)
{
    int isf32 = detect_f32(pe_w);
    int g = blockIdx.x * 256 + threadIdx.x;
    if (g < 49152) {
        int l = g >> 14, q = swz_q(g & 16383), n = q >> 7, k = q & 127;
        int na = fmap(n);   // head-interleaved actual col
        wqT[g] = ldb(Wq, ((l * 4 + (na >> 5)) * 128 + k) * 32 + (na & 31), isf32);
    } else if (g < 98304) {
        int q0 = g - 49152; int l = q0 >> 14, q = swz_q(q0 & 16383), n = q >> 7, k = q & 127;
        w1T[q0] = ldb(W1, (l * 128 + k) * 128 + fmap(n), isf32);
    } else if (g < 147456) {
        int q0 = g - 98304; int l = q0 >> 14, q = swz_q(q0 & 16383), n = q >> 7, k = q & 127;
        w2T[q0] = ldb(W2, (l * 128 + k) * 128 + fmap(n), isf32);
    } else if (g < 155648) {
        int q0 = g - 147456; int q = swz_q(q0), n = q >> 7, k = q & 127;
        pw1T[q0] = ldb(pw1, k * 64 + n, isf32);          // linear cols (no sigma)
    } else if (g < 204800) {
        int q0 = g - 155648; int l = q0 >> 14, q = swz_q(q0 & 16383), n = q >> 7, k = q & 127;
        int na = fmap(n);
        int hk = k >> 5, dk = k & 31;
        const float* kvp = kvs + (l * 4 + hk) * 1024 + dk * 32;
        float s = 0.f;
        if (isf32) {
            const float* wop = (const float*)Wo + (size_t)(l * 128 + hk * 32) * 128 + na;
            #pragma unroll 8
            for (int j = 0; j < 32; j++) s += kvp[j] * wop[j * 128];
        } else {
            const unsigned short* wop = Wo + (size_t)(l * 128 + hk * 32) * 128 + na;
            #pragma unroll 8
            for (int j = 0; j < 32; j++) s += kvp[j] * b2f(wop[j * 128]);
        }
        waT[q0] = f2b(s);
    } else if (g < 210944) {
        int q = g - 204800; int l = q >> 11, r = q & 2047, n = r >> 7, k = r & 127;
        unsigned short v = 0;
        if (n < 4 && (k >> 5) == n) v = f2b(kss[(l * 4 + n) * 32 + (k & 31)]);
        ksT[q] = v;                                      // linear (no swizzle)
    } else if (g < 215040) {
        int q = g - 210944; int n = q >> 5, k = q & 31;  // pe_wT [128 slot][32]
        pweT[q] = (k < 30) ? ldb(pe_w, k * 128 + fmap(n), isf32) : (unsigned short)0;
    }
}

// ---------- the fused mega kernel: encode + 3 layers + projector ----------
// ROUND-8: mega logic UNCHANGED from R7 (178us, MFMA 27 + VALU 57); this
// round consolidates the pipeline: convert_kernel deleted (raw reads +
// per-kernel dtype detection), khvh+kvred fused, 6 -> 4 launches.

template<int ITERS>
__device__ __forceinline__ void stage_gll(const unsigned short* __restrict__ g,
                                          unsigned short* __restrict__ lbase,
                                          int wvi, int ln) {
    const char* gp = (const char*)g + wvi * 1024 + ln * 16;
    char* lp = (char*)lbase + wvi * 1024;     // wave-uniform LDS base
    #pragma unroll
    for (int i = 0; i < ITERS; i++) {
        __builtin_amdgcn_global_load_lds(
            (const __attribute__((address_space(1))) unsigned int*)(gp + i * 4096),
            (__attribute__((address_space(3))) unsigned int*)(lp + i * 4096),
            16, 0, 0);
    }
}

// swizzled weight-fragment read from a 16KB HALF buffer: local ntile ntl
// (0-3), k-slice k, lane (qd,l16)
__device__ __forceinline__ s8v wfrag(const unsigned short* __restrict__ wb,
                                     int ntl, int k, int l16, int qd) {
    int lin = (ntl << 12) + (l16 << 8) + (k << 6) + (qd << 4);
    return *(const s8v*)((const char*)wb + (lin ^ ((l16 & 7) << 4)));
}

// capture pkd into MFMA B-fragments (sigma layout -> pure register renaming)
#define CAPTURE() do {                                                        \
    _Pragma("unroll")                                                         \
    for (int _s = 0; _s < 4; _s++) {                                          \
        bf0[_s] = mkfrag(pkd[0][2*_s][0], pkd[0][2*_s][1],                    \
                         pkd[0][2*_s+1][0], pkd[0][2*_s+1][1]);               \
        bf1[_s] = mkfrag(pkd[1][2*_s][0], pkd[1][2*_s][1],                    \
                         pkd[1][2*_s+1][0], pkd[1][2*_s+1][1]);               \
    }                                                                         \
} while (0)

// one HALF of a matmul: p = PB, PB+1 (PB=0: ntiles 0-3 from buf0; PB=2:
// ntiles 4-7 from buf1). Epilogue sees nt (global ntile), tile, x.
#define MM_HALF(WB, PB, EPI...) do {                                          \
    _Pragma("unroll")                                                         \
    for (int _pp = 0; _pp < 2; _pp++) {                                       \
        const int _p = (PB) + _pp;                                            \
        f4v _x0 = {0.f,0.f,0.f,0.f}, _x1 = _x0, _y0 = _x0, _y1 = _x0;         \
        _Pragma("unroll")                                                     \
        for (int _k = 0; _k < 4; _k++) {                                      \
            s8v _wa = wfrag(WB, (_p * 2) & 3,     _k, l16, qd);               \
            s8v _wb = wfrag(WB, (_p * 2 + 1) & 3, _k, l16, qd);               \
            _x0 = MFMA_BF16(_wa, bf0[_k], _x0, 0, 0, 0);                      \
            _x1 = MFMA_BF16(_wa, bf1[_k], _x1, 0, 0, 0);                      \
            _y0 = MFMA_BF16(_wb, bf0[_k], _y0, 0, 0, 0);                      \
            _y1 = MFMA_BF16(_wb, bf1[_k], _y1, 0, 0, 0);                      \
        }                                                                     \
        { const int nt = _p * 2;     const int tile = 0; const f4v x = _x0; EPI } \
        { const int nt = _p * 2;     const int tile = 1; const f4v x = _x1; EPI } \
        { const int nt = _p * 2 + 1; const int tile = 0; const f4v x = _y0; EPI } \
        { const int nt = _p * 2 + 1; const int tile = 1; const f4v x = _y1; EPI } \
    }                                                                         \
} while (0)

#define CBDEF int cb = ((nt >> 1) << 5) + (qd << 3) + ((nt & 1) << 2)

__global__ __launch_bounds__(256) void mega_kernel(
    const unsigned short* __restrict__ qpts,
    const unsigned short* __restrict__ pweT,
    const unsigned short* __restrict__ pe_b,
    const unsigned short* __restrict__ wqT,
    const unsigned short* __restrict__ waT,
    const unsigned short* __restrict__ ksT,
    const unsigned short* __restrict__ w1T,
    const unsigned short* __restrict__ w2T,
    const unsigned short* __restrict__ bq,
    const unsigned short* __restrict__ bo,
    const unsigned short* __restrict__ b1,
    const unsigned short* __restrict__ b2,
    const unsigned short* __restrict__ pw1T,
    const unsigned short* __restrict__ pb1,
    const unsigned short* __restrict__ pw2,
    const unsigned short* __restrict__ pb2,
    const unsigned short* __restrict__ pe_w_raw,
    void* __restrict__ outv)
{
    __shared__ __align__(16) unsigned short wbuf[2][8192];   // 2 x 16KB halves
    __shared__ __align__(16) float biasAll[12 * 128];        // 6144 B
    __shared__ __align__(16) float pebs[128];
    __shared__ __align__(16) float pb1s[64];
    __shared__ __align__(16) float w2s4[256];                // w2 cols padded
    __shared__ float pb2s[3];

    int isf32 = detect_f32(pe_w_raw);
    int t = threadIdx.x;
    int wvi = t >> 6, ln = t & 63, qd = ln >> 4, l16 = ln & 15;
    int row0 = blockIdx.x * 128;
    int rA0 = wvi * 32 + l16;        // lane's row, tile 0 (tile 1: +16)
    unsigned short* wb0 = &wbuf[0][0];
    unsigned short* wb1 = &wbuf[1][0];

    // issue wq[0].h0 -> buf0 immediately (latency covered by bias staging)
    stage_gll<4>(wqT, wb0, wvi, ln);

    // ===== one-time staging (raw biases, dtype-dispatched) =====
    if (isf32) {
        for (int i = t; i < 1536; i += 256) {
            int l = i >> 9, rem = i & 511, which = rem >> 7, c = rem & 127;
            const unsigned short* bsrc = (which == 0) ? bq : (which == 1) ? bo
                                       : (which == 2) ? b1 : b2;
            biasAll[i] = ((const float*)bsrc)[l * 128 + c];
        }
        if (t < 128) pebs[t] = ((const float*)pe_b)[t];
        if (t < 64)  pb1s[t] = ((const float*)pb1)[t];
        if (t < 64) {
            const float* w = (const float*)pw2;
            w2s4[t * 4 + 0] = w[t * 3 + 0];
            w2s4[t * 4 + 1] = w[t * 3 + 1];
            w2s4[t * 4 + 2] = w[t * 3 + 2];
            w2s4[t * 4 + 3] = 0.f;
        }
        if (t < 3) pb2s[t] = ((const float*)pb2)[t];
    } else {
        for (int i = t; i < 1536; i += 256) {
            int l = i >> 9, rem = i & 511, which = rem >> 7, c = rem & 127;
            const unsigned short* bsrc = (which == 0) ? bq : (which == 1) ? bo
                                       : (which == 2) ? b1 : b2;
            biasAll[i] = b2f(bsrc[l * 128 + c]);
        }
        if (t < 128) pebs[t] = b2f(pe_b[t]);
        if (t < 64)  pb1s[t] = b2f(pb1[t]);
        if (t < 64) {
            w2s4[t * 4 + 0] = b2f(pw2[t * 3 + 0]);
            w2s4[t * 4 + 1] = b2f(pw2[t * 3 + 1]);
            w2s4[t * 4 + 2] = b2f(pw2[t * 3 + 2]);
            w2s4[t * 4 + 3] = 0.f;
        }
        if (t < 3) pb2s[t] = b2f(pb2[t]);
    }
    __syncthreads();   // drains wq.h0; bias tables visible

    // issue wq[0].h1 -> buf1; encode covers its latency
    stage_gll<4>(wqT + 8192, wb1, wvi, ln);

    unsigned pkd[2][8][2];   // packed bf16 activations, slot layout
    f2v hresv[2][8][2];      // fp32 residual pairs, slot layout

    // ===== encode via MFMA: h = sin(feats @ pe_w + pe_b), pweT sigma'd =====
    {
        float x0a, x1a, x0b, x1b;
        if (isf32) {
            float2 p0 = ((const float2*)qpts)[row0 + rA0];
            float2 p1 = ((const float2*)qpts)[row0 + rA0 + 16];
            x0a = p0.x; x1a = p0.y; x0b = p1.x; x1b = p1.y;
        } else {
            unsigned pq0 = ((const unsigned*)qpts)[row0 + rA0];
            unsigned pq1 = ((const unsigned*)qpts)[row0 + rA0 + 16];
            x0a = b2f((unsigned short)(pq0 & 0xffff));
            x1a = b2f((unsigned short)(pq0 >> 16));
            x0b = b2f((unsigned short)(pq1 & 0xffff));
            x1b = b2f((unsigned short)(pq1 >> 16));
        }
        s8v ae0, ae1;
        {
            float f8[8]; feats8(x0a, x1a, qd, f8);
            unsigned* au = (unsigned*)&ae0;
            #pragma unroll
            for (int jj = 0; jj < 4; jj++) au[jj] = pk_bf16(f8[2 * jj], f8[2 * jj + 1]);
        }
        {
            float f8[8]; feats8(x0b, x1b, qd, f8);
            unsigned* au = (unsigned*)&ae1;
            #pragma unroll
            for (int jj = 0; jj < 4; jj++) au[jj] = pk_bf16(f8[2 * jj], f8[2 * jj + 1]);
        }
        const unsigned short* pb = pweT + l16 * 32 + qd * 8;
        #pragma unroll
        for (int nt = 0; nt < 8; nt++) {
            s8v aw = *(const s8v*)(pb + nt * 512);
            f4v x0 = {0.f, 0.f, 0.f, 0.f}, x1 = {0.f, 0.f, 0.f, 0.f};
            x0 = MFMA_BF16(aw, ae0, x0, 0, 0, 0);
            x1 = MFMA_BF16(aw, ae1, x1, 0, 0, 0);
            CBDEF;
            float4 bb = *(const float4*)&pebs[cb];
            float h0 = __sinf(x0[0] + bb.x), h1 = __sinf(x0[1] + bb.y);
            float h2 = __sinf(x0[2] + bb.z), h3 = __sinf(x0[3] + bb.w);
            f2v ha = {h0, h1}, hb = {h2, h3};
            hresv[0][nt][0] = ha; hresv[0][nt][1] = hb;
            pkd[0][nt][0] = pk_bf16(h0, h1);
            pkd[0][nt][1] = pk_bf16(h2, h3);
            float g0 = __sinf(x1[0] + bb.x), g1 = __sinf(x1[1] + bb.y);
            float g2 = __sinf(x1[2] + bb.z), g3 = __sinf(x1[3] + bb.w);
            f2v ga = {g0, g1}, gb = {g2, g3};
            hresv[1][nt][0] = ga; hresv[1][nt][1] = gb;
            pkd[1][nt][0] = pk_bf16(g0, g1);
            pkd[1][nt][1] = pk_bf16(g2, g3);
        }
    }

    s8v bf0[4], bf1[4];

    // epilogue bodies (f2v pair math -> v_pk_add/mul_f32)
    #define EPI_MM1 {                                                         \
        CBDEF;                                                                \
        float4 bb = *(const float4*)&bql[cb];                                 \
        f2v xa = {x[0], x[1]}, xb = {x[2], x[3]};                             \
        f2v ba = {bb.x, bb.y}, bc = {bb.z, bb.w};                             \
        f2v va = xa + ba, vb = xb + bc;                                       \
        f2v sa = va * va, sb = vb * vb;                                       \
        pkd[tile][nt][0] = pk_bf16(sa[0], sa[1]);                             \
        pkd[tile][nt][1] = pk_bf16(sb[0], sb[1]);                             \
    }
    #define EPI_RES(BIAS) {                                                   \
        CBDEF;                                                                \
        float4 bb = *(const float4*)&BIAS[cb];                                \
        f2v xa = {x[0], x[1]}, xb = {x[2], x[3]};                             \
        f2v ba = {bb.x, bb.y}, bc = {bb.z, bb.w};                             \
        f2v va = hresv[tile][nt][0] + xa + ba;                                \
        f2v vb = hresv[tile][nt][1] + xb + bc;                                \
        hresv[tile][nt][0] = va; hresv[tile][nt][1] = vb;                     \
        pkd[tile][nt][0] = pk_bf16(va[0], va[1]);                             \
        pkd[tile][nt][1] = pk_bf16(vb[0], vb[1]);                             \
    }
    #define EPI_GELU {                                                        \
        CBDEF;                                                                \
        float4 bb = *(const float4*)&b1l[cb];                                 \
        float g0 = gelu_l(x[0] + bb.x), g1 = gelu_l(x[1] + bb.y);             \
        float g2 = gelu_l(x[2] + bb.z), g3 = gelu_l(x[3] + bb.w);             \
        pkd[tile][nt][0] = pk_bf16(g0, g1);                                   \
        pkd[tile][nt][1] = pk_bf16(g2, g3);                                   \
    }

    // ===== 3 transformer layers (half-matrix double-buffer pipeline) =====
    // invariant at each mm start: buf0 = M.h0 resident, buf1 = M.h1 in flight
    for (int l = 0; l < 3; l++) {
        const float* bql = &biasAll[(l * 4 + 0) * 128];
        const float* bol = &biasAll[(l * 4 + 1) * 128];
        const float* b1l = &biasAll[(l * 4 + 2) * 128];
        const float* b2l = &biasAll[(l * 4 + 3) * 128];

        // kf loads issued early (resident by den)
        s8v kf[4];
        {
            const unsigned short* kb = ksT + l * 2048 + l16 * 128 + qd * 8;
            #pragma unroll
            for (int ks = 0; ks < 4; ks++) kf[ks] = *(const s8v*)(kb + ks * 32);
        }

        // mm1: qh = (h @ Wq + bq)^2
        CAPTURE();
        MM_HALF(wb0, 0, EPI_MM1);
        __syncthreads();                          // wq.h1 drained; buf0 free
        stage_gll<4>(waT + l * 16384, wb0, wvi, ln);
        MM_HALF(wb1, 2, EPI_MM1);
        __syncthreads();                          // wa.h0 drained; buf1 free
        stage_gll<4>(waT + l * 16384 + 8192, wb1, wvi, ln);

        // den: d[h] = qh_row . ksum_h (register MFMA); z-scale pkd in place
        #pragma unroll
        for (int tile = 0; tile < 2; tile++) {
            f4v d = {0.f, 0.f, 0.f, 0.f};
            #pragma unroll
            for (int ks = 0; ks < 4; ks++) {
                s8v b = mkfrag(pkd[tile][2 * ks][0], pkd[tile][2 * ks][1],
                               pkd[tile][2 * ks + 1][0], pkd[tile][2 * ks + 1][1]);
                d = MFMA_BF16(kf[ks], b, d, 0, 0, 0);
            }
            #pragma unroll
            for (int ks = 0; ks < 4; ks++) {
                float z = 1.f / (__shfl(d[ks], l16) + 1e-6f);
                #pragma unroll
                for (int h2 = 0; h2 < 2; h2++) {
                    #pragma unroll
                    for (int j = 0; j < 2; j++) {
                        unsigned w = pkd[tile][2 * ks + h2][j];
                        float lo = __uint_as_float(w << 16) * z;
                        float hi = __uint_as_float(w & 0xffff0000u) * z;
                        pkd[tile][2 * ks + h2][j] = pk_bf16(lo, hi);
                    }
                }
            }
        }

        // mm2: x = h + (z*qh) @ Wa + bo
        CAPTURE();
        MM_HALF(wb0, 0, EPI_RES(bol));
        __syncthreads();                          // wa.h1 drained; buf0 free
        stage_gll<4>(w1T + l * 16384, wb0, wvi, ln);
        MM_HALF(wb1, 2, EPI_RES(bol));
        __syncthreads();                          // w1.h0 drained; buf1 free
        stage_gll<4>(w1T + l * 16384 + 8192, wb1, wvi, ln);

        // mm3: t = gelu(x @ W1 + b1)
        CAPTURE();
        MM_HALF(wb0, 0, EPI_GELU);
        __syncthreads();                          // w1.h1 drained; buf0 free
        stage_gll<4>(w2T + l * 16384, wb0, wvi, ln);
        MM_HALF(wb1, 2, EPI_GELU);
        __syncthreads();                          // w2.h0 drained; buf1 free
        stage_gll<4>(w2T + l * 16384 + 8192, wb1, wvi, ln);

        // mm4: h_new = x + t @ W2 + b2
        CAPTURE();
        MM_HALF(wb0, 0, EPI_RES(b2l));
        __syncthreads();                          // w2.h1 drained; buf0 free
        if (l < 2) stage_gll<4>(wqT + (l + 1) * 16384, wb0, wvi, ln);
        else       stage_gll<4>(pw1T, wb0, wvi, ln);
        MM_HALF(wb1, 2, EPI_RES(b2l));
        __syncthreads();                          // next.h0 drained; buf1 free
        if (l < 2) stage_gll<4>(wqT + (l + 1) * 16384 + 8192, wb1, wvi, ln);
    }

    // ===== final projector: out = gelu(h @ pw1 + pb1) @ pw2 + pb2 =====
    // buf0 holds pw1T (16KB = local ntiles 0-3), drained at the last barrier
    {
        CAPTURE();
        float pt0[3] = {0.f, 0.f, 0.f}, pt1[3] = {0.f, 0.f, 0.f};
        #pragma unroll
        for (int p = 0; p < 2; p++) {
            f4v y00 = {0.f,0.f,0.f,0.f}, y01 = y00, y10 = y00, y11 = y00;
            #pragma unroll
            for (int ks = 0; ks < 4; ks++) {
                s8v wa = wfrag(wb0, p * 2,     ks, l16, qd);
                s8v wb = wfrag(wb0, p * 2 + 1, ks, l16, qd);
                y00 = MFMA_BF16(wa, bf0[ks], y00, 0, 0, 0);
                y01 = MFMA_BF16(wa, bf1[ks], y01, 0, 0, 0);
                y10 = MFMA_BF16(wb, bf0[ks], y10, 0, 0, 0);
                y11 = MFMA_BF16(wb, bf1[ks], y11, 0, 0, 0);
            }
            #pragma unroll
            for (int e = 0; e < 2; e++) {
                int c0 = (p * 2 + e) * 16 + qd * 4;   // pw1T linear -> actual col
                float4 bb = *(const float4*)&pb1s[c0];
                f4v ya = e ? y10 : y00;   // tile 0
                f4v yb = e ? y11 : y01;   // tile 1
                #pragma unroll
                for (int i = 0; i < 4; i++) {
                    float bbi = (i == 0) ? bb.x : (i == 1) ? bb.y : (i == 2) ? bb.z : bb.w;
                    float4 w = *(const float4*)&w2s4[(c0 + i) * 4];
                    float ga = gelu_l(ya[i] + bbi);
                    float gb = gelu_l(yb[i] + bbi);
                    pt0[0] = fmaf(ga, w.x, pt0[0]);
                    pt0[1] = fmaf(ga, w.y, pt0[1]);
                    pt0[2] = fmaf(ga, w.z, pt0[2]);
                    pt1[0] = fmaf(gb, w.x, pt1[0]);
                    pt1[1] = fmaf(gb, w.y, pt1[1]);
                    pt1[2] = fmaf(gb, w.z, pt1[2]);
                }
            }
        }
        // reduce over the qd group (lane bits 4-5), then lane qd==0 stores
        #pragma unroll
        for (int c = 0; c < 3; c++) {
            pt0[c] += __shfl_xor(pt0[c], 16); pt0[c] += __shfl_xor(pt0[c], 32);
            pt1[c] += __shfl_xor(pt1[c], 16); pt1[c] += __shfl_xor(pt1[c], 32);
            pt0[c] += pb2s[c]; pt1[c] += pb2s[c];
        }
        if (ln < 16) {
            size_t r0 = (size_t)(row0 + rA0) * 3;
            size_t r1 = (size_t)(row0 + rA0 + 16) * 3;
            if (isf32) {
                float* o = (float*)outv;
                o[r0] = pt0[0]; o[r0 + 1] = pt0[1]; o[r0 + 2] = pt0[2];
                o[r1] = pt1[0]; o[r1 + 1] = pt1[1]; o[r1 + 2] = pt1[2];
            } else {
                unsigned short* o = (unsigned short*)outv;
                o[r0] = f2b(pt0[0]); o[r0 + 1] = f2b(pt0[1]); o[r0 + 2] = f2b(pt0[2]);
                o[r1] = f2b(pt1[0]); o[r1 + 1] = f2b(pt1[1]); o[r1 + 2] = f2b(pt1[2]);
            }
        }
    }
}

// ---------- launch ----------
extern "C" void kernel_launch(void* const* d_in, const int* in_sizes, int n_in,
                              void* d_out, int out_size, void* d_ws, size_t ws_size,
                              hipStream_t stream) {
    const int N = in_sizes[0] / 2;   // 262144
    const int M = in_sizes[1] / 2;   // 4096

    // raw input pointers (indices per setup_inputs order)
    const unsigned short* r_qpts = (const unsigned short*)d_in[0];
    const unsigned short* r_bpts = (const unsigned short*)d_in[1];
    const unsigned short* r_pew  = (const unsigned short*)d_in[2];
    const unsigned short* r_peb  = (const unsigned short*)d_in[3];
    const unsigned short* r_bpew = (const unsigned short*)d_in[4];
    const unsigned short* r_bpeb = (const unsigned short*)d_in[5];
    const unsigned short* r_Wq   = (const unsigned short*)d_in[6];
    const unsigned short* r_bq   = (const unsigned short*)d_in[7];
    const unsigned short* r_Wk   = (const unsigned short*)d_in[8];
    const unsigned short* r_bk   = (const unsigned short*)d_in[9];
    const unsigned short* r_Wv   = (const unsigned short*)d_in[10];
    const unsigned short* r_bv   = (const unsigned short*)d_in[11];
    const unsigned short* r_Wo   = (const unsigned short*)d_in[12];
    const unsigned short* r_bo   = (const unsigned short*)d_in[13];
    const unsigned short* r_W1   = (const unsigned short*)d_in[14];
    const unsigned short* r_b1   = (const unsigned short*)d_in[15];
    const unsigned short* r_W2   = (const unsigned short*)d_in[16];
    const unsigned short* r_b2   = (const unsigned short*)d_in[17];
    const unsigned short* r_pw1  = (const unsigned short*)d_in[18];
    const unsigned short* r_pb1  = (const unsigned short*)d_in[19];
    const unsigned short* r_pw2  = (const unsigned short*)d_in[20];
    const unsigned short* r_pb2  = (const unsigned short*)d_in[21];

    float* ws = (float*)d_ws;
    float* b_enc = ws;                                     // M*128
    float* kvs   = b_enc + (size_t)M * 128;                // 12288
    float* kss   = kvs + 12288;                            // 384
    unsigned short* wqT  = (unsigned short*)(kss + 384);   // 3*16384
    unsigned short* waT  = wqT + 49152;
    unsigned short* w1T  = waT + 49152;
    unsigned short* w2T  = w1T + 49152;
    unsigned short* ksT  = w2T + 49152;                    // 3*2048
    unsigned short* pw1T = ksT + 6144;                     // 8192
    unsigned short* pweT = pw1T + 8192;                    // 4096

    encode_kernel<<<M / 8, 256, 0, stream>>>(
        r_bpts, r_bpew, r_bpeb, r_pew, b_enc, kvs);
    khvred_kernel<<<384, 1024, 0, stream>>>(
        b_enc, r_Wk, r_bk, r_Wv, r_bv, r_pew, kvs, kss);
    prep_kernel<<<215040 / 256, 256, 0, stream>>>(
        r_Wq, r_W1, r_W2, r_pw1, kvs, kss, r_Wo, r_pew,
        wqT, w1T, w2T, pw1T, waT, ksT, pweT);
    mega_kernel<<<N / 128, 256, 0, stream>>>(
        r_qpts, pweT, r_peb, wqT, waT, ksT, w1T, w2T,
        r_bq, r_bo, r_b1, r_b2, pw1T, r_pb1, r_pw2, r_pb2, r_pew, d_out);
}

// Round 9
// 354.575 us; speedup vs baseline: 2.6365x; 1.0066x over previous
//
#include <hip/hip_runtime.h>
#include <hip/hip_bf16.h>

// ---------- helpers ----------
__device__ __forceinline__ float b2f(unsigned short u) {
    return __uint_as_float(((unsigned)u) << 16);
}
__device__ __forceinline__ unsigned short f2b(float f) {
    __hip_bfloat16 h = __float2bfloat16(f);
    return *reinterpret_cast<unsigned short*>(&h);
}
// pack two f32 -> packed 2x bf16 (RNE), single VALU op
__device__ __forceinline__ unsigned pk_bf16(float lo, float hi) {
    unsigned r;
    asm("v_cvt_pk_bf16_f32 %0, %1, %2" : "=v"(r) : "v"(lo), "v"(hi));
    return r;
}
// hardware exp2 (v_exp_f32 computes 2^x)
__device__ __forceinline__ float exp2_hw(float x) {
    float r;
    asm("v_exp_f32 %0, %1" : "=v"(r) : "v"(x));
    return r;
}
__device__ __forceinline__ float sigm(float v) {
    return 1.f / (1.f + __expf(-v));
}
// lean tanh-approx GELU, exp2 form: g = x - x/(1+2^(x*(c1+c2*x^2)))
__device__ __forceinline__ float gelu_l(float x) {
    float x2 = x * x;
    float y  = x * __builtin_fmaf(0.10294535f, x2, 2.3022137f);
    float e  = exp2_hw(y);
    float r  = __builtin_amdgcn_rcpf(e + 1.f);
    return __builtin_fmaf(-x, r, x);
}

typedef __attribute__((ext_vector_type(8))) short s8v;   // 8 bf16 (4 VGPRs)
typedef __attribute__((ext_vector_type(4))) float f4v;   // 4 fp32 acc
typedef __attribute__((ext_vector_type(2))) float f2v;   // fp32 pair (v_pk_*)

#define MFMA_BF16 __builtin_amdgcn_mfma_f32_16x16x32_bf16

__device__ __forceinline__ s8v mkfrag(unsigned a, unsigned b, unsigned c, unsigned d) {
    union { unsigned u[4]; s8v v; } x;
    x.u[0] = a; x.u[1] = b; x.u[2] = c; x.u[3] = d;
    return x.v;
}

// dtype detection (replaces convert_kernel): same decision rule as the old
// convert (256 samples of pe_w's even ushorts interpreted as bf16; >=16
// "not small" => f32). Wave-level ballot => wave-uniform, deterministic,
// identical in every kernel. Safe for both dtypes (idx <= 510 < 3840).
__device__ __forceinline__ int detect_f32(const unsigned short* __restrict__ raw) {
    int ln = threadIdx.x & 63;
    int c = 0;
    #pragma unroll
    for (int j = 0; j < 4; j++) {
        float v = b2f(raw[(ln * 4 + j) * 2]);
        unsigned long long m = __ballot(!(fabsf(v) < 1.0f));
        c += __popcll(m);
    }
    return c >= 16;
}

// sigma: slot s -> actual column. s{i[1:0],qd[1:0],ntlo,nthi[1:0]} ->
// c{i[1:0], ntlo, qd[1:0], nthi[1:0]}. Bijective bit permutation.
// With weight ROWS stored at slots, the MFMA C output of slot (nt,qd,i) is
// actual col (nt>>1)*32 + qd*8 + (nt&1)*4 + i -> each lane's C is exactly
// the next mm's B-fragment (lane-local renaming, no LDS round-trip).
__device__ __forceinline__ int fmap(int s) {
    return (s & ~31) | (((s >> 2) & 3) << 3) | (((s >> 4) & 1) << 2) | (s & 3);
}
// inverse LDS bank swizzle applied in GLOBAL memory (ushort index involution):
// gll copies linearly, wfrag reads with byte XOR ((l16&7)<<4); pre-permuting
// the source by the same involution keeps both sides consistent.
__device__ __forceinline__ int swz_q(int q) {
    return q ^ (((q >> 7) & 7) << 3);
}

// ---------- 15-feature map on raw (x0,x1) ----------
__device__ __forceinline__ void make_feats2(float x0, float x1, float* __restrict__ f) {
    const float PI = 3.14159265358979323846f;
    float a0 = x0 - 1.5f, a1 = x1 - 1.5f, c0 = x0 - 4.5f, c1 = x1 - 4.5f;
    f[0] = x0;        f[1] = x1;
    f[2] = x0 * x0;   f[3] = x1 * x1;
    f[4] = a0 * a0;   f[5] = a1 * a1;
    f[6] = c0 * c0;   f[7] = c1 * c1;
    f[8] = sigm(x0);  f[9] = sigm(x1);
    f[10] = sigm(a0); f[11] = sigm(a1);
    f[12] = sigm(c0); f[13] = sigm(c1);
    f[14] = a0;       f[15] = a1;
    f[16] = c0;       f[17] = c1;
    f[18] = __sinf(PI * x0);          f[19] = __sinf(PI * x1);
    f[20] = __cosf(PI * x0);          f[21] = __cosf(PI * x1);
    f[22] = __sinf(PI * 0.25f * x0);  f[23] = __sinf(PI * 0.25f * x1);
    f[24] = __cosf(PI * 0.25f * x0);  f[25] = __cosf(PI * 0.25f * x1);
    f[26] = __sinf(PI * 0.5f * x0);   f[27] = __sinf(PI * 0.5f * x1);
    f[28] = __cosf(PI * 0.5f * x0);   f[29] = __cosf(PI * 0.5f * x1);
}

// 8 features for k = qd*8 .. qd*8+7 (quad-split of the 30-vector, 30/31 -> 0)
__device__ __forceinline__ void feats8(float x0, float x1, int qd, float* __restrict__ f8) {
    const float PI = 3.14159265358979323846f;
    float a0 = x0 - 1.5f, a1 = x1 - 1.5f, c0 = x0 - 4.5f, c1 = x1 - 4.5f;
    if (qd == 0) {
        f8[0] = x0;      f8[1] = x1;
        f8[2] = x0 * x0; f8[3] = x1 * x1;
        f8[4] = a0 * a0; f8[5] = a1 * a1;
        f8[6] = c0 * c0; f8[7] = c1 * c1;
    } else if (qd == 1) {
        f8[0] = sigm(x0); f8[1] = sigm(x1);
        f8[2] = sigm(a0); f8[3] = sigm(a1);
        f8[4] = sigm(c0); f8[5] = sigm(c1);
        f8[6] = a0;       f8[7] = a1;
    } else if (qd == 2) {
        f8[0] = c0; f8[1] = c1;
        f8[2] = __sinf(PI * x0);          f8[3] = __sinf(PI * x1);
        f8[4] = __cosf(PI * x0);          f8[5] = __cosf(PI * x1);
        f8[6] = __sinf(PI * 0.25f * x0);  f8[7] = __sinf(PI * 0.25f * x1);
    } else {
        f8[0] = __cosf(PI * 0.25f * x0);  f8[1] = __cosf(PI * 0.25f * x1);
        f8[2] = __sinf(PI * 0.5f * x0);   f8[3] = __sinf(PI * 0.5f * x1);
        f8[4] = __cosf(PI * 0.5f * x0);   f8[5] = __cosf(PI * 0.5f * x1);
        f8[6] = 0.f;                      f8[7] = 0.f;
    }
}

// raw accessors: explicit uniform branch (NEVER speculate the wrong-dtype
// load -- it can be OOB on the smaller buffer).
__device__ __forceinline__ unsigned short ldb(const unsigned short* __restrict__ p, int idx, int isf32) {
    unsigned short v;
    if (isf32) v = f2b(((const float*)p)[idx]);
    else       v = p[idx];
    return v;
}

// ---------- boundary positional encoding (raw inputs, + kvs/kss zeroing) ----------
__global__ __launch_bounds__(256) void encode_kernel(
    const unsigned short* __restrict__ pts_raw,
    const unsigned short* __restrict__ w_raw,
    const unsigned short* __restrict__ b_raw,
    const unsigned short* __restrict__ pe_w_raw,
    float* __restrict__ out, float* __restrict__ kvz)
{
    int isf32 = detect_f32(pe_w_raw);
    __shared__ __align__(16) float wsm[30 * 128];
    __shared__ float bs[128];
    int t = threadIdx.x;
    int g = blockIdx.x * 256 + t;
    if (g < 12672) kvz[g] = 0.f;   // kvs(12288) + kss(384), contiguous

    if (isf32) {
        const float* w = (const float*)w_raw;
        for (int i = t; i < 30 * 128; i += 256) wsm[i] = w[i];
        if (t < 128) bs[t] = ((const float*)b_raw)[t];
    } else {
        for (int i = t; i < 30 * 128; i += 256) wsm[i] = b2f(w_raw[i]);
        if (t < 128) bs[t] = b2f(b_raw[t]);
    }
    __syncthreads();

    int r = blockIdx.x * 8 + (t >> 5);
    int j = t & 31;
    float x0, x1;
    if (isf32) {
        float2 p = ((const float2*)pts_raw)[r];
        x0 = p.x; x1 = p.y;
    } else {
        unsigned pq = ((const unsigned*)pts_raw)[r];
        x0 = b2f((unsigned short)(pq & 0xffff));
        x1 = b2f((unsigned short)(pq >> 16));
    }
    float f[30];
    make_feats2(x0, x1, f);
    float s0 = bs[j * 4 + 0], s1 = bs[j * 4 + 1], s2 = bs[j * 4 + 2], s3 = bs[j * 4 + 3];
    #pragma unroll
    for (int ff = 0; ff < 30; ff++) {
        float4 wv = *(const float4*)&wsm[ff * 128 + j * 4];
        float fv = f[ff];
        s0 += fv * wv.x; s1 += fv * wv.y; s2 += fv * wv.z; s3 += fv * wv.w;
    }
    *(float4*)&out[(size_t)r * 128 + j * 4] =
        make_float4(__sinf(s0), __sinf(s1), __sinf(s2), __sinf(s3));
}

// ---------- FUSED k/v heads + reduction ----------
__global__ __launch_bounds__(1024) void khvred_kernel(
    const float* __restrict__ benc,
    const unsigned short* __restrict__ Wk_raw, const unsigned short* __restrict__ bk_raw,
    const unsigned short* __restrict__ Wv_raw, const unsigned short* __restrict__ bv_raw,
    const unsigned short* __restrict__ pe_w_raw,
    float* __restrict__ kvsum, float* __restrict__ ksum)
{
    int isf32 = detect_f32(pe_w_raw);
    __shared__ float khs[1024];
    __shared__ float vhs[1024];
    int t = threadIdx.x;
    int lh = blockIdx.x >> 5;        // 0..11
    int part = blockIdx.x & 31;      // 32 x 128 rows
    int mm = t >> 5, dd = t & 31;    // phase A roles
    int dd2 = t >> 5, ee = t & 31;   // phase B roles
    float kva = 0.f, ksa = 0.f;

    for (int ch = 0; ch < 4; ch++) {
        int m = part * 128 + ch * 32 + mm;
        const float* br = benc + (size_t)m * 128;
        float ka, va;
        if (isf32) {
            const float* wk = (const float*)Wk_raw + lh * 4096 + dd;
            const float* wv = (const float*)Wv_raw + lh * 4096 + dd;
            float a = 0.f, b = 0.f;
            #pragma unroll 8
            for (int c = 0; c < 128; c++) {
                float bb = br[c];
                a += bb * wk[c * 32];
                b += bb * wv[c * 32];
            }
            ka = a + ((const float*)bk_raw)[lh * 32 + dd];
            va = b + ((const float*)bv_raw)[lh * 32 + dd];
        } else {
            const unsigned short* wk = Wk_raw + lh * 4096 + dd;
            const unsigned short* wv = Wv_raw + lh * 4096 + dd;
            float a = 0.f, b = 0.f;
            #pragma unroll 8
            for (int c = 0; c < 128; c++) {
                float bb = br[c];
                a += bb * b2f(wk[c * 32]);
                b += bb * b2f(wv[c * 32]);
            }
            ka = a + b2f(bk_raw[lh * 32 + dd]);
            va = b + b2f(bv_raw[lh * 32 + dd]);
        }
        ka = ka * ka;
        khs[mm * 32 + dd] = ka;
        vhs[mm * 32 + dd] = va;
        __syncthreads();
        #pragma unroll
        for (int i = 0; i < 32; i++) {
            float kk = khs[i * 32 + dd2];
            kva += kk * vhs[i * 32 + ee];
            ksa += kk;
        }
        __syncthreads();
    }
    atomicAdd(&kvsum[lh * 1024 + dd2 * 32 + ee], kva);
    if (ee == 0) atomicAdd(&ksum[lh * 32 + dd2], ksa);
}

// ---------- prep: sigma rows + PRE-SWIZZLED storage + Wa fold + Ks (raw in) ----------
__global__ __launch_bounds__(256) void prep_kernel(
    const unsigned short* __restrict__ Wq, const unsigned short* __restrict__ W1,
    const unsigned short* __restrict__ W2, const unsigned short* __restrict__ pw1,
    const float* __restrict__ kvs, const float* __restrict__ kss,
    const unsigned short* __restrict__ Wo, const unsigned short* __restrict__ pe_w,
    unsigned short* __restrict__ wqT, unsigned short* __restrict__ w1T,
    unsigned short* __restrict__ w2T, unsigned short* __restrict__ pw1T,
    unsigned short* __restrict__ waT, unsigned short* __restrict__ ksT,
    unsigned short* __restrict__ pweT)
{
    int isf32 = detect_f32(pe_w);
    int g = blockIdx.x * 256 + threadIdx.x;
    if (g < 49152) {
        int l = g >> 14, q = swz_q(g & 16383), n = q >> 7, k = q & 127;
        int na = fmap(n);   // head-interleaved actual col
        wqT[g] = ldb(Wq, ((l * 4 + (na >> 5)) * 128 + k) * 32 + (na & 31), isf32);
    } else if (g < 98304) {
        int q0 = g - 49152; int l = q0 >> 14, q = swz_q(q0 & 16383), n = q >> 7, k = q & 127;
        w1T[q0] = ldb(W1, (l * 128 + k) * 128 + fmap(n), isf32);
    } else if (g < 147456) {
        int q0 = g - 98304; int l = q0 >> 14, q = swz_q(q0 & 16383), n = q >> 7, k = q & 127;
        w2T[q0] = ldb(W2, (l * 128 + k) * 128 + fmap(n), isf32);
    } else if (g < 155648) {
        int q0 = g - 147456; int q = swz_q(q0), n = q >> 7, k = q & 127;
        pw1T[q0] = ldb(pw1, k * 64 + n, isf32);          // linear cols (no sigma)
    } else if (g < 204800) {
        int q0 = g - 155648; int l = q0 >> 14, q = swz_q(q0 & 16383), n = q >> 7, k = q & 127;
        int na = fmap(n);
        int hk = k >> 5, dk = k & 31;
        const float* kvp = kvs + (l * 4 + hk) * 1024 + dk * 32;
        float s = 0.f;
        if (isf32) {
            const float* wop = (const float*)Wo + (size_t)(l * 128 + hk * 32) * 128 + na;
            #pragma unroll 8
            for (int j = 0; j < 32; j++) s += kvp[j] * wop[j * 128];
        } else {
            const unsigned short* wop = Wo + (size_t)(l * 128 + hk * 32) * 128 + na;
            #pragma unroll 8
            for (int j = 0; j < 32; j++) s += kvp[j] * b2f(wop[j * 128]);
        }
        waT[q0] = f2b(s);
    } else if (g < 210944) {
        int q = g - 204800; int l = q >> 11, r = q & 2047, n = r >> 7, k = r & 127;
        unsigned short v = 0;
        if (n < 4 && (k >> 5) == n) v = f2b(kss[(l * 4 + n) * 32 + (k & 31)]);
        ksT[q] = v;                                      // linear (no swizzle)
    } else if (g < 215040) {
        int q = g - 210944; int n = q >> 5, k = q & 31;  // pe_wT [128 slot][32]
        pweT[q] = (k < 30) ? ldb(pe_w, k * 128 + fmap(n), isf32) : (unsigned short)0;
    }
}

// ---------- the fused mega kernel: encode + 3 layers + projector ----------
// ROUND-9: R8 discovery -- pre-mega time is a ~130us fixed harness floor
// (deleting 2 launches + 25MB traffic changed total by -0.5us). Only mega
// (180us, MFMA 27 + VALU 56 = 83%) is controllable. This round: T5
// s_setprio(1) around the pure-MFMA clusters (cross-BLOCK phase diversity:
// 2 blocks/CU at different phases -> scheduler can favor the MFMA-issuing
// wave; m224 regime) + v_rcp for the z divide. No structural changes.

template<int ITERS>
__device__ __forceinline__ void stage_gll(const unsigned short* __restrict__ g,
                                          unsigned short* __restrict__ lbase,
                                          int wvi, int ln) {
    const char* gp = (const char*)g + wvi * 1024 + ln * 16;
    char* lp = (char*)lbase + wvi * 1024;     // wave-uniform LDS base
    #pragma unroll
    for (int i = 0; i < ITERS; i++) {
        __builtin_amdgcn_global_load_lds(
            (const __attribute__((address_space(1))) unsigned int*)(gp + i * 4096),
            (__attribute__((address_space(3))) unsigned int*)(lp + i * 4096),
            16, 0, 0);
    }
}

// swizzled weight-fragment read from a 16KB HALF buffer: local ntile ntl
// (0-3), k-slice k, lane (qd,l16)
__device__ __forceinline__ s8v wfrag(const unsigned short* __restrict__ wb,
                                     int ntl, int k, int l16, int qd) {
    int lin = (ntl << 12) + (l16 << 8) + (k << 6) + (qd << 4);
    return *(const s8v*)((const char*)wb + (lin ^ ((l16 & 7) << 4)));
}

// capture pkd into MFMA B-fragments (sigma layout -> pure register renaming)
#define CAPTURE() do {                                                        \
    _Pragma("unroll")                                                         \
    for (int _s = 0; _s < 4; _s++) {                                          \
        bf0[_s] = mkfrag(pkd[0][2*_s][0], pkd[0][2*_s][1],                    \
                         pkd[0][2*_s+1][0], pkd[0][2*_s+1][1]);               \
        bf1[_s] = mkfrag(pkd[1][2*_s][0], pkd[1][2*_s][1],                    \
                         pkd[1][2*_s+1][0], pkd[1][2*_s+1][1]);               \
    }                                                                         \
} while (0)

// one HALF of a matmul: p = PB, PB+1 (PB=0: ntiles 0-3 from buf0; PB=2:
// ntiles 4-7 from buf1). Epilogue sees nt (global ntile), tile, x.
// MFMA cluster wrapped in s_setprio(1)/(0)  [T5].
#define MM_HALF(WB, PB, EPI...) do {                                          \
    _Pragma("unroll")                                                         \
    for (int _pp = 0; _pp < 2; _pp++) {                                       \
        const int _p = (PB) + _pp;                                            \
        f4v _x0 = {0.f,0.f,0.f,0.f}, _x1 = _x0, _y0 = _x0, _y1 = _x0;         \
        __builtin_amdgcn_s_setprio(1);                                        \
        _Pragma("unroll")                                                     \
        for (int _k = 0; _k < 4; _k++) {                                      \
            s8v _wa = wfrag(WB, (_p * 2) & 3,     _k, l16, qd);               \
            s8v _wb = wfrag(WB, (_p * 2 + 1) & 3, _k, l16, qd);               \
            _x0 = MFMA_BF16(_wa, bf0[_k], _x0, 0, 0, 0);                      \
            _x1 = MFMA_BF16(_wa, bf1[_k], _x1, 0, 0, 0);                      \
            _y0 = MFMA_BF16(_wb, bf0[_k], _y0, 0, 0, 0);                      \
            _y1 = MFMA_BF16(_wb, bf1[_k], _y1, 0, 0, 0);                      \
        }                                                                     \
        __builtin_amdgcn_s_setprio(0);                                        \
        { const int nt = _p * 2;     const int tile = 0; const f4v x = _x0; EPI } \
        { const int nt = _p * 2;     const int tile = 1; const f4v x = _x1; EPI } \
        { const int nt = _p * 2 + 1; const int tile = 0; const f4v x = _y0; EPI } \
        { const int nt = _p * 2 + 1; const int tile = 1; const f4v x = _y1; EPI } \
    }                                                                         \
} while (0)

#define CBDEF int cb = ((nt >> 1) << 5) + (qd << 3) + ((nt & 1) << 2)

__global__ __launch_bounds__(256) void mega_kernel(
    const unsigned short* __restrict__ qpts,
    const unsigned short* __restrict__ pweT,
    const unsigned short* __restrict__ pe_b,
    const unsigned short* __restrict__ wqT,
    const unsigned short* __restrict__ waT,
    const unsigned short* __restrict__ ksT,
    const unsigned short* __restrict__ w1T,
    const unsigned short* __restrict__ w2T,
    const unsigned short* __restrict__ bq,
    const unsigned short* __restrict__ bo,
    const unsigned short* __restrict__ b1,
    const unsigned short* __restrict__ b2,
    const unsigned short* __restrict__ pw1T,
    const unsigned short* __restrict__ pb1,
    const unsigned short* __restrict__ pw2,
    const unsigned short* __restrict__ pb2,
    const unsigned short* __restrict__ pe_w_raw,
    void* __restrict__ outv)
{
    __shared__ __align__(16) unsigned short wbuf[2][8192];   // 2 x 16KB halves
    __shared__ __align__(16) float biasAll[12 * 128];        // 6144 B
    __shared__ __align__(16) float pebs[128];
    __shared__ __align__(16) float pb1s[64];
    __shared__ __align__(16) float w2s4[256];                // w2 cols padded
    __shared__ float pb2s[3];

    int isf32 = detect_f32(pe_w_raw);
    int t = threadIdx.x;
    int wvi = t >> 6, ln = t & 63, qd = ln >> 4, l16 = ln & 15;
    int row0 = blockIdx.x * 128;
    int rA0 = wvi * 32 + l16;        // lane's row, tile 0 (tile 1: +16)
    unsigned short* wb0 = &wbuf[0][0];
    unsigned short* wb1 = &wbuf[1][0];

    // issue wq[0].h0 -> buf0 immediately (latency covered by bias staging)
    stage_gll<4>(wqT, wb0, wvi, ln);

    // ===== one-time staging (raw biases, dtype-dispatched) =====
    if (isf32) {
        for (int i = t; i < 1536; i += 256) {
            int l = i >> 9, rem = i & 511, which = rem >> 7, c = rem & 127;
            const unsigned short* bsrc = (which == 0) ? bq : (which == 1) ? bo
                                       : (which == 2) ? b1 : b2;
            biasAll[i] = ((const float*)bsrc)[l * 128 + c];
        }
        if (t < 128) pebs[t] = ((const float*)pe_b)[t];
        if (t < 64)  pb1s[t] = ((const float*)pb1)[t];
        if (t < 64) {
            const float* w = (const float*)pw2;
            w2s4[t * 4 + 0] = w[t * 3 + 0];
            w2s4[t * 4 + 1] = w[t * 3 + 1];
            w2s4[t * 4 + 2] = w[t * 3 + 2];
            w2s4[t * 4 + 3] = 0.f;
        }
        if (t < 3) pb2s[t] = ((const float*)pb2)[t];
    } else {
        for (int i = t; i < 1536; i += 256) {
            int l = i >> 9, rem = i & 511, which = rem >> 7, c = rem & 127;
            const unsigned short* bsrc = (which == 0) ? bq : (which == 1) ? bo
                                       : (which == 2) ? b1 : b2;
            biasAll[i] = b2f(bsrc[l * 128 + c]);
        }
        if (t < 128) pebs[t] = b2f(pe_b[t]);
        if (t < 64)  pb1s[t] = b2f(pb1[t]);
        if (t < 64) {
            w2s4[t * 4 + 0] = b2f(pw2[t * 3 + 0]);
            w2s4[t * 4 + 1] = b2f(pw2[t * 3 + 1]);
            w2s4[t * 4 + 2] = b2f(pw2[t * 3 + 2]);
            w2s4[t * 4 + 3] = 0.f;
        }
        if (t < 3) pb2s[t] = b2f(pb2[t]);
    }
    __syncthreads();   // drains wq.h0; bias tables visible

    // issue wq[0].h1 -> buf1; encode covers its latency
    stage_gll<4>(wqT + 8192, wb1, wvi, ln);

    unsigned pkd[2][8][2];   // packed bf16 activations, slot layout
    f2v hresv[2][8][2];      // fp32 residual pairs, slot layout

    // ===== encode via MFMA: h = sin(feats @ pe_w + pe_b), pweT sigma'd =====
    {
        float x0a, x1a, x0b, x1b;
        if (isf32) {
            float2 p0 = ((const float2*)qpts)[row0 + rA0];
            float2 p1 = ((const float2*)qpts)[row0 + rA0 + 16];
            x0a = p0.x; x1a = p0.y; x0b = p1.x; x1b = p1.y;
        } else {
            unsigned pq0 = ((const unsigned*)qpts)[row0 + rA0];
            unsigned pq1 = ((const unsigned*)qpts)[row0 + rA0 + 16];
            x0a = b2f((unsigned short)(pq0 & 0xffff));
            x1a = b2f((unsigned short)(pq0 >> 16));
            x0b = b2f((unsigned short)(pq1 & 0xffff));
            x1b = b2f((unsigned short)(pq1 >> 16));
        }
        s8v ae0, ae1;
        {
            float f8[8]; feats8(x0a, x1a, qd, f8);
            unsigned* au = (unsigned*)&ae0;
            #pragma unroll
            for (int jj = 0; jj < 4; jj++) au[jj] = pk_bf16(f8[2 * jj], f8[2 * jj + 1]);
        }
        {
            float f8[8]; feats8(x0b, x1b, qd, f8);
            unsigned* au = (unsigned*)&ae1;
            #pragma unroll
            for (int jj = 0; jj < 4; jj++) au[jj] = pk_bf16(f8[2 * jj], f8[2 * jj + 1]);
        }
        const unsigned short* pb = pweT + l16 * 32 + qd * 8;
        #pragma unroll
        for (int nt = 0; nt < 8; nt++) {
            s8v aw = *(const s8v*)(pb + nt * 512);
            f4v x0 = {0.f, 0.f, 0.f, 0.f}, x1 = {0.f, 0.f, 0.f, 0.f};
            x0 = MFMA_BF16(aw, ae0, x0, 0, 0, 0);
            x1 = MFMA_BF16(aw, ae1, x1, 0, 0, 0);
            CBDEF;
            float4 bb = *(const float4*)&pebs[cb];
            float h0 = __sinf(x0[0] + bb.x), h1 = __sinf(x0[1] + bb.y);
            float h2 = __sinf(x0[2] + bb.z), h3 = __sinf(x0[3] + bb.w);
            f2v ha = {h0, h1}, hb = {h2, h3};
            hresv[0][nt][0] = ha; hresv[0][nt][1] = hb;
            pkd[0][nt][0] = pk_bf16(h0, h1);
            pkd[0][nt][1] = pk_bf16(h2, h3);
            float g0 = __sinf(x1[0] + bb.x), g1 = __sinf(x1[1] + bb.y);
            float g2 = __sinf(x1[2] + bb.z), g3 = __sinf(x1[3] + bb.w);
            f2v ga = {g0, g1}, gb = {g2, g3};
            hresv[1][nt][0] = ga; hresv[1][nt][1] = gb;
            pkd[1][nt][0] = pk_bf16(g0, g1);
            pkd[1][nt][1] = pk_bf16(g2, g3);
        }
    }

    s8v bf0[4], bf1[4];

    // epilogue bodies (f2v pair math -> v_pk_add/mul_f32)
    #define EPI_MM1 {                                                         \
        CBDEF;                                                                \
        float4 bb = *(const float4*)&bql[cb];                                 \
        f2v xa = {x[0], x[1]}, xb = {x[2], x[3]};                             \
        f2v ba = {bb.x, bb.y}, bc = {bb.z, bb.w};                             \
        f2v va = xa + ba, vb = xb + bc;                                       \
        f2v sa = va * va, sb = vb * vb;                                       \
        pkd[tile][nt][0] = pk_bf16(sa[0], sa[1]);                             \
        pkd[tile][nt][1] = pk_bf16(sb[0], sb[1]);                             \
    }
    #define EPI_RES(BIAS) {                                                   \
        CBDEF;                                                                \
        float4 bb = *(const float4*)&BIAS[cb];                                \
        f2v xa = {x[0], x[1]}, xb = {x[2], x[3]};                             \
        f2v ba = {bb.x, bb.y}, bc = {bb.z, bb.w};                             \
        f2v va = hresv[tile][nt][0] + xa + ba;                                \
        f2v vb = hresv[tile][nt][1] + xb + bc;                                \
        hresv[tile][nt][0] = va; hresv[tile][nt][1] = vb;                     \
        pkd[tile][nt][0] = pk_bf16(va[0], va[1]);                             \
        pkd[tile][nt][1] = pk_bf16(vb[0], vb[1]);                             \
    }
    #define EPI_GELU {                                                        \
        CBDEF;                                                                \
        float4 bb = *(const float4*)&b1l[cb];                                 \
        float g0 = gelu_l(x[0] + bb.x), g1 = gelu_l(x[1] + bb.y);             \
        float g2 = gelu_l(x[2] + bb.z), g3 = gelu_l(x[3] + bb.w);             \
        pkd[tile][nt][0] = pk_bf16(g0, g1);                                   \
        pkd[tile][nt][1] = pk_bf16(g2, g3);                                   \
    }

    // ===== 3 transformer layers (half-matrix double-buffer pipeline) =====
    // invariant at each mm start: buf0 = M.h0 resident, buf1 = M.h1 in flight
    for (int l = 0; l < 3; l++) {
        const float* bql = &biasAll[(l * 4 + 0) * 128];
        const float* bol = &biasAll[(l * 4 + 1) * 128];
        const float* b1l = &biasAll[(l * 4 + 2) * 128];
        const float* b2l = &biasAll[(l * 4 + 3) * 128];

        // kf loads issued early (resident by den)
        s8v kf[4];
        {
            const unsigned short* kb = ksT + l * 2048 + l16 * 128 + qd * 8;
            #pragma unroll
            for (int ks = 0; ks < 4; ks++) kf[ks] = *(const s8v*)(kb + ks * 32);
        }

        // mm1: qh = (h @ Wq + bq)^2
        CAPTURE();
        MM_HALF(wb0, 0, EPI_MM1);
        __syncthreads();                          // wq.h1 drained; buf0 free
        stage_gll<4>(waT + l * 16384, wb0, wvi, ln);
        MM_HALF(wb1, 2, EPI_MM1);
        __syncthreads();                          // wa.h0 drained; buf1 free
        stage_gll<4>(waT + l * 16384 + 8192, wb1, wvi, ln);

        // den: d[h] = qh_row . ksum_h (register MFMA); z-scale pkd in place
        #pragma unroll
        for (int tile = 0; tile < 2; tile++) {
            f4v d = {0.f, 0.f, 0.f, 0.f};
            __builtin_amdgcn_s_setprio(1);
            #pragma unroll
            for (int ks = 0; ks < 4; ks++) {
                s8v b = mkfrag(pkd[tile][2 * ks][0], pkd[tile][2 * ks][1],
                               pkd[tile][2 * ks + 1][0], pkd[tile][2 * ks + 1][1]);
                d = MFMA_BF16(kf[ks], b, d, 0, 0, 0);
            }
            __builtin_amdgcn_s_setprio(0);
            #pragma unroll
            for (int ks = 0; ks < 4; ks++) {
                float z = __builtin_amdgcn_rcpf(__shfl(d[ks], l16) + 1e-6f);
                #pragma unroll
                for (int h2 = 0; h2 < 2; h2++) {
                    #pragma unroll
                    for (int j = 0; j < 2; j++) {
                        unsigned w = pkd[tile][2 * ks + h2][j];
                        float lo = __uint_as_float(w << 16) * z;
                        float hi = __uint_as_float(w & 0xffff0000u) * z;
                        pkd[tile][2 * ks + h2][j] = pk_bf16(lo, hi);
                    }
                }
            }
        }

        // mm2: x = h + (z*qh) @ Wa + bo
        CAPTURE();
        MM_HALF(wb0, 0, EPI_RES(bol));
        __syncthreads();                          // wa.h1 drained; buf0 free
        stage_gll<4>(w1T + l * 16384, wb0, wvi, ln);
        MM_HALF(wb1, 2, EPI_RES(bol));
        __syncthreads();                          // w1.h0 drained; buf1 free
        stage_gll<4>(w1T + l * 16384 + 8192, wb1, wvi, ln);

        // mm3: t = gelu(x @ W1 + b1)
        CAPTURE();
        MM_HALF(wb0, 0, EPI_GELU);
        __syncthreads();                          // w1.h1 drained; buf0 free
        stage_gll<4>(w2T + l * 16384, wb0, wvi, ln);
        MM_HALF(wb1, 2, EPI_GELU);
        __syncthreads();                          // w2.h0 drained; buf1 free
        stage_gll<4>(w2T + l * 16384 + 8192, wb1, wvi, ln);

        // mm4: h_new = x + t @ W2 + b2
        CAPTURE();
        MM_HALF(wb0, 0, EPI_RES(b2l));
        __syncthreads();                          // w2.h1 drained; buf0 free
        if (l < 2) stage_gll<4>(wqT + (l + 1) * 16384, wb0, wvi, ln);
        else       stage_gll<4>(pw1T, wb0, wvi, ln);
        MM_HALF(wb1, 2, EPI_RES(b2l));
        __syncthreads();                          // next.h0 drained; buf1 free
        if (l < 2) stage_gll<4>(wqT + (l + 1) * 16384 + 8192, wb1, wvi, ln);
    }

    // ===== final projector: out = gelu(h @ pw1 + pb1) @ pw2 + pb2 =====
    // buf0 holds pw1T (16KB = local ntiles 0-3), drained at the last barrier
    {
        CAPTURE();
        float pt0[3] = {0.f, 0.f, 0.f}, pt1[3] = {0.f, 0.f, 0.f};
        #pragma unroll
        for (int p = 0; p < 2; p++) {
            f4v y00 = {0.f,0.f,0.f,0.f}, y01 = y00, y10 = y00, y11 = y00;
            __builtin_amdgcn_s_setprio(1);
            #pragma unroll
            for (int ks = 0; ks < 4; ks++) {
                s8v wa = wfrag(wb0, p * 2,     ks, l16, qd);
                s8v wb = wfrag(wb0, p * 2 + 1, ks, l16, qd);
                y00 = MFMA_BF16(wa, bf0[ks], y00, 0, 0, 0);
                y01 = MFMA_BF16(wa, bf1[ks], y01, 0, 0, 0);
                y10 = MFMA_BF16(wb, bf0[ks], y10, 0, 0, 0);
                y11 = MFMA_BF16(wb, bf1[ks], y11, 0, 0, 0);
            }
            __builtin_amdgcn_s_setprio(0);
            #pragma unroll
            for (int e = 0; e < 2; e++) {
                int c0 = (p * 2 + e) * 16 + qd * 4;   // pw1T linear -> actual col
                float4 bb = *(const float4*)&pb1s[c0];
                f4v ya = e ? y10 : y00;   // tile 0
                f4v yb = e ? y11 : y01;   // tile 1
                #pragma unroll
                for (int i = 0; i < 4; i++) {
                    float bbi = (i == 0) ? bb.x : (i == 1) ? bb.y : (i == 2) ? bb.z : bb.w;
                    float4 w = *(const float4*)&w2s4[(c0 + i) * 4];
                    float ga = gelu_l(ya[i] + bbi);
                    float gb = gelu_l(yb[i] + bbi);
                    pt0[0] = fmaf(ga, w.x, pt0[0]);
                    pt0[1] = fmaf(ga, w.y, pt0[1]);
                    pt0[2] = fmaf(ga, w.z, pt0[2]);
                    pt1[0] = fmaf(gb, w.x, pt1[0]);
                    pt1[1] = fmaf(gb, w.y, pt1[1]);
                    pt1[2] = fmaf(gb, w.z, pt1[2]);
                }
            }
        }
        // reduce over the qd group (lane bits 4-5), then lane qd==0 stores
        #pragma unroll
        for (int c = 0; c < 3; c++) {
            pt0[c] += __shfl_xor(pt0[c], 16); pt0[c] += __shfl_xor(pt0[c], 32);
            pt1[c] += __shfl_xor(pt1[c], 16); pt1[c] += __shfl_xor(pt1[c], 32);
            pt0[c] += pb2s[c]; pt1[c] += pb2s[c];
        }
        if (ln < 16) {
            size_t r0 = (size_t)(row0 + rA0) * 3;
            size_t r1 = (size_t)(row0 + rA0 + 16) * 3;
            if (isf32) {
                float* o = (float*)outv;
                o[r0] = pt0[0]; o[r0 + 1] = pt0[1]; o[r0 + 2] = pt0[2];
                o[r1] = pt1[0]; o[r1 + 1] = pt1[1]; o[r1 + 2] = pt1[2];
            } else {
                unsigned short* o = (unsigned short*)outv;
                o[r0] = f2b(pt0[0]); o[r0 + 1] = f2b(pt0[1]); o[r0 + 2] = f2b(pt0[2]);
                o[r1] = f2b(pt1[0]); o[r1 + 1] = f2b(pt1[1]); o[r1 + 2] = f2b(pt1[2]);
            }
        }
    }
}

// ---------- launch ----------
extern "C" void kernel_launch(void* const* d_in, const int* in_sizes, int n_in,
                              void* d_out, int out_size, void* d_ws, size_t ws_size,
                              hipStream_t stream) {
    const int N = in_sizes[0] / 2;   // 262144
    const int M = in_sizes[1] / 2;   // 4096

    // raw input pointers (indices per setup_inputs order)
    const unsigned short* r_qpts = (const unsigned short*)d_in[0];
    const unsigned short* r_bpts = (const unsigned short*)d_in[1];
    const unsigned short* r_pew  = (const unsigned short*)d_in[2];
    const unsigned short* r_peb  = (const unsigned short*)d_in[3];
    const unsigned short* r_bpew = (const unsigned short*)d_in[4];
    const unsigned short* r_bpeb = (const unsigned short*)d_in[5];
    const unsigned short* r_Wq   = (const unsigned short*)d_in[6];
    const unsigned short* r_bq   = (const unsigned short*)d_in[7];
    const unsigned short* r_Wk   = (const unsigned short*)d_in[8];
    const unsigned short* r_bk   = (const unsigned short*)d_in[9];
    const unsigned short* r_Wv   = (const unsigned short*)d_in[10];
    const unsigned short* r_bv   = (const unsigned short*)d_in[11];
    const unsigned short* r_Wo   = (const unsigned short*)d_in[12];
    const unsigned short* r_bo   = (const unsigned short*)d_in[13];
    const unsigned short* r_W1   = (const unsigned short*)d_in[14];
    const unsigned short* r_b1   = (const unsigned short*)d_in[15];
    const unsigned short* r_W2   = (const unsigned short*)d_in[16];
    const unsigned short* r_b2   = (const unsigned short*)d_in[17];
    const unsigned short* r_pw1  = (const unsigned short*)d_in[18];
    const unsigned short* r_pb1  = (const unsigned short*)d_in[19];
    const unsigned short* r_pw2  = (const unsigned short*)d_in[20];
    const unsigned short* r_pb2  = (const unsigned short*)d_in[21];

    float* ws = (float*)d_ws;
    float* b_enc = ws;                                     // M*128
    float* kvs   = b_enc + (size_t)M * 128;                // 12288
    float* kss   = kvs + 12288;                            // 384
    unsigned short* wqT  = (unsigned short*)(kss + 384);   // 3*16384
    unsigned short* waT  = wqT + 49152;
    unsigned short* w1T  = waT + 49152;
    unsigned short* w2T  = w1T + 49152;
    unsigned short* ksT  = w2T + 49152;                    // 3*2048
    unsigned short* pw1T = ksT + 6144;                     // 8192
    unsigned short* pweT = pw1T + 8192;                    // 4096

    encode_kernel<<<M / 8, 256, 0, stream>>>(
        r_bpts, r_bpew, r_bpeb, r_pew, b_enc, kvs);
    khvred_kernel<<<384, 1024, 0, stream>>>(
        b_enc, r_Wk, r_bk, r_Wv, r_bv, r_pew, kvs, kss);
    prep_kernel<<<215040 / 256, 256, 0, stream>>>(
        r_Wq, r_W1, r_W2, r_pw1, kvs, kss, r_Wo, r_pew,
        wqT, w1T, w2T, pw1T, waT, ksT, pweT);
    mega_kernel<<<N / 128, 256, 0, stream>>>(
        r_qpts, pweT, r_peb, wqT, waT, ksT, w1T, w2T,
        r_bq, r_bo, r_b1, r_b2, pw1T, r_pb1, r_pw2, r_pb2, r_pew, d_out);
}